// Round 4
// baseline (1431.246 us; speedup 1.0000x reference)
//
#include <hip/hip_runtime.h>

#define NU 100000
#define NM 20000
#define NE 2000000
#define NL 500000
#define H  128
#define MROW 48   // decoder rows/block. Weight stream is 512 KB per block regardless of
                  // MROW, so rows/block sets L2 weight traffic: MROW=48 -> 5.3 GB (R1: 18 TB/s,
                  // not saturated), MROW=32 -> 8 GB hit the ~22 TB/s achievable L2 ceiling
                  // (R3: 364us regression). R4: keep 48 rows, halve LDS via kh-split h1
                  // (48 KB total) -> 3 blocks/CU with __launch_bounds__(512,6).

typedef __attribute__((ext_vector_type(8))) short bf16x8;            // 8 bf16 (4 VGPRs)
typedef __attribute__((ext_vector_type(4))) float floatx4;           // 4 fp32 acc
typedef __attribute__((ext_vector_type(8))) unsigned short u16x8;    // 16B load/store
typedef __attribute__((ext_vector_type(4))) unsigned short u16x4;    // 8B store

// Native bf16 convert (RNE) — lowers to v_cvt_pk_bf16_f32 on gfx950.
__device__ __forceinline__ unsigned short f2b(float x) {
    union { __bf16 h; unsigned short u; } v;
    v.h = (__bf16)x;
    return v.u;
}
__device__ __forceinline__ float b2f(unsigned short h) {
    union { unsigned u; float f; } v; v.u = ((unsigned)h) << 16;
    return v.f;
}

// rotated LDS chunk addressing (chunk = 16B = 8 bf16), zero-waste bank pad.
// NOTE (R2): residual SQ_LDS_BANK_CONFLICT (~2.8e7) is inherent b128 wide-op
// serialization at full LDS BW, not a fixable conflict.
#define SFCH(r, c)  ((r) * 32 + (((c) + (r)) & 31))   // rows x 32 chunks (256 cols)
#define SH1CH(r, c) ((r) * 16 + (((c) + (r)) & 15))   // rows x 16 chunks (128 cols)

// ---------------------------------------------------------------- transpose (proj weights only)
struct TDesc { const float* s; float* d; int R; int C; };
struct TPack { TDesc t[2]; };

__global__ __launch_bounds__(256) void transpose_all(TPack p) {
    TDesc d = p.t[blockIdx.y];
    int n = d.R * d.C;
    for (int i = blockIdx.x * 256 + threadIdx.x; i < n; i += gridDim.x * 256) {
        int r = i / d.C, c = i - r * d.C;
        d.d[c * d.R + r] = d.s[i];  // dst[k][h] = src[h][k]
    }
}

// ---------------------------------------------------------------- pack decoder weights into MFMA frag order
// (A-fragment and B-fragment lane layouts are identical for 16x16x32)
__global__ __launch_bounds__(256) void pack_weights(const float* __restrict__ W1,
                                                    const float* __restrict__ W2,
                                                    unsigned short* __restrict__ W1p,
                                                    unsigned short* __restrict__ W2p) {
    const int n = 512 * 256;
    for (int i = blockIdx.x * 256 + threadIdx.x; i < n; i += gridDim.x * 256) {
        int j = i & 7, lane = (i >> 3) & 63;
        int ln = lane & 15, lq = lane >> 4;
        int kg1 = (i >> 9) & 7,  t1 = i >> 12;
        W1p[i] = f2b(W1[(t1 * 16 + ln) * 256 + kg1 * 32 + lq * 8 + j]);
        int kg2 = (i >> 9) & 15, t2 = i >> 13;
        W2p[i] = f2b(W2[(t2 * 16 + ln) * 512 + kg2 * 32 + lq * 8 + j]);
    }
}

// ---------------------------------------------------------------- pack 8 sage weights (H x H) into B-frag order
struct SPack { const float* w[8]; };
__global__ __launch_bounds__(256) void pack_sage(SPack sp, unsigned short* __restrict__ out) {
    const int n = 8 * 16384;
    for (int i = blockIdx.x * 256 + threadIdx.x; i < n; i += gridDim.x * 256) {
        int j = i & 7, lane = (i >> 3) & 63;
        int kg = (i >> 9) & 3, t = (i >> 11) & 7, wsel = i >> 14;
        int ln = lane & 15, lq = lane >> 4;
        out[i] = f2b(sp.w[wsel][(t * 16 + ln) * H + kg * 32 + lq * 8 + j]);
    }
}

// ---------------------------------------------------------------- CSR build
__global__ __launch_bounds__(256) void deg_kernel(const int* __restrict__ ei,
                                                  int* rp_m, int* rp_u) {
    for (int i = blockIdx.x * 256 + threadIdx.x; i < NE; i += gridDim.x * 256) {
        int u = ei[i], m = ei[NE + i];
        atomicAdd(&rp_u[u + 1], 1);
        atomicAdd(&rp_m[m + 1], 1);
    }
}

__global__ __launch_bounds__(256) void scan2_kernel(int* rp_m, int n_m,
                                                    int* rp_u, int n_u) {
    int* a = (blockIdx.x == 0) ? rp_m : rp_u;
    int n  = (blockIdx.x == 0) ? n_m : n_u;
    __shared__ int s[256];
    __shared__ int carry;
    int tid = threadIdx.x;
    if (tid == 0) carry = 0;
    __syncthreads();
    for (int base = 0; base < n; base += 4096) {
        int v[16];
        int run = 0;
        int i0 = base + tid * 16;
#pragma unroll
        for (int i = 0; i < 16; ++i) {
            int x = (i0 + i < n) ? a[i0 + i] : 0;
            run += x; v[i] = run;
        }
        s[tid] = run;
        __syncthreads();
        for (int off = 1; off < 256; off <<= 1) {
            int t = (tid >= off) ? s[tid - off] : 0;
            __syncthreads();
            s[tid] += t;
            __syncthreads();
        }
        int prev = carry + (tid > 0 ? s[tid - 1] : 0);
#pragma unroll
        for (int i = 0; i < 16; ++i)
            if (i0 + i < n) a[i0 + i] = v[i] + prev;
        int total = s[255];
        __syncthreads();
        if (tid == 0) carry += total;
        __syncthreads();
    }
}

__global__ __launch_bounds__(256) void bucket_kernel(const int* __restrict__ ei,
        const int* __restrict__ rp_m, const int* __restrict__ rp_u,
        int* cur_m, int* cur_u, int* es_m, int* es_u) {
    for (int i = blockIdx.x * 256 + threadIdx.x; i < NE; i += gridDim.x * 256) {
        int u = ei[i], m = ei[NE + i];
        int pm = atomicAdd(&cur_m[m], 1);
        es_m[rp_m[m] + pm] = u;
        int pu = atomicAdd(&cur_u[u], 1);
        es_u[rp_u[u] + pu] = m;
    }
}

// ---------------------------------------------------------------- projection (Linear + BN(eval) + ReLU) -> bf16
template <int K>
__global__ __launch_bounds__(256, 2) void proj_kernel(
        const float* __restrict__ x, const float* __restrict__ Wt,
        const float* __restrict__ lb, const float* __restrict__ g,
        const float* __restrict__ bb, const float* __restrict__ bm,
        const float* __restrict__ bv, unsigned short* __restrict__ out, int N) {
    __shared__ float sA[64 * K];
    const int tid = threadIdx.x;
    const int row0 = blockIdx.x * 64;
    constexpr int F4 = K / 4;
#pragma unroll
    for (int i = 0; i < (64 * F4) / 256; ++i) {
        int idx = tid + i * 256;
        int r = idx / F4, c = idx - r * F4;
        int gr = min(row0 + r, N - 1);
        ((float4*)sA)[idx] = ((const float4*)(x + (size_t)gr * K))[c];
    }
    __syncthreads();
    const int h_t = tid & 31, r_t = tid >> 5;
    float acc[8][4] = {};
#pragma unroll 4
    for (int k = 0; k < K; k += 4) {
        float4 w[4];
#pragma unroll
        for (int kk = 0; kk < 4; ++kk)
            w[kk] = *(const float4*)(Wt + (k + kk) * H + h_t * 4);
#pragma unroll
        for (int rr = 0; rr < 8; ++rr) {
            float4 a = *(const float4*)(sA + (r_t * 8 + rr) * K + k);
            acc[rr][0] += a.x * w[0].x + a.y * w[1].x + a.z * w[2].x + a.w * w[3].x;
            acc[rr][1] += a.x * w[0].y + a.y * w[1].y + a.z * w[2].y + a.w * w[3].y;
            acc[rr][2] += a.x * w[0].z + a.y * w[1].z + a.z * w[2].z + a.w * w[3].z;
            acc[rr][3] += a.x * w[0].w + a.y * w[1].w + a.z * w[2].w + a.w * w[3].w;
        }
    }
    const int h = h_t * 4;
    float4 lb4 = *(const float4*)(lb + h);
    float4 g4  = *(const float4*)(g  + h);
    float4 bb4 = *(const float4*)(bb + h);
    float4 m4  = *(const float4*)(bm + h);
    float4 v4  = *(const float4*)(bv + h);
    float sc[4] = { g4.x * rsqrtf(v4.x + 1e-5f), g4.y * rsqrtf(v4.y + 1e-5f),
                    g4.z * rsqrtf(v4.z + 1e-5f), g4.w * rsqrtf(v4.w + 1e-5f) };
    float lbv[4] = { lb4.x, lb4.y, lb4.z, lb4.w };
    float mv[4]  = { m4.x, m4.y, m4.z, m4.w };
    float bbv[4] = { bb4.x, bb4.y, bb4.z, bb4.w };
#pragma unroll
    for (int rr = 0; rr < 8; ++rr) {
        int gr = row0 + r_t * 8 + rr;
        if (gr < N) {
            u16x4 o;
#pragma unroll
            for (int c = 0; c < 4; ++c)
                o[c] = f2b(fmaxf((acc[rr][c] + lbv[c] - mv[c]) * sc[c] + bbv[c], 0.0f));
            *(u16x4*)(out + (size_t)gr * H + h) = o;
        }
    }
}

// ---------------------------------------------------------------- segment mean (bf16 in/out, fp32 acc)
// one WAVE per node. 16 lanes x 16B per row, 4 rows per wave-instruction,
// 16 rows in flight (R2 rewrite: ~57us total win vs 64-lane x 4B layout).
__global__ __launch_bounds__(256) void agg_bf16(
        const unsigned short* __restrict__ srcA, const int* __restrict__ esA,
        const int* __restrict__ rpA, unsigned short* __restrict__ outA, int nA,
        const unsigned short* __restrict__ srcB, const int* __restrict__ esB,
        const int* __restrict__ rpB, unsigned short* __restrict__ outB, int nB) {
    int wid = blockIdx.x * 4 + (threadIdx.x >> 6);
    const int lane = threadIdx.x & 63;
    const unsigned short* src; const int* es; const int* rp; unsigned short* out; int n;
    if (wid < nA) { src = srcA; es = esA; rp = rpA; out = outA; n = wid; }
    else {
        wid -= nA;
        if (wid >= nB) return;
        src = srcB; es = esB; rp = rpB; out = outB; n = wid;
    }
    const int start = rp[n], end = rp[n + 1];
    const int cb = (lane & 15) * 8;   // col base (8 bf16 = 16B)
    const int ro = lane >> 4;         // row slot 0..3
    float acc[8] = {};
    if (end > start) {
        int j = start;
        for (; j + 16 <= end; j += 16) {   // 16 rows in flight
            u16x8 v0 = *(const u16x8*)(src + (size_t)es[j +      ro] * H + cb);
            u16x8 v1 = *(const u16x8*)(src + (size_t)es[j +  4 + ro] * H + cb);
            u16x8 v2 = *(const u16x8*)(src + (size_t)es[j +  8 + ro] * H + cb);
            u16x8 v3 = *(const u16x8*)(src + (size_t)es[j + 12 + ro] * H + cb);
#pragma unroll
            for (int e = 0; e < 8; ++e)
                acc[e] += b2f(v0[e]) + b2f(v1[e]) + b2f(v2[e]) + b2f(v3[e]);
        }
        for (; j + 4 <= end; j += 4) {
            u16x8 v = *(const u16x8*)(src + (size_t)es[j + ro] * H + cb);
#pragma unroll
            for (int e = 0; e < 8; ++e) acc[e] += b2f(v[e]);
        }
        if (j < end) {   // tail 1..3 rows: masked batch (clamped index, end>start)
            int idx = j + ro;
            int row = es[idx < end ? idx : end - 1];
            float m = (idx < end) ? 1.0f : 0.0f;
            u16x8 v = *(const u16x8*)(src + (size_t)row * H + cb);
#pragma unroll
            for (int e = 0; e < 8; ++e) acc[e] = fmaf(m, b2f(v[e]), acc[e]);
        }
    }
#pragma unroll
    for (int e = 0; e < 8; ++e) {
        acc[e] += __shfl_xor(acc[e], 16);
        acc[e] += __shfl_xor(acc[e], 32);
    }
    float inv = (end > start) ? 1.0f / (float)(end - start) : 0.0f;
    if (ro == 0) {
        u16x8 o;
#pragma unroll
        for (int e = 0; e < 8; ++e) o[e] = f2b(acc[e] * inv);
        *(u16x8*)(out + (size_t)n * H + cb) = o;
    }
}

// ---------------------------------------------------------------- SAGE via MFMA
__global__ __launch_bounds__(256, 4) void sage_mfma(
        const unsigned short* __restrict__ aggA, const unsigned short* __restrict__ xA,
        const unsigned short* __restrict__ WlA, const unsigned short* __restrict__ WrA,
        const float* __restrict__ blA, unsigned short* __restrict__ outA, int NA, int NBLKA,
        const unsigned short* __restrict__ aggB, const unsigned short* __restrict__ xB,
        const unsigned short* __restrict__ WlB, const unsigned short* __restrict__ WrB,
        const float* __restrict__ blB, unsigned short* __restrict__ outB, int NB,
        int relu) {
    __shared__ unsigned short sAg[64 * 16 * 8];  // 16 KB
    __shared__ unsigned short sX[64 * 16 * 8];   // 16 KB
    const int tid = threadIdx.x;
    const unsigned short *agg, *x, *Wl, *Wr; const float* bl; unsigned short* out;
    int N, row0;
    if ((int)blockIdx.x < NBLKA) {
        agg = aggA; x = xA; Wl = WlA; Wr = WrA; bl = blA; out = outA; N = NA;
        row0 = blockIdx.x * 64;
    } else {
        agg = aggB; x = xB; Wl = WlB; Wr = WrB; bl = blB; out = outB; N = NB;
        row0 = (blockIdx.x - NBLKA) * 64;
    }
#pragma unroll
    for (int i = 0; i < 4; ++i) {
        int idx = tid + i * 256;           // 1024 chunks
        int r = idx >> 4, c = idx & 15;
        int gr = min(row0 + r, N - 1);
        *(u16x8*)(sAg + SH1CH(r, c) * 8) = *(const u16x8*)(agg + (size_t)gr * H + c * 8);
        *(u16x8*)(sX  + SH1CH(r, c) * 8) = *(const u16x8*)(x   + (size_t)gr * H + c * 8);
    }
    __syncthreads();
    const int lane = tid & 63, w = tid >> 6;
    const int ln = lane & 15, lq = lane >> 4;
    floatx4 acc[2][4] = {};
#pragma unroll 2
    for (int kg = 0; kg < 4; ++kg) {
        bf16x8 aA[4], aX[4];
#pragma unroll
        for (int mt = 0; mt < 4; ++mt) {
            aA[mt] = *(const bf16x8*)(sAg + SH1CH(mt * 16 + ln, kg * 4 + lq) * 8);
            aX[mt] = *(const bf16x8*)(sX  + SH1CH(mt * 16 + ln, kg * 4 + lq) * 8);
        }
#pragma unroll
        for (int nt = 0; nt < 2; ++nt) {
            int widx = ((w * 2 + nt) * 4 + kg) * 512 + lane * 8;
            bf16x8 bL = *(const bf16x8*)(Wl + widx);
            bf16x8 bR = *(const bf16x8*)(Wr + widx);
#pragma unroll
            for (int mt = 0; mt < 4; ++mt) {
                acc[nt][mt] = __builtin_amdgcn_mfma_f32_16x16x32_bf16(aA[mt], bL, acc[nt][mt], 0, 0, 0);
                acc[nt][mt] = __builtin_amdgcn_mfma_f32_16x16x32_bf16(aX[mt], bR, acc[nt][mt], 0, 0, 0);
            }
        }
    }
    __syncthreads();   // done reading sAg; reuse it for output staging
    {
#pragma unroll
        for (int nt = 0; nt < 2; ++nt) {
            int ncol = w * 32 + nt * 16 + ln;   // 0..127
            float bv = bl[ncol];
            int cch = ncol >> 3, coff = ncol & 7;
#pragma unroll
            for (int mt = 0; mt < 4; ++mt)
#pragma unroll
                for (int i = 0; i < 4; ++i) {
                    int row = mt * 16 + lq * 4 + i;
                    float v = acc[nt][mt][i] + bv;
                    if (relu) v = fmaxf(v, 0.0f);
                    sAg[SH1CH(row, cch) * 8 + coff] = f2b(v);
                }
        }
    }
    __syncthreads();
#pragma unroll
    for (int i = 0; i < 4; ++i) {
        int idx = tid + i * 256;
        int r = idx >> 4, c = idx & 15;
        int gr = row0 + r;
        if (gr < N)
            *(u16x8*)(out + (size_t)gr * H + c * 8) = *(const u16x8*)(sAg + SH1CH(r, c) * 8);
    }
}

// ---------------------------------------------------------------- fused edge decoder MLP — kh-split, M=48
// R4: keep MROW=48 (weight amortization, R3 lesson) but halve LDS by splitting
// h1 into two 256-col half-tiles: for kh in {0,1}: phase1 computes h1 cols
// [kh*256,+256) into a 24 KB half-buffer, phase2 immediately accumulates that
// K-range into persistent acc3. LDS = sF 24K + sH1h 24K = 48 KB -> 3 blocks/CU.
// Accumulation order identical to full-h1 version (kg 0..15 = kh0:0-7, kh1:0-7).
// Register budget for 6 waves/SIMD (3 blk x 8 waves / 4 SIMD): <=85 unified
// VGPR+AGPR. Live peak: acc3 24 + acc1 24 + wa 8 + fb 4 + addressing ~= 80.
// Layer 3 fused into phase-2 registers (R1): no LDS h2, no bf16 round-trip.
__global__ __launch_bounds__(512, 6) void decoder_mfma(
        const unsigned short* __restrict__ zu, const unsigned short* __restrict__ zm,
        const int* __restrict__ eli,
        const unsigned short* __restrict__ W1p, const float* __restrict__ b1,
        const unsigned short* __restrict__ W2p, const float* __restrict__ b2,
        const float* __restrict__ W3, const float* __restrict__ b3,
        float* __restrict__ out) {
    __shared__ unsigned short sF[MROW * 32 * 8];   // feat 48x256 bf16 rotated (24 KB), later f32 partials
    __shared__ unsigned short sH1[MROW * 32 * 8];  // h1 HALF 48x256 bf16 rotated (24 KB)
    const int tid = threadIdx.x;
    const int row0 = blockIdx.x * MROW;
    // ---- gather feat = [zu[eu] | zm[em]] (bf16 straight copy); 8 threads/row
    {
        int r = tid >> 3, p = tid & 7;
        if (r < MROW) {
            int rg = min(row0 + r, NL - 1);
            int iu = eli[rg], im = eli[NL + rg];
            const unsigned short* zur = zu + (size_t)iu * H;
            const unsigned short* zmr = zm + (size_t)im * H;
#pragma unroll
            for (int j = 0; j < 4; ++j) {
                int c = p + j * 8;   // 0..31
                const unsigned short* s = (c < 16) ? (zur + c * 8) : (zmr + (c - 16) * 8);
                *(u16x8*)(sF + SFCH(r, c) * 8) = *(const u16x8*)s;
            }
        }
    }
    __syncthreads();
    const int lane = tid & 63, w = tid >> 6;   // 8 waves
    const int ln = lane & 15, lq = lane >> 4;
    floatx4 acc3[2][3] = {};   // h2 accumulator, persists across kh halves
#pragma unroll
    for (int kh = 0; kh < 2; ++kh) {
        // ---- phase 1 (kh): h1^T cols [kh*256,+256); wave w owns local cols [w*32,+32)
        {
            floatx4 acc1[2][3] = {};
            const unsigned short* w1base = W1p + (size_t)((kh * 16 + w * 2) * 8) * 512 + lane * 8;
            for (int kg = 0; kg < 8; ++kg) {
                bf16x8 wa0 = *(const bf16x8*)(w1base + (size_t)kg * 512);
                bf16x8 wa1 = *(const bf16x8*)(w1base + (size_t)(8 + kg) * 512);
#pragma unroll
                for (int mt = 0; mt < 3; ++mt) {
                    bf16x8 fb = *(const bf16x8*)(sF + SFCH(mt * 16 + ln, kg * 4 + lq) * 8);
                    acc1[0][mt] = __builtin_amdgcn_mfma_f32_16x16x32_bf16(wa0, fb, acc1[0][mt], 0, 0, 0);
                    acc1[1][mt] = __builtin_amdgcn_mfma_f32_16x16x32_bf16(wa1, fb, acc1[1][mt], 0, 0, 0);
                }
            }
            // epilogue: ReLU(acc1 + b1) -> sH1 half-buffer (local cols 0..255)
#pragma unroll
            for (int nt = 0; nt < 2; ++nt) {
                int colbase = w * 32 + nt * 16 + lq * 4;   // local h1 col of reg 0
                float4 bv = *(const float4*)(b1 + kh * 256 + colbase);
                int cch = colbase >> 3, coff = colbase & 7;   // coff = (lq&1)*4
#pragma unroll
                for (int mt = 0; mt < 3; ++mt) {
                    int erow = mt * 16 + ln;
                    u16x4 o = { f2b(fmaxf(acc1[nt][mt][0] + bv.x, 0.0f)),
                                f2b(fmaxf(acc1[nt][mt][1] + bv.y, 0.0f)),
                                f2b(fmaxf(acc1[nt][mt][2] + bv.z, 0.0f)),
                                f2b(fmaxf(acc1[nt][mt][3] + bv.w, 0.0f)) };
                    *(u16x4*)(sH1 + SFCH(erow, cch) * 8 + coff) = o;
                }
            }
        }
        __syncthreads();
        // ---- phase 2 (kh): acc3 += W2[:, kh*256:+256] · h1half^T; wave w owns h2 cols [w*32,+32)
        {
            const unsigned short* w2base = W2p + (size_t)((w * 2) * 16 + kh * 8) * 512 + lane * 8;
            for (int kg = 0; kg < 8; ++kg) {
                bf16x8 wa0 = *(const bf16x8*)(w2base + (size_t)kg * 512);
                bf16x8 wa1 = *(const bf16x8*)(w2base + (size_t)(16 + 0) * 512 * 1 + (size_t)kg * 512 + (size_t)0 * 512);
                wa1 = *(const bf16x8*)(w2base + (size_t)(16 + kg) * 512);
#pragma unroll
                for (int mt = 0; mt < 3; ++mt) {
                    bf16x8 hb = *(const bf16x8*)(sH1 + SFCH(mt * 16 + ln, kg * 4 + lq) * 8);
                    acc3[0][mt] = __builtin_amdgcn_mfma_f32_16x16x32_bf16(wa0, hb, acc3[0][mt], 0, 0, 0);
                    acc3[1][mt] = __builtin_amdgcn_mfma_f32_16x16x32_bf16(wa1, hb, acc3[1][mt], 0, 0, 0);
                }
            }
        }
        if (kh == 0) __syncthreads();   // all reads of sH1 half done before kh=1 overwrites
    }
    // ---- fused layer 3: per-lane partial dot over this lane's 8 h2 cols
    // (ReLU + b2 applied in fp32 registers; sF free: last read was P1(kh=1), barrier since)
    float* sP = (float*)sF;   // 48 x 36 f32 partials (6.9 KB, stride 36 -> <=2-way banks)
    {
        float4 w3a = *(const float4*)(W3 + w * 32 + lq * 4);
        float4 w3b = *(const float4*)(W3 + w * 32 + 16 + lq * 4);
        float4 b2a = *(const float4*)(b2 + w * 32 + lq * 4);
        float4 b2b = *(const float4*)(b2 + w * 32 + 16 + lq * 4);
#pragma unroll
        for (int mt = 0; mt < 3; ++mt) {
            float s =
                fmaxf(acc3[0][mt][0] + b2a.x, 0.0f) * w3a.x +
                fmaxf(acc3[0][mt][1] + b2a.y, 0.0f) * w3a.y +
                fmaxf(acc3[0][mt][2] + b2a.z, 0.0f) * w3a.z +
                fmaxf(acc3[0][mt][3] + b2a.w, 0.0f) * w3a.w +
                fmaxf(acc3[1][mt][0] + b2b.x, 0.0f) * w3b.x +
                fmaxf(acc3[1][mt][1] + b2b.y, 0.0f) * w3b.y +
                fmaxf(acc3[1][mt][2] + b2b.z, 0.0f) * w3b.z +
                fmaxf(acc3[1][mt][3] + b2b.w, 0.0f) * w3b.w;
            sP[(mt * 16 + ln) * 36 + w * 4 + lq] = s;
        }
    }
    __syncthreads();
    // ---- reduce 32 partials per edge row: 8 threads/row, float4 each, shfl
    {
        int r = tid >> 3, p = tid & 7;
        if (r < MROW) {
            float4 v = *(const float4*)(sP + r * 36 + p * 4);
            float sum = v.x + v.y + v.z + v.w;
            sum += __shfl_down(sum, 4, 8);
            sum += __shfl_down(sum, 2, 8);
            sum += __shfl_down(sum, 1, 8);
            if (p == 0 && row0 + r < NL) out[row0 + r] = sum + b3[0];
        }
    }
}

// ---------------------------------------------------------------- host
extern "C" void kernel_launch(void* const* d_in, const int* in_sizes, int n_in,
                              void* d_out, int out_size, void* d_ws, size_t ws_size,
                              hipStream_t stream) {
    const float* x_user  = (const float*)d_in[0];
    const float* x_movie = (const float*)d_in[1];
    const int*   ei      = (const int*)d_in[2];
    const int*   eli     = (const int*)d_in[3];
    const float* lin_u_W = (const float*)d_in[4];
    const float* lin_u_b = (const float*)d_in[5];
    const float* lin_m_W = (const float*)d_in[6];
    const float* lin_m_b = (const float*)d_in[7];
    const float* bn_u_g  = (const float*)d_in[8];
    const float* bn_u_b  = (const float*)d_in[9];
    const float* bn_u_m  = (const float*)d_in[10];
    const float* bn_u_v  = (const float*)d_in[11];
    const float* bn_m_g  = (const float*)d_in[12];
    const float* bn_m_b  = (const float*)d_in[13];
    const float* bn_m_m  = (const float*)d_in[14];
    const float* bn_m_v  = (const float*)d_in[15];
    const float* c1_um_Wl = (const float*)d_in[16];
    const float* c1_um_bl = (const float*)d_in[17];
    const float* c1_um_Wr = (const float*)d_in[18];
    const float* c1_mu_Wl = (const float*)d_in[19];
    const float* c1_mu_bl = (const float*)d_in[20];
    const float* c1_mu_Wr = (const float*)d_in[21];
    const float* c2_um_Wl = (const float*)d_in[22];
    const float* c2_um_bl = (const float*)d_in[23];
    const float* c2_um_Wr = (const float*)d_in[24];
    const float* c2_mu_Wl = (const float*)d_in[25];
    const float* c2_mu_bl = (const float*)d_in[26];
    const float* c2_mu_Wr = (const float*)d_in[27];
    const float* dec_W1 = (const float*)d_in[28];
    const float* dec_b1 = (const float*)d_in[29];
    const float* dec_W2 = (const float*)d_in[30];
    const float* dec_b2 = (const float*)d_in[31];
    const float* dec_W3 = (const float*)d_in[32];
    const float* dec_b3 = (const float*)d_in[33];

    char* base = (char*)d_ws;
    size_t off = 0;
    auto alloc = [&](size_t bytes) -> char* {
        char* p = base + off;
        off += (bytes + 255) & ~(size_t)255;
        return p;
    };
    unsigned short* xu_b  = (unsigned short*)alloc((size_t)NU * H * 2);
    unsigned short* xm_b  = (unsigned short*)alloc((size_t)NM * H * 2);
    unsigned short* xu1_b = (unsigned short*)alloc((size_t)NU * H * 2);
    unsigned short* xm1_b = (unsigned short*)alloc((size_t)NM * H * 2);
    unsigned short* aggu  = (unsigned short*)alloc((size_t)NU * H * 2);
    unsigned short* aggm  = (unsigned short*)alloc((size_t)NM * H * 2);
    float* wt_u = (float*)alloc((size_t)64 * H * 4);
    float* wt_m = (float*)alloc((size_t)H * H * 4);
    unsigned short* wsg = (unsigned short*)alloc((size_t)8 * 16384 * 2);  // packed sage weights
    unsigned short* w1p = (unsigned short*)alloc((size_t)512 * 256 * 2);
    unsigned short* w2p = (unsigned short*)alloc((size_t)256 * 512 * 2);
    int* rp_m  = (int*)alloc((size_t)(NM + 1) * 4);
    int* rp_u  = (int*)alloc((size_t)(NU + 1) * 4);
    int* cur_m = (int*)alloc((size_t)NM * 4);
    int* cur_u = (int*)alloc((size_t)NU * 4);
    int* es_m  = (int*)alloc((size_t)NE * 4);
    int* es_u  = (int*)alloc((size_t)NE * 4);
    unsigned short* zu = xu_b;   // xu_b dead after conv1 sage -> reuse
    unsigned short* zm = xm_b;

    // zero CSR meta (rp_m .. cur_u incl. padding)
    hipMemsetAsync(rp_m, 0, (size_t)((char*)es_m - (char*)rp_m), stream);

    TPack tp;
    tp.t[0] = { lin_u_W, wt_u, H, 64 };
    tp.t[1] = { lin_m_W, wt_m, H, H };
    transpose_all<<<dim3(64, 2), 256, 0, stream>>>(tp);
    pack_weights<<<256, 256, 0, stream>>>(dec_W1, dec_W2, w1p, w2p);
    SPack sp;
    sp.w[0] = c1_um_Wl; sp.w[1] = c1_um_Wr; sp.w[2] = c1_mu_Wl; sp.w[3] = c1_mu_Wr;
    sp.w[4] = c2_um_Wl; sp.w[5] = c2_um_Wr; sp.w[6] = c2_mu_Wl; sp.w[7] = c2_mu_Wr;
    pack_sage<<<128, 256, 0, stream>>>(sp, wsg);
    const unsigned short* W_c1um_l = wsg + 0 * 16384;
    const unsigned short* W_c1um_r = wsg + 1 * 16384;
    const unsigned short* W_c1mu_l = wsg + 2 * 16384;
    const unsigned short* W_c1mu_r = wsg + 3 * 16384;
    const unsigned short* W_c2um_l = wsg + 4 * 16384;
    const unsigned short* W_c2um_r = wsg + 5 * 16384;
    const unsigned short* W_c2mu_l = wsg + 6 * 16384;
    const unsigned short* W_c2mu_r = wsg + 7 * 16384;

    deg_kernel<<<2048, 256, 0, stream>>>(ei, rp_m, rp_u);
    scan2_kernel<<<2, 256, 0, stream>>>(rp_m, NM + 1, rp_u, NU + 1);
    bucket_kernel<<<2048, 256, 0, stream>>>(ei, rp_m, rp_u, cur_m, cur_u, es_m, es_u);

    proj_kernel<64><<<(NU + 63) / 64, 256, 0, stream>>>(
        x_user, wt_u, lin_u_b, bn_u_g, bn_u_b, bn_u_m, bn_u_v, xu_b, NU);
    proj_kernel<128><<<(NM + 63) / 64, 256, 0, stream>>>(
        x_movie, wt_m, lin_m_b, bn_m_g, bn_m_b, bn_m_m, bn_m_v, xm_b, NM);

    const int AGG_BLOCKS = (NM + NU + 3) / 4;
    const int NBLK_M = (NM + 63) / 64, NBLK_U = (NU + 63) / 64;

    // conv1
    agg_bf16<<<AGG_BLOCKS, 256, 0, stream>>>(xu_b, es_m, rp_m, aggm, NM,
                                             xm_b, es_u, rp_u, aggu, NU);
    sage_mfma<<<NBLK_M + NBLK_U, 256, 0, stream>>>(
        aggm, xm_b, W_c1um_l, W_c1um_r, c1_um_bl, xm1_b, NM, NBLK_M,
        aggu, xu_b, W_c1mu_l, W_c1mu_r, c1_mu_bl, xu1_b, NU, 1);
    // conv2
    agg_bf16<<<AGG_BLOCKS, 256, 0, stream>>>(xu1_b, es_m, rp_m, aggm, NM,
                                             xm1_b, es_u, rp_u, aggu, NU);
    sage_mfma<<<NBLK_M + NBLK_U, 256, 0, stream>>>(
        aggm, xm1_b, W_c2um_l, W_c2um_r, c2_um_bl, zm, NM, NBLK_M,
        aggu, xu1_b, W_c2mu_l, W_c2mu_r, c2_mu_bl, zu, NU, 0);

    // decoder (bf16 MFMA, kh-split h1, fused layer-3, M=48, 48 KB LDS -> 3 blocks/CU)
    decoder_mfma<<<(NL + MROW - 1) / MROW, 512, 0, stream>>>(
        zu, zm, eli, w1p, dec_b1, w2p, dec_b2, dec_W3, dec_b3, (float*)d_out);
}

// Round 5
// 1388.990 us; speedup vs baseline: 1.0304x; 1.0304x over previous
//
#include <hip/hip_runtime.h>

#define NU 100000
#define NM 20000
#define NE 2000000
#define NL 500000
#define H  128
#define MROW 64   // decoder rows/block. Weight stream is 512 KB per block regardless of
                  // MROW (kh loop covers all of W1p+W2p), so bigger MROW = less L2 weight
                  // traffic: 64 -> 4.0 GB vs 48 -> 5.3 GB vs 32 -> 8 GB (R3: 8 GB hit the
                  // ~22 TB/s L2 ceiling, 364us). kh-split h1 keeps LDS at 64 KB -> 2 blk/CU.
                  // R4 lesson: do NOT force waves/EU beyond the live-register peak —
                  // __launch_bounds__(512,6) (85 regs) spilled accumulators: FETCH 106->735 MB,
                  // decoder 520us. Stay at (512,4) = 128 regs; live peak ~91.

typedef __attribute__((ext_vector_type(8))) short bf16x8;            // 8 bf16 (4 VGPRs)
typedef __attribute__((ext_vector_type(4))) float floatx4;           // 4 fp32 acc
typedef __attribute__((ext_vector_type(8))) unsigned short u16x8;    // 16B load/store
typedef __attribute__((ext_vector_type(4))) unsigned short u16x4;    // 8B store

// Native bf16 convert (RNE) — lowers to v_cvt_pk_bf16_f32 on gfx950.
__device__ __forceinline__ unsigned short f2b(float x) {
    union { __bf16 h; unsigned short u; } v;
    v.h = (__bf16)x;
    return v.u;
}
__device__ __forceinline__ float b2f(unsigned short h) {
    union { unsigned u; float f; } v; v.u = ((unsigned)h) << 16;
    return v.f;
}

// rotated LDS chunk addressing (chunk = 16B = 8 bf16), zero-waste bank pad.
// NOTE (R2): residual SQ_LDS_BANK_CONFLICT (~2.8e7) is inherent b128 wide-op
// serialization at full LDS BW, not a fixable conflict.
#define SFCH(r, c)  ((r) * 32 + (((c) + (r)) & 31))   // rows x 32 chunks (256 cols)
#define SH1CH(r, c) ((r) * 16 + (((c) + (r)) & 15))   // rows x 16 chunks (128 cols)

// ---------------------------------------------------------------- transpose (proj weights only)
struct TDesc { const float* s; float* d; int R; int C; };
struct TPack { TDesc t[2]; };

__global__ __launch_bounds__(256) void transpose_all(TPack p) {
    TDesc d = p.t[blockIdx.y];
    int n = d.R * d.C;
    for (int i = blockIdx.x * 256 + threadIdx.x; i < n; i += gridDim.x * 256) {
        int r = i / d.C, c = i - r * d.C;
        d.d[c * d.R + r] = d.s[i];  // dst[k][h] = src[h][k]
    }
}

// ---------------------------------------------------------------- pack decoder weights into MFMA frag order
// (A-fragment and B-fragment lane layouts are identical for 16x16x32)
__global__ __launch_bounds__(256) void pack_weights(const float* __restrict__ W1,
                                                    const float* __restrict__ W2,
                                                    unsigned short* __restrict__ W1p,
                                                    unsigned short* __restrict__ W2p) {
    const int n = 512 * 256;
    for (int i = blockIdx.x * 256 + threadIdx.x; i < n; i += gridDim.x * 256) {
        int j = i & 7, lane = (i >> 3) & 63;
        int ln = lane & 15, lq = lane >> 4;
        int kg1 = (i >> 9) & 7,  t1 = i >> 12;
        W1p[i] = f2b(W1[(t1 * 16 + ln) * 256 + kg1 * 32 + lq * 8 + j]);
        int kg2 = (i >> 9) & 15, t2 = i >> 13;
        W2p[i] = f2b(W2[(t2 * 16 + ln) * 512 + kg2 * 32 + lq * 8 + j]);
    }
}

// ---------------------------------------------------------------- pack 8 sage weights (H x H) into B-frag order
struct SPack { const float* w[8]; };
__global__ __launch_bounds__(256) void pack_sage(SPack sp, unsigned short* __restrict__ out) {
    const int n = 8 * 16384;
    for (int i = blockIdx.x * 256 + threadIdx.x; i < n; i += gridDim.x * 256) {
        int j = i & 7, lane = (i >> 3) & 63;
        int kg = (i >> 9) & 3, t = (i >> 11) & 7, wsel = i >> 14;
        int ln = lane & 15, lq = lane >> 4;
        out[i] = f2b(sp.w[wsel][(t * 16 + ln) * H + kg * 32 + lq * 8 + j]);
    }
}

// ---------------------------------------------------------------- CSR build
__global__ __launch_bounds__(256) void deg_kernel(const int* __restrict__ ei,
                                                  int* rp_m, int* rp_u) {
    for (int i = blockIdx.x * 256 + threadIdx.x; i < NE; i += gridDim.x * 256) {
        int u = ei[i], m = ei[NE + i];
        atomicAdd(&rp_u[u + 1], 1);
        atomicAdd(&rp_m[m + 1], 1);
    }
}

__global__ __launch_bounds__(256) void scan2_kernel(int* rp_m, int n_m,
                                                    int* rp_u, int n_u) {
    int* a = (blockIdx.x == 0) ? rp_m : rp_u;
    int n  = (blockIdx.x == 0) ? n_m : n_u;
    __shared__ int s[256];
    __shared__ int carry;
    int tid = threadIdx.x;
    if (tid == 0) carry = 0;
    __syncthreads();
    for (int base = 0; base < n; base += 4096) {
        int v[16];
        int run = 0;
        int i0 = base + tid * 16;
#pragma unroll
        for (int i = 0; i < 16; ++i) {
            int x = (i0 + i < n) ? a[i0 + i] : 0;
            run += x; v[i] = run;
        }
        s[tid] = run;
        __syncthreads();
        for (int off = 1; off < 256; off <<= 1) {
            int t = (tid >= off) ? s[tid - off] : 0;
            __syncthreads();
            s[tid] += t;
            __syncthreads();
        }
        int prev = carry + (tid > 0 ? s[tid - 1] : 0);
#pragma unroll
        for (int i = 0; i < 16; ++i)
            if (i0 + i < n) a[i0 + i] = v[i] + prev;
        int total = s[255];
        __syncthreads();
        if (tid == 0) carry += total;
        __syncthreads();
    }
}

__global__ __launch_bounds__(256) void bucket_kernel(const int* __restrict__ ei,
        const int* __restrict__ rp_m, const int* __restrict__ rp_u,
        int* cur_m, int* cur_u, int* es_m, int* es_u) {
    for (int i = blockIdx.x * 256 + threadIdx.x; i < NE; i += gridDim.x * 256) {
        int u = ei[i], m = ei[NE + i];
        int pm = atomicAdd(&cur_m[m], 1);
        es_m[rp_m[m] + pm] = u;
        int pu = atomicAdd(&cur_u[u], 1);
        es_u[rp_u[u] + pu] = m;
    }
}

// ---------------------------------------------------------------- projection (Linear + BN(eval) + ReLU) -> bf16
template <int K>
__global__ __launch_bounds__(256, 2) void proj_kernel(
        const float* __restrict__ x, const float* __restrict__ Wt,
        const float* __restrict__ lb, const float* __restrict__ g,
        const float* __restrict__ bb, const float* __restrict__ bm,
        const float* __restrict__ bv, unsigned short* __restrict__ out, int N) {
    __shared__ float sA[64 * K];
    const int tid = threadIdx.x;
    const int row0 = blockIdx.x * 64;
    constexpr int F4 = K / 4;
#pragma unroll
    for (int i = 0; i < (64 * F4) / 256; ++i) {
        int idx = tid + i * 256;
        int r = idx / F4, c = idx - r * F4;
        int gr = min(row0 + r, N - 1);
        ((float4*)sA)[idx] = ((const float4*)(x + (size_t)gr * K))[c];
    }
    __syncthreads();
    const int h_t = tid & 31, r_t = tid >> 5;
    float acc[8][4] = {};
#pragma unroll 4
    for (int k = 0; k < K; k += 4) {
        float4 w[4];
#pragma unroll
        for (int kk = 0; kk < 4; ++kk)
            w[kk] = *(const float4*)(Wt + (k + kk) * H + h_t * 4);
#pragma unroll
        for (int rr = 0; rr < 8; ++rr) {
            float4 a = *(const float4*)(sA + (r_t * 8 + rr) * K + k);
            acc[rr][0] += a.x * w[0].x + a.y * w[1].x + a.z * w[2].x + a.w * w[3].x;
            acc[rr][1] += a.x * w[0].y + a.y * w[1].y + a.z * w[2].y + a.w * w[3].y;
            acc[rr][2] += a.x * w[0].z + a.y * w[1].z + a.z * w[2].z + a.w * w[3].z;
            acc[rr][3] += a.x * w[0].w + a.y * w[1].w + a.z * w[2].w + a.w * w[3].w;
        }
    }
    const int h = h_t * 4;
    float4 lb4 = *(const float4*)(lb + h);
    float4 g4  = *(const float4*)(g  + h);
    float4 bb4 = *(const float4*)(bb + h);
    float4 m4  = *(const float4*)(bm + h);
    float4 v4  = *(const float4*)(bv + h);
    float sc[4] = { g4.x * rsqrtf(v4.x + 1e-5f), g4.y * rsqrtf(v4.y + 1e-5f),
                    g4.z * rsqrtf(v4.z + 1e-5f), g4.w * rsqrtf(v4.w + 1e-5f) };
    float lbv[4] = { lb4.x, lb4.y, lb4.z, lb4.w };
    float mv[4]  = { m4.x, m4.y, m4.z, m4.w };
    float bbv[4] = { bb4.x, bb4.y, bb4.z, bb4.w };
#pragma unroll
    for (int rr = 0; rr < 8; ++rr) {
        int gr = row0 + r_t * 8 + rr;
        if (gr < N) {
            u16x4 o;
#pragma unroll
            for (int c = 0; c < 4; ++c)
                o[c] = f2b(fmaxf((acc[rr][c] + lbv[c] - mv[c]) * sc[c] + bbv[c], 0.0f));
            *(u16x4*)(out + (size_t)gr * H + h) = o;
        }
    }
}

// ---------------------------------------------------------------- segment mean (bf16 in/out, fp32 acc)
// one WAVE per node. 16 lanes x 16B per row, 4 rows per wave-instruction,
// 16 rows in flight (R2 rewrite: ~57us total win vs 64-lane x 4B layout).
__global__ __launch_bounds__(256) void agg_bf16(
        const unsigned short* __restrict__ srcA, const int* __restrict__ esA,
        const int* __restrict__ rpA, unsigned short* __restrict__ outA, int nA,
        const unsigned short* __restrict__ srcB, const int* __restrict__ esB,
        const int* __restrict__ rpB, unsigned short* __restrict__ outB, int nB) {
    int wid = blockIdx.x * 4 + (threadIdx.x >> 6);
    const int lane = threadIdx.x & 63;
    const unsigned short* src; const int* es; const int* rp; unsigned short* out; int n;
    if (wid < nA) { src = srcA; es = esA; rp = rpA; out = outA; n = wid; }
    else {
        wid -= nA;
        if (wid >= nB) return;
        src = srcB; es = esB; rp = rpB; out = outB; n = wid;
    }
    const int start = rp[n], end = rp[n + 1];
    const int cb = (lane & 15) * 8;   // col base (8 bf16 = 16B)
    const int ro = lane >> 4;         // row slot 0..3
    float acc[8] = {};
    if (end > start) {
        int j = start;
        for (; j + 16 <= end; j += 16) {   // 16 rows in flight
            u16x8 v0 = *(const u16x8*)(src + (size_t)es[j +      ro] * H + cb);
            u16x8 v1 = *(const u16x8*)(src + (size_t)es[j +  4 + ro] * H + cb);
            u16x8 v2 = *(const u16x8*)(src + (size_t)es[j +  8 + ro] * H + cb);
            u16x8 v3 = *(const u16x8*)(src + (size_t)es[j + 12 + ro] * H + cb);
#pragma unroll
            for (int e = 0; e < 8; ++e)
                acc[e] += b2f(v0[e]) + b2f(v1[e]) + b2f(v2[e]) + b2f(v3[e]);
        }
        for (; j + 4 <= end; j += 4) {
            u16x8 v = *(const u16x8*)(src + (size_t)es[j + ro] * H + cb);
#pragma unroll
            for (int e = 0; e < 8; ++e) acc[e] += b2f(v[e]);
        }
        if (j < end) {   // tail 1..3 rows: masked batch (clamped index, end>start)
            int idx = j + ro;
            int row = es[idx < end ? idx : end - 1];
            float m = (idx < end) ? 1.0f : 0.0f;
            u16x8 v = *(const u16x8*)(src + (size_t)row * H + cb);
#pragma unroll
            for (int e = 0; e < 8; ++e) acc[e] = fmaf(m, b2f(v[e]), acc[e]);
        }
    }
#pragma unroll
    for (int e = 0; e < 8; ++e) {
        acc[e] += __shfl_xor(acc[e], 16);
        acc[e] += __shfl_xor(acc[e], 32);
    }
    float inv = (end > start) ? 1.0f / (float)(end - start) : 0.0f;
    if (ro == 0) {
        u16x8 o;
#pragma unroll
        for (int e = 0; e < 8; ++e) o[e] = f2b(acc[e] * inv);
        *(u16x8*)(out + (size_t)n * H + cb) = o;
    }
}

// ---------------------------------------------------------------- SAGE via MFMA
__global__ __launch_bounds__(256, 4) void sage_mfma(
        const unsigned short* __restrict__ aggA, const unsigned short* __restrict__ xA,
        const unsigned short* __restrict__ WlA, const unsigned short* __restrict__ WrA,
        const float* __restrict__ blA, unsigned short* __restrict__ outA, int NA, int NBLKA,
        const unsigned short* __restrict__ aggB, const unsigned short* __restrict__ xB,
        const unsigned short* __restrict__ WlB, const unsigned short* __restrict__ WrB,
        const float* __restrict__ blB, unsigned short* __restrict__ outB, int NB,
        int relu) {
    __shared__ unsigned short sAg[64 * 16 * 8];  // 16 KB
    __shared__ unsigned short sX[64 * 16 * 8];   // 16 KB
    const int tid = threadIdx.x;
    const unsigned short *agg, *x, *Wl, *Wr; const float* bl; unsigned short* out;
    int N, row0;
    if ((int)blockIdx.x < NBLKA) {
        agg = aggA; x = xA; Wl = WlA; Wr = WrA; bl = blA; out = outA; N = NA;
        row0 = blockIdx.x * 64;
    } else {
        agg = aggB; x = xB; Wl = WlB; Wr = WrB; bl = blB; out = outB; N = NB;
        row0 = (blockIdx.x - NBLKA) * 64;
    }
#pragma unroll
    for (int i = 0; i < 4; ++i) {
        int idx = tid + i * 256;           // 1024 chunks
        int r = idx >> 4, c = idx & 15;
        int gr = min(row0 + r, N - 1);
        *(u16x8*)(sAg + SH1CH(r, c) * 8) = *(const u16x8*)(agg + (size_t)gr * H + c * 8);
        *(u16x8*)(sX  + SH1CH(r, c) * 8) = *(const u16x8*)(x   + (size_t)gr * H + c * 8);
    }
    __syncthreads();
    const int lane = tid & 63, w = tid >> 6;
    const int ln = lane & 15, lq = lane >> 4;
    floatx4 acc[2][4] = {};
#pragma unroll 2
    for (int kg = 0; kg < 4; ++kg) {
        bf16x8 aA[4], aX[4];
#pragma unroll
        for (int mt = 0; mt < 4; ++mt) {
            aA[mt] = *(const bf16x8*)(sAg + SH1CH(mt * 16 + ln, kg * 4 + lq) * 8);
            aX[mt] = *(const bf16x8*)(sX  + SH1CH(mt * 16 + ln, kg * 4 + lq) * 8);
        }
#pragma unroll
        for (int nt = 0; nt < 2; ++nt) {
            int widx = ((w * 2 + nt) * 4 + kg) * 512 + lane * 8;
            bf16x8 bL = *(const bf16x8*)(Wl + widx);
            bf16x8 bR = *(const bf16x8*)(Wr + widx);
#pragma unroll
            for (int mt = 0; mt < 4; ++mt) {
                acc[nt][mt] = __builtin_amdgcn_mfma_f32_16x16x32_bf16(aA[mt], bL, acc[nt][mt], 0, 0, 0);
                acc[nt][mt] = __builtin_amdgcn_mfma_f32_16x16x32_bf16(aX[mt], bR, acc[nt][mt], 0, 0, 0);
            }
        }
    }
    __syncthreads();   // done reading sAg; reuse it for output staging
    {
#pragma unroll
        for (int nt = 0; nt < 2; ++nt) {
            int ncol = w * 32 + nt * 16 + ln;   // 0..127
            float bv = bl[ncol];
            int cch = ncol >> 3, coff = ncol & 7;
#pragma unroll
            for (int mt = 0; mt < 4; ++mt)
#pragma unroll
                for (int i = 0; i < 4; ++i) {
                    int row = mt * 16 + lq * 4 + i;
                    float v = acc[nt][mt][i] + bv;
                    if (relu) v = fmaxf(v, 0.0f);
                    sAg[SH1CH(row, cch) * 8 + coff] = f2b(v);
                }
        }
    }
    __syncthreads();
#pragma unroll
    for (int i = 0; i < 4; ++i) {
        int idx = tid + i * 256;
        int r = idx >> 4, c = idx & 15;
        int gr = row0 + r;
        if (gr < N)
            *(u16x8*)(out + (size_t)gr * H + c * 8) = *(const u16x8*)(sAg + SH1CH(r, c) * 8);
    }
}

// ---------------------------------------------------------------- fused edge decoder MLP — kh-split, M=64
// kh-split h1 (correctness verified in R4): for kh in {0,1}: phase1 computes
// h1 cols [kh*256,+256) into a 32 KB half-buffer, phase2 accumulates that
// K-range into persistent acc3. Accumulation order identical to full-h1.
// MROW=64: LDS = sF 32K + sH1h 32K = 64 KB -> 2 blocks/CU; weight L2 traffic
// 4.0 GB (vs 5.3 at M=48). Register regime (512,4)=128/wave, live peak ~91:
// acc3 32 + acc1 32 + wa 8 + fb 4 + addressing. (R4: forcing (512,6)=85 regs
// spilled accumulators -> FETCH x7, NEVER force below live peak.)
// Layer 3 fused into phase-2 registers (R1): no LDS h2, no bf16 round-trip.
__global__ __launch_bounds__(512, 4) void decoder_mfma(
        const unsigned short* __restrict__ zu, const unsigned short* __restrict__ zm,
        const int* __restrict__ eli,
        const unsigned short* __restrict__ W1p, const float* __restrict__ b1,
        const unsigned short* __restrict__ W2p, const float* __restrict__ b2,
        const float* __restrict__ W3, const float* __restrict__ b3,
        float* __restrict__ out) {
    __shared__ unsigned short sF[MROW * 32 * 8];   // feat 64x256 bf16 rotated (32 KB), later f32 partials
    __shared__ unsigned short sH1[MROW * 32 * 8];  // h1 HALF 64x256 bf16 rotated (32 KB)
    const int tid = threadIdx.x;
    const int row0 = blockIdx.x * MROW;
    // ---- gather feat = [zu[eu] | zm[em]] (bf16 straight copy); 8 threads/row, 64 rows
    {
        int r = tid >> 3, p = tid & 7;
        int rg = min(row0 + r, NL - 1);
        int iu = eli[rg], im = eli[NL + rg];
        const unsigned short* zur = zu + (size_t)iu * H;
        const unsigned short* zmr = zm + (size_t)im * H;
#pragma unroll
        for (int j = 0; j < 4; ++j) {
            int c = p + j * 8;   // 0..31
            const unsigned short* s = (c < 16) ? (zur + c * 8) : (zmr + (c - 16) * 8);
            *(u16x8*)(sF + SFCH(r, c) * 8) = *(const u16x8*)s;
        }
    }
    __syncthreads();
    const int lane = tid & 63, w = tid >> 6;   // 8 waves
    const int ln = lane & 15, lq = lane >> 4;
    floatx4 acc3[2][4] = {};   // h2 accumulator, persists across kh halves
#pragma unroll
    for (int kh = 0; kh < 2; ++kh) {
        // ---- phase 1 (kh): h1^T cols [kh*256,+256); wave w owns local cols [w*32,+32)
        {
            floatx4 acc1[2][4] = {};
            const unsigned short* w1base = W1p + (size_t)((kh * 16 + w * 2) * 8) * 512 + lane * 8;
            for (int kg = 0; kg < 8; ++kg) {
                bf16x8 wa0 = *(const bf16x8*)(w1base + (size_t)kg * 512);
                bf16x8 wa1 = *(const bf16x8*)(w1base + (size_t)(8 + kg) * 512);
#pragma unroll
                for (int mt = 0; mt < 4; ++mt) {
                    bf16x8 fb = *(const bf16x8*)(sF + SFCH(mt * 16 + ln, kg * 4 + lq) * 8);
                    acc1[0][mt] = __builtin_amdgcn_mfma_f32_16x16x32_bf16(wa0, fb, acc1[0][mt], 0, 0, 0);
                    acc1[1][mt] = __builtin_amdgcn_mfma_f32_16x16x32_bf16(wa1, fb, acc1[1][mt], 0, 0, 0);
                }
            }
            // epilogue: ReLU(acc1 + b1) -> sH1 half-buffer (local cols 0..255)
#pragma unroll
            for (int nt = 0; nt < 2; ++nt) {
                int colbase = w * 32 + nt * 16 + lq * 4;   // local h1 col of reg 0
                float4 bv = *(const float4*)(b1 + kh * 256 + colbase);
                int cch = colbase >> 3, coff = colbase & 7;   // coff = (lq&1)*4
#pragma unroll
                for (int mt = 0; mt < 4; ++mt) {
                    int erow = mt * 16 + ln;
                    u16x4 o = { f2b(fmaxf(acc1[nt][mt][0] + bv.x, 0.0f)),
                                f2b(fmaxf(acc1[nt][mt][1] + bv.y, 0.0f)),
                                f2b(fmaxf(acc1[nt][mt][2] + bv.z, 0.0f)),
                                f2b(fmaxf(acc1[nt][mt][3] + bv.w, 0.0f)) };
                    *(u16x4*)(sH1 + SFCH(erow, cch) * 8 + coff) = o;
                }
            }
        }
        __syncthreads();
        // ---- phase 2 (kh): acc3 += W2[:, kh*256:+256] · h1half^T; wave w owns h2 cols [w*32,+32)
        {
            const unsigned short* w2base = W2p + (size_t)((w * 2) * 16 + kh * 8) * 512 + lane * 8;
            for (int kg = 0; kg < 8; ++kg) {
                bf16x8 wa0 = *(const bf16x8*)(w2base + (size_t)kg * 512);
                bf16x8 wa1 = *(const bf16x8*)(w2base + (size_t)(16 + kg) * 512);
#pragma unroll
                for (int mt = 0; mt < 4; ++mt) {
                    bf16x8 hb = *(const bf16x8*)(sH1 + SFCH(mt * 16 + ln, kg * 4 + lq) * 8);
                    acc3[0][mt] = __builtin_amdgcn_mfma_f32_16x16x32_bf16(wa0, hb, acc3[0][mt], 0, 0, 0);
                    acc3[1][mt] = __builtin_amdgcn_mfma_f32_16x16x32_bf16(wa1, hb, acc3[1][mt], 0, 0, 0);
                }
            }
        }
        if (kh == 0) __syncthreads();   // all reads of sH1 half done before kh=1 overwrites
    }
    // ---- fused layer 3: per-lane partial dot over this lane's 8 h2 cols
    // (ReLU + b2 applied in fp32 registers; sF free: last read was P1(kh=1), barrier since)
    float* sP = (float*)sF;   // 64 x 36 f32 partials (9.2 KB, stride 36 -> <=2-way banks)
    {
        float4 w3a = *(const float4*)(W3 + w * 32 + lq * 4);
        float4 w3b = *(const float4*)(W3 + w * 32 + 16 + lq * 4);
        float4 b2a = *(const float4*)(b2 + w * 32 + lq * 4);
        float4 b2b = *(const float4*)(b2 + w * 32 + 16 + lq * 4);
#pragma unroll
        for (int mt = 0; mt < 4; ++mt) {
            float s =
                fmaxf(acc3[0][mt][0] + b2a.x, 0.0f) * w3a.x +
                fmaxf(acc3[0][mt][1] + b2a.y, 0.0f) * w3a.y +
                fmaxf(acc3[0][mt][2] + b2a.z, 0.0f) * w3a.z +
                fmaxf(acc3[0][mt][3] + b2a.w, 0.0f) * w3a.w +
                fmaxf(acc3[1][mt][0] + b2b.x, 0.0f) * w3b.x +
                fmaxf(acc3[1][mt][1] + b2b.y, 0.0f) * w3b.y +
                fmaxf(acc3[1][mt][2] + b2b.z, 0.0f) * w3b.z +
                fmaxf(acc3[1][mt][3] + b2b.w, 0.0f) * w3b.w;
            sP[(mt * 16 + ln) * 36 + w * 4 + lq] = s;
        }
    }
    __syncthreads();
    // ---- reduce 32 partials per edge row: 8 threads/row, float4 each, shfl
    {
        int r = tid >> 3, p = tid & 7;   // 64 rows x 8 threads
        float4 v = *(const float4*)(sP + r * 36 + p * 4);
        float sum = v.x + v.y + v.z + v.w;
        sum += __shfl_down(sum, 4, 8);
        sum += __shfl_down(sum, 2, 8);
        sum += __shfl_down(sum, 1, 8);
        if (p == 0 && row0 + r < NL) out[row0 + r] = sum + b3[0];
    }
}

// ---------------------------------------------------------------- host
extern "C" void kernel_launch(void* const* d_in, const int* in_sizes, int n_in,
                              void* d_out, int out_size, void* d_ws, size_t ws_size,
                              hipStream_t stream) {
    const float* x_user  = (const float*)d_in[0];
    const float* x_movie = (const float*)d_in[1];
    const int*   ei      = (const int*)d_in[2];
    const int*   eli     = (const int*)d_in[3];
    const float* lin_u_W = (const float*)d_in[4];
    const float* lin_u_b = (const float*)d_in[5];
    const float* lin_m_W = (const float*)d_in[6];
    const float* lin_m_b = (const float*)d_in[7];
    const float* bn_u_g  = (const float*)d_in[8];
    const float* bn_u_b  = (const float*)d_in[9];
    const float* bn_u_m  = (const float*)d_in[10];
    const float* bn_u_v  = (const float*)d_in[11];
    const float* bn_m_g  = (const float*)d_in[12];
    const float* bn_m_b  = (const float*)d_in[13];
    const float* bn_m_m  = (const float*)d_in[14];
    const float* bn_m_v  = (const float*)d_in[15];
    const float* c1_um_Wl = (const float*)d_in[16];
    const float* c1_um_bl = (const float*)d_in[17];
    const float* c1_um_Wr = (const float*)d_in[18];
    const float* c1_mu_Wl = (const float*)d_in[19];
    const float* c1_mu_bl = (const float*)d_in[20];
    const float* c1_mu_Wr = (const float*)d_in[21];
    const float* c2_um_Wl = (const float*)d_in[22];
    const float* c2_um_bl = (const float*)d_in[23];
    const float* c2_um_Wr = (const float*)d_in[24];
    const float* c2_mu_Wl = (const float*)d_in[25];
    const float* c2_mu_bl = (const float*)d_in[26];
    const float* c2_mu_Wr = (const float*)d_in[27];
    const float* dec_W1 = (const float*)d_in[28];
    const float* dec_b1 = (const float*)d_in[29];
    const float* dec_W2 = (const float*)d_in[30];
    const float* dec_b2 = (const float*)d_in[31];
    const float* dec_W3 = (const float*)d_in[32];
    const float* dec_b3 = (const float*)d_in[33];

    char* base = (char*)d_ws;
    size_t off = 0;
    auto alloc = [&](size_t bytes) -> char* {
        char* p = base + off;
        off += (bytes + 255) & ~(size_t)255;
        return p;
    };
    unsigned short* xu_b  = (unsigned short*)alloc((size_t)NU * H * 2);
    unsigned short* xm_b  = (unsigned short*)alloc((size_t)NM * H * 2);
    unsigned short* xu1_b = (unsigned short*)alloc((size_t)NU * H * 2);
    unsigned short* xm1_b = (unsigned short*)alloc((size_t)NM * H * 2);
    unsigned short* aggu  = (unsigned short*)alloc((size_t)NU * H * 2);
    unsigned short* aggm  = (unsigned short*)alloc((size_t)NM * H * 2);
    float* wt_u = (float*)alloc((size_t)64 * H * 4);
    float* wt_m = (float*)alloc((size_t)H * H * 4);
    unsigned short* wsg = (unsigned short*)alloc((size_t)8 * 16384 * 2);  // packed sage weights
    unsigned short* w1p = (unsigned short*)alloc((size_t)512 * 256 * 2);
    unsigned short* w2p = (unsigned short*)alloc((size_t)256 * 512 * 2);
    int* rp_m  = (int*)alloc((size_t)(NM + 1) * 4);
    int* rp_u  = (int*)alloc((size_t)(NU + 1) * 4);
    int* cur_m = (int*)alloc((size_t)NM * 4);
    int* cur_u = (int*)alloc((size_t)NU * 4);
    int* es_m  = (int*)alloc((size_t)NE * 4);
    int* es_u  = (int*)alloc((size_t)NE * 4);
    unsigned short* zu = xu_b;   // xu_b dead after conv1 sage -> reuse
    unsigned short* zm = xm_b;

    // zero CSR meta (rp_m .. cur_u incl. padding)
    hipMemsetAsync(rp_m, 0, (size_t)((char*)es_m - (char*)rp_m), stream);

    TPack tp;
    tp.t[0] = { lin_u_W, wt_u, H, 64 };
    tp.t[1] = { lin_m_W, wt_m, H, H };
    transpose_all<<<dim3(64, 2), 256, 0, stream>>>(tp);
    pack_weights<<<256, 256, 0, stream>>>(dec_W1, dec_W2, w1p, w2p);
    SPack sp;
    sp.w[0] = c1_um_Wl; sp.w[1] = c1_um_Wr; sp.w[2] = c1_mu_Wl; sp.w[3] = c1_mu_Wr;
    sp.w[4] = c2_um_Wl; sp.w[5] = c2_um_Wr; sp.w[6] = c2_mu_Wl; sp.w[7] = c2_mu_Wr;
    pack_sage<<<128, 256, 0, stream>>>(sp, wsg);
    const unsigned short* W_c1um_l = wsg + 0 * 16384;
    const unsigned short* W_c1um_r = wsg + 1 * 16384;
    const unsigned short* W_c1mu_l = wsg + 2 * 16384;
    const unsigned short* W_c1mu_r = wsg + 3 * 16384;
    const unsigned short* W_c2um_l = wsg + 4 * 16384;
    const unsigned short* W_c2um_r = wsg + 5 * 16384;
    const unsigned short* W_c2mu_l = wsg + 6 * 16384;
    const unsigned short* W_c2mu_r = wsg + 7 * 16384;

    deg_kernel<<<2048, 256, 0, stream>>>(ei, rp_m, rp_u);
    scan2_kernel<<<2, 256, 0, stream>>>(rp_m, NM + 1, rp_u, NU + 1);
    bucket_kernel<<<2048, 256, 0, stream>>>(ei, rp_m, rp_u, cur_m, cur_u, es_m, es_u);

    proj_kernel<64><<<(NU + 63) / 64, 256, 0, stream>>>(
        x_user, wt_u, lin_u_b, bn_u_g, bn_u_b, bn_u_m, bn_u_v, xu_b, NU);
    proj_kernel<128><<<(NM + 63) / 64, 256, 0, stream>>>(
        x_movie, wt_m, lin_m_b, bn_m_g, bn_m_b, bn_m_m, bn_m_v, xm_b, NM);

    const int AGG_BLOCKS = (NM + NU + 3) / 4;
    const int NBLK_M = (NM + 63) / 64, NBLK_U = (NU + 63) / 64;

    // conv1
    agg_bf16<<<AGG_BLOCKS, 256, 0, stream>>>(xu_b, es_m, rp_m, aggm, NM,
                                             xm_b, es_u, rp_u, aggu, NU);
    sage_mfma<<<NBLK_M + NBLK_U, 256, 0, stream>>>(
        aggm, xm_b, W_c1um_l, W_c1um_r, c1_um_bl, xm1_b, NM, NBLK_M,
        aggu, xu_b, W_c1mu_l, W_c1mu_r, c1_mu_bl, xu1_b, NU, 1);
    // conv2
    agg_bf16<<<AGG_BLOCKS, 256, 0, stream>>>(xu1_b, es_m, rp_m, aggm, NM,
                                             xm1_b, es_u, rp_u, aggu, NU);
    sage_mfma<<<NBLK_M + NBLK_U, 256, 0, stream>>>(
        aggm, xm1_b, W_c2um_l, W_c2um_r, c2_um_bl, zm, NM, NBLK_M,
        aggu, xu1_b, W_c2mu_l, W_c2mu_r, c2_mu_bl, zu, NU, 0);

    // decoder (bf16 MFMA, kh-split h1, fused layer-3, M=64, 64 KB LDS -> 2 blocks/CU)
    decoder_mfma<<<(NL + MROW - 1) / MROW, 512, 0, stream>>>(
        zu, zm, eli, w1p, dec_b1, w2p, dec_b2, dec_W3, dec_b3, (float*)d_out);
}

// Round 6
// 1368.605 us; speedup vs baseline: 1.0458x; 1.0149x over previous
//
#include <hip/hip_runtime.h>

#define NU 100000
#define NM 20000
#define NE 2000000
#define NL 500000
#define H  128
#define MROW 64   // decoder rows/block. Weight stream is 512 KB per block regardless of
                  // MROW, so bigger MROW = less L2 weight traffic: 64 -> 4.0 GB vs 48 ->
                  // 5.3 GB vs 32 -> 8 GB (R3: 8 GB hit ~22 TB/s L2 ceiling). kh-split h1
                  // keeps LDS at 64 KB -> 2 blk/CU.
                  // REGISTER HISTORY: R4 forced (512,6)=85 regs -> acc spill (FETCH x7).
                  // R5 kh-split at (512,4) STILL spilled: acc3(32)+acc1(32) simultaneously
                  // live + operands > 128 unified. R6: nt-split phase 1 -> acc1 live=16,
                  // peak ~70. If FETCH >> 110 MB this round: revert decoder to R2 3-phase.

typedef __attribute__((ext_vector_type(8))) short bf16x8;            // 8 bf16 (4 VGPRs)
typedef __attribute__((ext_vector_type(4))) float floatx4;           // 4 fp32 acc
typedef __attribute__((ext_vector_type(8))) unsigned short u16x8;    // 16B load/store
typedef __attribute__((ext_vector_type(4))) unsigned short u16x4;    // 8B store

// Native bf16 convert (RNE) — lowers to v_cvt_pk_bf16_f32 on gfx950.
__device__ __forceinline__ unsigned short f2b(float x) {
    union { __bf16 h; unsigned short u; } v;
    v.h = (__bf16)x;
    return v.u;
}
__device__ __forceinline__ float b2f(unsigned short h) {
    union { unsigned u; float f; } v; v.u = ((unsigned)h) << 16;
    return v.f;
}

// rotated LDS chunk addressing (chunk = 16B = 8 bf16), zero-waste bank pad.
// NOTE (R2): residual SQ_LDS_BANK_CONFLICT (~2.8e7) is inherent b128 wide-op
// serialization at full LDS BW, not a fixable conflict.
#define SFCH(r, c)  ((r) * 32 + (((c) + (r)) & 31))   // rows x 32 chunks (256 cols)
#define SH1CH(r, c) ((r) * 16 + (((c) + (r)) & 15))   // rows x 16 chunks (128 cols)

// ---------------------------------------------------------------- transpose (proj weights only)
struct TDesc { const float* s; float* d; int R; int C; };
struct TPack { TDesc t[2]; };

__global__ __launch_bounds__(256) void transpose_all(TPack p) {
    TDesc d = p.t[blockIdx.y];
    int n = d.R * d.C;
    for (int i = blockIdx.x * 256 + threadIdx.x; i < n; i += gridDim.x * 256) {
        int r = i / d.C, c = i - r * d.C;
        d.d[c * d.R + r] = d.s[i];  // dst[k][h] = src[h][k]
    }
}

// ---------------------------------------------------------------- pack decoder weights into MFMA frag order
// (A-fragment and B-fragment lane layouts are identical for 16x16x32)
__global__ __launch_bounds__(256) void pack_weights(const float* __restrict__ W1,
                                                    const float* __restrict__ W2,
                                                    unsigned short* __restrict__ W1p,
                                                    unsigned short* __restrict__ W2p) {
    const int n = 512 * 256;
    for (int i = blockIdx.x * 256 + threadIdx.x; i < n; i += gridDim.x * 256) {
        int j = i & 7, lane = (i >> 3) & 63;
        int ln = lane & 15, lq = lane >> 4;
        int kg1 = (i >> 9) & 7,  t1 = i >> 12;
        W1p[i] = f2b(W1[(t1 * 16 + ln) * 256 + kg1 * 32 + lq * 8 + j]);
        int kg2 = (i >> 9) & 15, t2 = i >> 13;
        W2p[i] = f2b(W2[(t2 * 16 + ln) * 512 + kg2 * 32 + lq * 8 + j]);
    }
}

// ---------------------------------------------------------------- pack 8 sage weights (H x H) into B-frag order
struct SPack { const float* w[8]; };
__global__ __launch_bounds__(256) void pack_sage(SPack sp, unsigned short* __restrict__ out) {
    const int n = 8 * 16384;
    for (int i = blockIdx.x * 256 + threadIdx.x; i < n; i += gridDim.x * 256) {
        int j = i & 7, lane = (i >> 3) & 63;
        int kg = (i >> 9) & 3, t = (i >> 11) & 7, wsel = i >> 14;
        int ln = lane & 15, lq = lane >> 4;
        out[i] = f2b(sp.w[wsel][(t * 16 + ln) * H + kg * 32 + lq * 8 + j]);
    }
}

// ---------------------------------------------------------------- CSR build
__global__ __launch_bounds__(256) void deg_kernel(const int* __restrict__ ei,
                                                  int* rp_m, int* rp_u) {
    for (int i = blockIdx.x * 256 + threadIdx.x; i < NE; i += gridDim.x * 256) {
        int u = ei[i], m = ei[NE + i];
        atomicAdd(&rp_u[u + 1], 1);
        atomicAdd(&rp_m[m + 1], 1);
    }
}

__global__ __launch_bounds__(256) void scan2_kernel(int* rp_m, int n_m,
                                                    int* rp_u, int n_u) {
    int* a = (blockIdx.x == 0) ? rp_m : rp_u;
    int n  = (blockIdx.x == 0) ? n_m : n_u;
    __shared__ int s[256];
    __shared__ int carry;
    int tid = threadIdx.x;
    if (tid == 0) carry = 0;
    __syncthreads();
    for (int base = 0; base < n; base += 4096) {
        int v[16];
        int run = 0;
        int i0 = base + tid * 16;
#pragma unroll
        for (int i = 0; i < 16; ++i) {
            int x = (i0 + i < n) ? a[i0 + i] : 0;
            run += x; v[i] = run;
        }
        s[tid] = run;
        __syncthreads();
        for (int off = 1; off < 256; off <<= 1) {
            int t = (tid >= off) ? s[tid - off] : 0;
            __syncthreads();
            s[tid] += t;
            __syncthreads();
        }
        int prev = carry + (tid > 0 ? s[tid - 1] : 0);
#pragma unroll
        for (int i = 0; i < 16; ++i)
            if (i0 + i < n) a[i0 + i] = v[i] + prev;
        int total = s[255];
        __syncthreads();
        if (tid == 0) carry += total;
        __syncthreads();
    }
}

__global__ __launch_bounds__(256) void bucket_kernel(const int* __restrict__ ei,
        const int* __restrict__ rp_m, const int* __restrict__ rp_u,
        int* cur_m, int* cur_u, int* es_m, int* es_u) {
    for (int i = blockIdx.x * 256 + threadIdx.x; i < NE; i += gridDim.x * 256) {
        int u = ei[i], m = ei[NE + i];
        int pm = atomicAdd(&cur_m[m], 1);
        es_m[rp_m[m] + pm] = u;
        int pu = atomicAdd(&cur_u[u], 1);
        es_u[rp_u[u] + pu] = m;
    }
}

// ---------------------------------------------------------------- projection (Linear + BN(eval) + ReLU) -> bf16
template <int K>
__global__ __launch_bounds__(256, 2) void proj_kernel(
        const float* __restrict__ x, const float* __restrict__ Wt,
        const float* __restrict__ lb, const float* __restrict__ g,
        const float* __restrict__ bb, const float* __restrict__ bm,
        const float* __restrict__ bv, unsigned short* __restrict__ out, int N) {
    __shared__ float sA[64 * K];
    const int tid = threadIdx.x;
    const int row0 = blockIdx.x * 64;
    constexpr int F4 = K / 4;
#pragma unroll
    for (int i = 0; i < (64 * F4) / 256; ++i) {
        int idx = tid + i * 256;
        int r = idx / F4, c = idx - r * F4;
        int gr = min(row0 + r, N - 1);
        ((float4*)sA)[idx] = ((const float4*)(x + (size_t)gr * K))[c];
    }
    __syncthreads();
    const int h_t = tid & 31, r_t = tid >> 5;
    float acc[8][4] = {};
#pragma unroll 4
    for (int k = 0; k < K; k += 4) {
        float4 w[4];
#pragma unroll
        for (int kk = 0; kk < 4; ++kk)
            w[kk] = *(const float4*)(Wt + (k + kk) * H + h_t * 4);
#pragma unroll
        for (int rr = 0; rr < 8; ++rr) {
            float4 a = *(const float4*)(sA + (r_t * 8 + rr) * K + k);
            acc[rr][0] += a.x * w[0].x + a.y * w[1].x + a.z * w[2].x + a.w * w[3].x;
            acc[rr][1] += a.x * w[0].y + a.y * w[1].y + a.z * w[2].y + a.w * w[3].y;
            acc[rr][2] += a.x * w[0].z + a.y * w[1].z + a.z * w[2].z + a.w * w[3].z;
            acc[rr][3] += a.x * w[0].w + a.y * w[1].w + a.z * w[2].w + a.w * w[3].w;
        }
    }
    const int h = h_t * 4;
    float4 lb4 = *(const float4*)(lb + h);
    float4 g4  = *(const float4*)(g  + h);
    float4 bb4 = *(const float4*)(bb + h);
    float4 m4  = *(const float4*)(bm + h);
    float4 v4  = *(const float4*)(bv + h);
    float sc[4] = { g4.x * rsqrtf(v4.x + 1e-5f), g4.y * rsqrtf(v4.y + 1e-5f),
                    g4.z * rsqrtf(v4.z + 1e-5f), g4.w * rsqrtf(v4.w + 1e-5f) };
    float lbv[4] = { lb4.x, lb4.y, lb4.z, lb4.w };
    float mv[4]  = { m4.x, m4.y, m4.z, m4.w };
    float bbv[4] = { bb4.x, bb4.y, bb4.z, bb4.w };
#pragma unroll
    for (int rr = 0; rr < 8; ++rr) {
        int gr = row0 + r_t * 8 + rr;
        if (gr < N) {
            u16x4 o;
#pragma unroll
            for (int c = 0; c < 4; ++c)
                o[c] = f2b(fmaxf((acc[rr][c] + lbv[c] - mv[c]) * sc[c] + bbv[c], 0.0f));
            *(u16x4*)(out + (size_t)gr * H + h) = o;
        }
    }
}

// ---------------------------------------------------------------- segment mean (bf16 in/out, fp32 acc)
// one WAVE per node. 16 lanes x 16B per row, 4 rows per wave-instruction,
// 16 rows in flight (R2 rewrite: ~57us total win vs 64-lane x 4B layout).
__global__ __launch_bounds__(256) void agg_bf16(
        const unsigned short* __restrict__ srcA, const int* __restrict__ esA,
        const int* __restrict__ rpA, unsigned short* __restrict__ outA, int nA,
        const unsigned short* __restrict__ srcB, const int* __restrict__ esB,
        const int* __restrict__ rpB, unsigned short* __restrict__ outB, int nB) {
    int wid = blockIdx.x * 4 + (threadIdx.x >> 6);
    const int lane = threadIdx.x & 63;
    const unsigned short* src; const int* es; const int* rp; unsigned short* out; int n;
    if (wid < nA) { src = srcA; es = esA; rp = rpA; out = outA; n = wid; }
    else {
        wid -= nA;
        if (wid >= nB) return;
        src = srcB; es = esB; rp = rpB; out = outB; n = wid;
    }
    const int start = rp[n], end = rp[n + 1];
    const int cb = (lane & 15) * 8;   // col base (8 bf16 = 16B)
    const int ro = lane >> 4;         // row slot 0..3
    float acc[8] = {};
    if (end > start) {
        int j = start;
        for (; j + 16 <= end; j += 16) {   // 16 rows in flight
            u16x8 v0 = *(const u16x8*)(src + (size_t)es[j +      ro] * H + cb);
            u16x8 v1 = *(const u16x8*)(src + (size_t)es[j +  4 + ro] * H + cb);
            u16x8 v2 = *(const u16x8*)(src + (size_t)es[j +  8 + ro] * H + cb);
            u16x8 v3 = *(const u16x8*)(src + (size_t)es[j + 12 + ro] * H + cb);
#pragma unroll
            for (int e = 0; e < 8; ++e)
                acc[e] += b2f(v0[e]) + b2f(v1[e]) + b2f(v2[e]) + b2f(v3[e]);
        }
        for (; j + 4 <= end; j += 4) {
            u16x8 v = *(const u16x8*)(src + (size_t)es[j + ro] * H + cb);
#pragma unroll
            for (int e = 0; e < 8; ++e) acc[e] += b2f(v[e]);
        }
        if (j < end) {   // tail 1..3 rows: masked batch (clamped index, end>start)
            int idx = j + ro;
            int row = es[idx < end ? idx : end - 1];
            float m = (idx < end) ? 1.0f : 0.0f;
            u16x8 v = *(const u16x8*)(src + (size_t)row * H + cb);
#pragma unroll
            for (int e = 0; e < 8; ++e) acc[e] = fmaf(m, b2f(v[e]), acc[e]);
        }
    }
#pragma unroll
    for (int e = 0; e < 8; ++e) {
        acc[e] += __shfl_xor(acc[e], 16);
        acc[e] += __shfl_xor(acc[e], 32);
    }
    float inv = (end > start) ? 1.0f / (float)(end - start) : 0.0f;
    if (ro == 0) {
        u16x8 o;
#pragma unroll
        for (int e = 0; e < 8; ++e) o[e] = f2b(acc[e] * inv);
        *(u16x8*)(out + (size_t)n * H + cb) = o;
    }
}

// ---------------------------------------------------------------- SAGE via MFMA
__global__ __launch_bounds__(256, 4) void sage_mfma(
        const unsigned short* __restrict__ aggA, const unsigned short* __restrict__ xA,
        const unsigned short* __restrict__ WlA, const unsigned short* __restrict__ WrA,
        const float* __restrict__ blA, unsigned short* __restrict__ outA, int NA, int NBLKA,
        const unsigned short* __restrict__ aggB, const unsigned short* __restrict__ xB,
        const unsigned short* __restrict__ WlB, const unsigned short* __restrict__ WrB,
        const float* __restrict__ blB, unsigned short* __restrict__ outB, int NB,
        int relu) {
    __shared__ unsigned short sAg[64 * 16 * 8];  // 16 KB
    __shared__ unsigned short sX[64 * 16 * 8];   // 16 KB
    const int tid = threadIdx.x;
    const unsigned short *agg, *x, *Wl, *Wr; const float* bl; unsigned short* out;
    int N, row0;
    if ((int)blockIdx.x < NBLKA) {
        agg = aggA; x = xA; Wl = WlA; Wr = WrA; bl = blA; out = outA; N = NA;
        row0 = blockIdx.x * 64;
    } else {
        agg = aggB; x = xB; Wl = WlB; Wr = WrB; bl = blB; out = outB; N = NB;
        row0 = (blockIdx.x - NBLKA) * 64;
    }
#pragma unroll
    for (int i = 0; i < 4; ++i) {
        int idx = tid + i * 256;           // 1024 chunks
        int r = idx >> 4, c = idx & 15;
        int gr = min(row0 + r, N - 1);
        *(u16x8*)(sAg + SH1CH(r, c) * 8) = *(const u16x8*)(agg + (size_t)gr * H + c * 8);
        *(u16x8*)(sX  + SH1CH(r, c) * 8) = *(const u16x8*)(x   + (size_t)gr * H + c * 8);
    }
    __syncthreads();
    const int lane = tid & 63, w = tid >> 6;
    const int ln = lane & 15, lq = lane >> 4;
    floatx4 acc[2][4] = {};
#pragma unroll 2
    for (int kg = 0; kg < 4; ++kg) {
        bf16x8 aA[4], aX[4];
#pragma unroll
        for (int mt = 0; mt < 4; ++mt) {
            aA[mt] = *(const bf16x8*)(sAg + SH1CH(mt * 16 + ln, kg * 4 + lq) * 8);
            aX[mt] = *(const bf16x8*)(sX  + SH1CH(mt * 16 + ln, kg * 4 + lq) * 8);
        }
#pragma unroll
        for (int nt = 0; nt < 2; ++nt) {
            int widx = ((w * 2 + nt) * 4 + kg) * 512 + lane * 8;
            bf16x8 bL = *(const bf16x8*)(Wl + widx);
            bf16x8 bR = *(const bf16x8*)(Wr + widx);
#pragma unroll
            for (int mt = 0; mt < 4; ++mt) {
                acc[nt][mt] = __builtin_amdgcn_mfma_f32_16x16x32_bf16(aA[mt], bL, acc[nt][mt], 0, 0, 0);
                acc[nt][mt] = __builtin_amdgcn_mfma_f32_16x16x32_bf16(aX[mt], bR, acc[nt][mt], 0, 0, 0);
            }
        }
    }
    __syncthreads();   // done reading sAg; reuse it for output staging
    {
#pragma unroll
        for (int nt = 0; nt < 2; ++nt) {
            int ncol = w * 32 + nt * 16 + ln;   // 0..127
            float bv = bl[ncol];
            int cch = ncol >> 3, coff = ncol & 7;
#pragma unroll
            for (int mt = 0; mt < 4; ++mt)
#pragma unroll
                for (int i = 0; i < 4; ++i) {
                    int row = mt * 16 + lq * 4 + i;
                    float v = acc[nt][mt][i] + bv;
                    if (relu) v = fmaxf(v, 0.0f);
                    sAg[SH1CH(row, cch) * 8 + coff] = f2b(v);
                }
        }
    }
    __syncthreads();
#pragma unroll
    for (int i = 0; i < 4; ++i) {
        int idx = tid + i * 256;
        int r = idx >> 4, c = idx & 15;
        int gr = row0 + r;
        if (gr < N)
            *(u16x8*)(out + (size_t)gr * H + c * 8) = *(const u16x8*)(sAg + SH1CH(r, c) * 8);
    }
}

// ---------------------------------------------------------------- fused edge decoder MLP — kh-split + nt-split, M=64
// kh-split h1: for kh in {0,1}: phase1 computes h1 cols [kh*256,+256) into a
// 32 KB half-buffer, phase2 accumulates that K-range into persistent acc3.
// R6: phase 1 is nt-SPLIT (two sequential 16-col tiles, each with its own
// acc1[4] and immediate epilogue) so only 16 acc1 regs are live beside the
// 32 persistent acc3 regs — R5's fused-nt version (32+32 live) spilled at
// the (512,4)=128 unified budget (FETCH 106->528 MB). Costs +32 fb LDS
// reads/wave/kh; removes ~1.3 GB scratch traffic.
// Layer 3 fused into phase-2 registers (R1): no LDS h2, no bf16 round-trip.
__global__ __launch_bounds__(512, 4) void decoder_mfma(
        const unsigned short* __restrict__ zu, const unsigned short* __restrict__ zm,
        const int* __restrict__ eli,
        const unsigned short* __restrict__ W1p, const float* __restrict__ b1,
        const unsigned short* __restrict__ W2p, const float* __restrict__ b2,
        const float* __restrict__ W3, const float* __restrict__ b3,
        float* __restrict__ out) {
    __shared__ unsigned short sF[MROW * 32 * 8];   // feat 64x256 bf16 rotated (32 KB), later f32 partials
    __shared__ unsigned short sH1[MROW * 32 * 8];  // h1 HALF 64x256 bf16 rotated (32 KB)
    const int tid = threadIdx.x;
    const int row0 = blockIdx.x * MROW;
    // ---- gather feat = [zu[eu] | zm[em]] (bf16 straight copy); 8 threads/row, 64 rows
    {
        int r = tid >> 3, p = tid & 7;
        int rg = min(row0 + r, NL - 1);
        int iu = eli[rg], im = eli[NL + rg];
        const unsigned short* zur = zu + (size_t)iu * H;
        const unsigned short* zmr = zm + (size_t)im * H;
#pragma unroll
        for (int j = 0; j < 4; ++j) {
            int c = p + j * 8;   // 0..31
            const unsigned short* s = (c < 16) ? (zur + c * 8) : (zmr + (c - 16) * 8);
            *(u16x8*)(sF + SFCH(r, c) * 8) = *(const u16x8*)s;
        }
    }
    __syncthreads();
    const int lane = tid & 63, w = tid >> 6;   // 8 waves
    const int ln = lane & 15, lq = lane >> 4;
    floatx4 acc3[2][4] = {};   // h2 accumulator, persists across kh halves
#pragma unroll
    for (int kh = 0; kh < 2; ++kh) {
        // ---- phase 1 (kh): h1^T cols [kh*256,+256); wave w owns local cols [w*32,+32).
        // nt-split: one 16-col tile at a time -> acc1 live = 16 regs.
#pragma unroll
        for (int nt = 0; nt < 2; ++nt) {
            floatx4 acc1[4] = {};
            const unsigned short* w1b = W1p + (size_t)((kh * 16 + w * 2 + nt) * 8) * 512 + lane * 8;
            for (int kg = 0; kg < 8; ++kg) {
                bf16x8 wa = *(const bf16x8*)(w1b + (size_t)kg * 512);
#pragma unroll
                for (int mt = 0; mt < 4; ++mt) {
                    bf16x8 fb = *(const bf16x8*)(sF + SFCH(mt * 16 + ln, kg * 4 + lq) * 8);
                    acc1[mt] = __builtin_amdgcn_mfma_f32_16x16x32_bf16(wa, fb, acc1[mt], 0, 0, 0);
                }
            }
            // epilogue (this nt): ReLU(acc1 + b1) -> sH1 half-buffer (local cols)
            int colbase = w * 32 + nt * 16 + lq * 4;   // local h1 col of reg 0
            float4 bv = *(const float4*)(b1 + kh * 256 + colbase);
            int cch = colbase >> 3, coff = colbase & 7;   // coff = (lq&1)*4
#pragma unroll
            for (int mt = 0; mt < 4; ++mt) {
                int erow = mt * 16 + ln;
                u16x4 o = { f2b(fmaxf(acc1[mt][0] + bv.x, 0.0f)),
                            f2b(fmaxf(acc1[mt][1] + bv.y, 0.0f)),
                            f2b(fmaxf(acc1[mt][2] + bv.z, 0.0f)),
                            f2b(fmaxf(acc1[mt][3] + bv.w, 0.0f)) };
                *(u16x4*)(sH1 + SFCH(erow, cch) * 8 + coff) = o;
            }
        }
        __syncthreads();
        // ---- phase 2 (kh): acc3 += W2[:, kh*256:+256] · h1half^T; wave w owns h2 cols [w*32,+32)
        {
            const unsigned short* w2base = W2p + (size_t)((w * 2) * 16 + kh * 8) * 512 + lane * 8;
            for (int kg = 0; kg < 8; ++kg) {
                bf16x8 wa0 = *(const bf16x8*)(w2base + (size_t)kg * 512);
                bf16x8 wa1 = *(const bf16x8*)(w2base + (size_t)(16 + kg) * 512);
#pragma unroll
                for (int mt = 0; mt < 4; ++mt) {
                    bf16x8 hb = *(const bf16x8*)(sH1 + SFCH(mt * 16 + ln, kg * 4 + lq) * 8);
                    acc3[0][mt] = __builtin_amdgcn_mfma_f32_16x16x32_bf16(wa0, hb, acc3[0][mt], 0, 0, 0);
                    acc3[1][mt] = __builtin_amdgcn_mfma_f32_16x16x32_bf16(wa1, hb, acc3[1][mt], 0, 0, 0);
                }
            }
        }
        if (kh == 0) __syncthreads();   // all reads of sH1 half done before kh=1 overwrites
    }
    // ---- fused layer 3: per-lane partial dot over this lane's 8 h2 cols
    // (ReLU + b2 applied in fp32 registers; sF free: last read was P1(kh=1), barrier since)
    float* sP = (float*)sF;   // 64 x 36 f32 partials (9.2 KB, stride 36 -> <=2-way banks)
    {
        float4 w3a = *(const float4*)(W3 + w * 32 + lq * 4);
        float4 w3b = *(const float4*)(W3 + w * 32 + 16 + lq * 4);
        float4 b2a = *(const float4*)(b2 + w * 32 + lq * 4);
        float4 b2b = *(const float4*)(b2 + w * 32 + 16 + lq * 4);
#pragma unroll
        for (int mt = 0; mt < 4; ++mt) {
            float s =
                fmaxf(acc3[0][mt][0] + b2a.x, 0.0f) * w3a.x +
                fmaxf(acc3[0][mt][1] + b2a.y, 0.0f) * w3a.y +
                fmaxf(acc3[0][mt][2] + b2a.z, 0.0f) * w3a.z +
                fmaxf(acc3[0][mt][3] + b2a.w, 0.0f) * w3a.w +
                fmaxf(acc3[1][mt][0] + b2b.x, 0.0f) * w3b.x +
                fmaxf(acc3[1][mt][1] + b2b.y, 0.0f) * w3b.y +
                fmaxf(acc3[1][mt][2] + b2b.z, 0.0f) * w3b.z +
                fmaxf(acc3[1][mt][3] + b2b.w, 0.0f) * w3b.w;
            sP[(mt * 16 + ln) * 36 + w * 4 + lq] = s;
        }
    }
    __syncthreads();
    // ---- reduce 32 partials per edge row: 8 threads/row, float4 each, shfl
    {
        int r = tid >> 3, p = tid & 7;   // 64 rows x 8 threads
        float4 v = *(const float4*)(sP + r * 36 + p * 4);
        float sum = v.x + v.y + v.z + v.w;
        sum += __shfl_down(sum, 4, 8);
        sum += __shfl_down(sum, 2, 8);
        sum += __shfl_down(sum, 1, 8);
        if (p == 0 && row0 + r < NL) out[row0 + r] = sum + b3[0];
    }
}

// ---------------------------------------------------------------- host
extern "C" void kernel_launch(void* const* d_in, const int* in_sizes, int n_in,
                              void* d_out, int out_size, void* d_ws, size_t ws_size,
                              hipStream_t stream) {
    const float* x_user  = (const float*)d_in[0];
    const float* x_movie = (const float*)d_in[1];
    const int*   ei      = (const int*)d_in[2];
    const int*   eli     = (const int*)d_in[3];
    const float* lin_u_W = (const float*)d_in[4];
    const float* lin_u_b = (const float*)d_in[5];
    const float* lin_m_W = (const float*)d_in[6];
    const float* lin_m_b = (const float*)d_in[7];
    const float* bn_u_g  = (const float*)d_in[8];
    const float* bn_u_b  = (const float*)d_in[9];
    const float* bn_u_m  = (const float*)d_in[10];
    const float* bn_u_v  = (const float*)d_in[11];
    const float* bn_m_g  = (const float*)d_in[12];
    const float* bn_m_b  = (const float*)d_in[13];
    const float* bn_m_m  = (const float*)d_in[14];
    const float* bn_m_v  = (const float*)d_in[15];
    const float* c1_um_Wl = (const float*)d_in[16];
    const float* c1_um_bl = (const float*)d_in[17];
    const float* c1_um_Wr = (const float*)d_in[18];
    const float* c1_mu_Wl = (const float*)d_in[19];
    const float* c1_mu_bl = (const float*)d_in[20];
    const float* c1_mu_Wr = (const float*)d_in[21];
    const float* c2_um_Wl = (const float*)d_in[22];
    const float* c2_um_bl = (const float*)d_in[23];
    const float* c2_um_Wr = (const float*)d_in[24];
    const float* c2_mu_Wl = (const float*)d_in[25];
    const float* c2_mu_bl = (const float*)d_in[26];
    const float* c2_mu_Wr = (const float*)d_in[27];
    const float* dec_W1 = (const float*)d_in[28];
    const float* dec_b1 = (const float*)d_in[29];
    const float* dec_W2 = (const float*)d_in[30];
    const float* dec_b2 = (const float*)d_in[31];
    const float* dec_W3 = (const float*)d_in[32];
    const float* dec_b3 = (const float*)d_in[33];

    char* base = (char*)d_ws;
    size_t off = 0;
    auto alloc = [&](size_t bytes) -> char* {
        char* p = base + off;
        off += (bytes + 255) & ~(size_t)255;
        return p;
    };
    unsigned short* xu_b  = (unsigned short*)alloc((size_t)NU * H * 2);
    unsigned short* xm_b  = (unsigned short*)alloc((size_t)NM * H * 2);
    unsigned short* xu1_b = (unsigned short*)alloc((size_t)NU * H * 2);
    unsigned short* xm1_b = (unsigned short*)alloc((size_t)NM * H * 2);
    unsigned short* aggu  = (unsigned short*)alloc((size_t)NU * H * 2);
    unsigned short* aggm  = (unsigned short*)alloc((size_t)NM * H * 2);
    float* wt_u = (float*)alloc((size_t)64 * H * 4);
    float* wt_m = (float*)alloc((size_t)H * H * 4);
    unsigned short* wsg = (unsigned short*)alloc((size_t)8 * 16384 * 2);  // packed sage weights
    unsigned short* w1p = (unsigned short*)alloc((size_t)512 * 256 * 2);
    unsigned short* w2p = (unsigned short*)alloc((size_t)256 * 512 * 2);
    int* rp_m  = (int*)alloc((size_t)(NM + 1) * 4);
    int* rp_u  = (int*)alloc((size_t)(NU + 1) * 4);
    int* cur_m = (int*)alloc((size_t)NM * 4);
    int* cur_u = (int*)alloc((size_t)NU * 4);
    int* es_m  = (int*)alloc((size_t)NE * 4);
    int* es_u  = (int*)alloc((size_t)NE * 4);
    unsigned short* zu = xu_b;   // xu_b dead after conv1 sage -> reuse
    unsigned short* zm = xm_b;

    // zero CSR meta (rp_m .. cur_u incl. padding)
    hipMemsetAsync(rp_m, 0, (size_t)((char*)es_m - (char*)rp_m), stream);

    TPack tp;
    tp.t[0] = { lin_u_W, wt_u, H, 64 };
    tp.t[1] = { lin_m_W, wt_m, H, H };
    transpose_all<<<dim3(64, 2), 256, 0, stream>>>(tp);
    pack_weights<<<256, 256, 0, stream>>>(dec_W1, dec_W2, w1p, w2p);
    SPack sp;
    sp.w[0] = c1_um_Wl; sp.w[1] = c1_um_Wr; sp.w[2] = c1_mu_Wl; sp.w[3] = c1_mu_Wr;
    sp.w[4] = c2_um_Wl; sp.w[5] = c2_um_Wr; sp.w[6] = c2_mu_Wl; sp.w[7] = c2_mu_Wr;
    pack_sage<<<128, 256, 0, stream>>>(sp, wsg);
    const unsigned short* W_c1um_l = wsg + 0 * 16384;
    const unsigned short* W_c1um_r = wsg + 1 * 16384;
    const unsigned short* W_c1mu_l = wsg + 2 * 16384;
    const unsigned short* W_c1mu_r = wsg + 3 * 16384;
    const unsigned short* W_c2um_l = wsg + 4 * 16384;
    const unsigned short* W_c2um_r = wsg + 5 * 16384;
    const unsigned short* W_c2mu_l = wsg + 6 * 16384;
    const unsigned short* W_c2mu_r = wsg + 7 * 16384;

    deg_kernel<<<2048, 256, 0, stream>>>(ei, rp_m, rp_u);
    scan2_kernel<<<2, 256, 0, stream>>>(rp_m, NM + 1, rp_u, NU + 1);
    bucket_kernel<<<2048, 256, 0, stream>>>(ei, rp_m, rp_u, cur_m, cur_u, es_m, es_u);

    proj_kernel<64><<<(NU + 63) / 64, 256, 0, stream>>>(
        x_user, wt_u, lin_u_b, bn_u_g, bn_u_b, bn_u_m, bn_u_v, xu_b, NU);
    proj_kernel<128><<<(NM + 63) / 64, 256, 0, stream>>>(
        x_movie, wt_m, lin_m_b, bn_m_g, bn_m_b, bn_m_m, bn_m_v, xm_b, NM);

    const int AGG_BLOCKS = (NM + NU + 3) / 4;
    const int NBLK_M = (NM + 63) / 64, NBLK_U = (NU + 63) / 64;

    // conv1
    agg_bf16<<<AGG_BLOCKS, 256, 0, stream>>>(xu_b, es_m, rp_m, aggm, NM,
                                             xm_b, es_u, rp_u, aggu, NU);
    sage_mfma<<<NBLK_M + NBLK_U, 256, 0, stream>>>(
        aggm, xm_b, W_c1um_l, W_c1um_r, c1_um_bl, xm1_b, NM, NBLK_M,
        aggu, xu_b, W_c1mu_l, W_c1mu_r, c1_mu_bl, xu1_b, NU, 1);
    // conv2
    agg_bf16<<<AGG_BLOCKS, 256, 0, stream>>>(xu1_b, es_m, rp_m, aggm, NM,
                                             xm1_b, es_u, rp_u, aggu, NU);
    sage_mfma<<<NBLK_M + NBLK_U, 256, 0, stream>>>(
        aggm, xm1_b, W_c2um_l, W_c2um_r, c2_um_bl, zm, NM, NBLK_M,
        aggu, xu1_b, W_c2mu_l, W_c2mu_r, c2_mu_bl, zu, NU, 0);

    // decoder (bf16 MFMA, kh-split + nt-split, fused layer-3, M=64, 64 KB LDS -> 2 blk/CU)
    decoder_mfma<<<(NL + MROW - 1) / MROW, 512, 0, stream>>>(
        zu, zm, eli, w1p, dec_b1, w2p, dec_b2, dec_W3, dec_b3, (float*)d_out);
}

// Round 7
// 1194.224 us; speedup vs baseline: 1.1985x; 1.1460x over previous
//
#include <hip/hip_runtime.h>

#define NU 100000
#define NM 20000
#define NE 2000000
#define NL 500000
#define H  128
#define MROW 48   // decoder rows/block: 72 KB LDS -> 2 blocks/CU. PROVEN config (R2:
                  // 293us, VGPR 52, no spill). M=64/kh-split attempts (R4-R6) all spilled
                  // ~40 dwords/thread (FETCH 106->500+ MB, WRITE 2->700 MB) regardless of
                  // accumulator live-range splitting — cause not identifiable without
                  // disasm; reverted. M=32 regressed via 1.5x weight L2 traffic (R3).

typedef __attribute__((ext_vector_type(8))) short bf16x8;            // 8 bf16 (4 VGPRs)
typedef __attribute__((ext_vector_type(4))) float floatx4;           // 4 fp32 acc
typedef __attribute__((ext_vector_type(8))) unsigned short u16x8;    // 16B load/store
typedef __attribute__((ext_vector_type(4))) unsigned short u16x4;    // 8B store

// Native bf16 convert (RNE) — lowers to v_cvt_pk_bf16_f32 on gfx950.
__device__ __forceinline__ unsigned short f2b(float x) {
    union { __bf16 h; unsigned short u; } v;
    v.h = (__bf16)x;
    return v.u;
}
__device__ __forceinline__ float b2f(unsigned short h) {
    union { unsigned u; float f; } v; v.u = ((unsigned)h) << 16;
    return v.f;
}

// rotated LDS chunk addressing (chunk = 16B = 8 bf16), zero-waste bank pad.
// NOTE (R2): residual SQ_LDS_BANK_CONFLICT (~2.8e7) is inherent b128 wide-op
// serialization at full LDS BW, not a fixable conflict.
#define SFCH(r, c)  ((r) * 32 + (((c) + (r)) & 31))   // rows x 32 chunks (256 cols)
#define SH1CH(r, c) ((r) * 16 + (((c) + (r)) & 15))   // rows x 16 chunks (128 cols)
#define SH2CH(r, c) ((r) * 64 + (((c) + (r)) & 63))   // rows x 64 chunks (512 cols)

// ---------------------------------------------------------------- transpose (proj weights only)
struct TDesc { const float* s; float* d; int R; int C; };
struct TPack { TDesc t[2]; };

__global__ __launch_bounds__(256) void transpose_all(TPack p) {
    TDesc d = p.t[blockIdx.y];
    int n = d.R * d.C;
    for (int i = blockIdx.x * 256 + threadIdx.x; i < n; i += gridDim.x * 256) {
        int r = i / d.C, c = i - r * d.C;
        d.d[c * d.R + r] = d.s[i];  // dst[k][h] = src[h][k]
    }
}

// ---------------------------------------------------------------- pack decoder weights into MFMA frag order
// (A-fragment and B-fragment lane layouts are identical for 16x16x32)
__global__ __launch_bounds__(256) void pack_weights(const float* __restrict__ W1,
                                                    const float* __restrict__ W2,
                                                    unsigned short* __restrict__ W1p,
                                                    unsigned short* __restrict__ W2p) {
    const int n = 512 * 256;
    for (int i = blockIdx.x * 256 + threadIdx.x; i < n; i += gridDim.x * 256) {
        int j = i & 7, lane = (i >> 3) & 63;
        int ln = lane & 15, lq = lane >> 4;
        int kg1 = (i >> 9) & 7,  t1 = i >> 12;
        W1p[i] = f2b(W1[(t1 * 16 + ln) * 256 + kg1 * 32 + lq * 8 + j]);
        int kg2 = (i >> 9) & 15, t2 = i >> 13;
        W2p[i] = f2b(W2[(t2 * 16 + ln) * 512 + kg2 * 32 + lq * 8 + j]);
    }
}

// ---------------------------------------------------------------- pack 8 sage weights (H x H) into B-frag order
struct SPack { const float* w[8]; };
__global__ __launch_bounds__(256) void pack_sage(SPack sp, unsigned short* __restrict__ out) {
    const int n = 8 * 16384;
    for (int i = blockIdx.x * 256 + threadIdx.x; i < n; i += gridDim.x * 256) {
        int j = i & 7, lane = (i >> 3) & 63;
        int kg = (i >> 9) & 3, t = (i >> 11) & 7, wsel = i >> 14;
        int ln = lane & 15, lq = lane >> 4;
        out[i] = f2b(sp.w[wsel][(t * 16 + ln) * H + kg * 32 + lq * 8 + j]);
    }
}

// ---------------------------------------------------------------- CSR build
__global__ __launch_bounds__(256) void deg_kernel(const int* __restrict__ ei,
                                                  int* rp_m, int* rp_u) {
    for (int i = blockIdx.x * 256 + threadIdx.x; i < NE; i += gridDim.x * 256) {
        int u = ei[i], m = ei[NE + i];
        atomicAdd(&rp_u[u + 1], 1);
        atomicAdd(&rp_m[m + 1], 1);
    }
}

__global__ __launch_bounds__(256) void scan2_kernel(int* rp_m, int n_m,
                                                    int* rp_u, int n_u) {
    int* a = (blockIdx.x == 0) ? rp_m : rp_u;
    int n  = (blockIdx.x == 0) ? n_m : n_u;
    __shared__ int s[256];
    __shared__ int carry;
    int tid = threadIdx.x;
    if (tid == 0) carry = 0;
    __syncthreads();
    for (int base = 0; base < n; base += 4096) {
        int v[16];
        int run = 0;
        int i0 = base + tid * 16;
#pragma unroll
        for (int i = 0; i < 16; ++i) {
            int x = (i0 + i < n) ? a[i0 + i] : 0;
            run += x; v[i] = run;
        }
        s[tid] = run;
        __syncthreads();
        for (int off = 1; off < 256; off <<= 1) {
            int t = (tid >= off) ? s[tid - off] : 0;
            __syncthreads();
            s[tid] += t;
            __syncthreads();
        }
        int prev = carry + (tid > 0 ? s[tid - 1] : 0);
#pragma unroll
        for (int i = 0; i < 16; ++i)
            if (i0 + i < n) a[i0 + i] = v[i] + prev;
        int total = s[255];
        __syncthreads();
        if (tid == 0) carry += total;
        __syncthreads();
    }
}

__global__ __launch_bounds__(256) void bucket_kernel(const int* __restrict__ ei,
        const int* __restrict__ rp_m, const int* __restrict__ rp_u,
        int* cur_m, int* cur_u, int* es_m, int* es_u) {
    for (int i = blockIdx.x * 256 + threadIdx.x; i < NE; i += gridDim.x * 256) {
        int u = ei[i], m = ei[NE + i];
        int pm = atomicAdd(&cur_m[m], 1);
        es_m[rp_m[m] + pm] = u;
        int pu = atomicAdd(&cur_u[u], 1);
        es_u[rp_u[u] + pu] = m;
    }
}

// ---------------------------------------------------------------- projection (Linear + BN(eval) + ReLU) -> bf16
template <int K>
__global__ __launch_bounds__(256, 2) void proj_kernel(
        const float* __restrict__ x, const float* __restrict__ Wt,
        const float* __restrict__ lb, const float* __restrict__ g,
        const float* __restrict__ bb, const float* __restrict__ bm,
        const float* __restrict__ bv, unsigned short* __restrict__ out, int N) {
    __shared__ float sA[64 * K];
    const int tid = threadIdx.x;
    const int row0 = blockIdx.x * 64;
    constexpr int F4 = K / 4;
#pragma unroll
    for (int i = 0; i < (64 * F4) / 256; ++i) {
        int idx = tid + i * 256;
        int r = idx / F4, c = idx - r * F4;
        int gr = min(row0 + r, N - 1);
        ((float4*)sA)[idx] = ((const float4*)(x + (size_t)gr * K))[c];
    }
    __syncthreads();
    const int h_t = tid & 31, r_t = tid >> 5;
    float acc[8][4] = {};
#pragma unroll 4
    for (int k = 0; k < K; k += 4) {
        float4 w[4];
#pragma unroll
        for (int kk = 0; kk < 4; ++kk)
            w[kk] = *(const float4*)(Wt + (k + kk) * H + h_t * 4);
#pragma unroll
        for (int rr = 0; rr < 8; ++rr) {
            float4 a = *(const float4*)(sA + (r_t * 8 + rr) * K + k);
            acc[rr][0] += a.x * w[0].x + a.y * w[1].x + a.z * w[2].x + a.w * w[3].x;
            acc[rr][1] += a.x * w[0].y + a.y * w[1].y + a.z * w[2].y + a.w * w[3].y;
            acc[rr][2] += a.x * w[0].z + a.y * w[1].z + a.z * w[2].z + a.w * w[3].z;
            acc[rr][3] += a.x * w[0].w + a.y * w[1].w + a.z * w[2].w + a.w * w[3].w;
        }
    }
    const int h = h_t * 4;
    float4 lb4 = *(const float4*)(lb + h);
    float4 g4  = *(const float4*)(g  + h);
    float4 bb4 = *(const float4*)(bb + h);
    float4 m4  = *(const float4*)(bm + h);
    float4 v4  = *(const float4*)(bv + h);
    float sc[4] = { g4.x * rsqrtf(v4.x + 1e-5f), g4.y * rsqrtf(v4.y + 1e-5f),
                    g4.z * rsqrtf(v4.z + 1e-5f), g4.w * rsqrtf(v4.w + 1e-5f) };
    float lbv[4] = { lb4.x, lb4.y, lb4.z, lb4.w };
    float mv[4]  = { m4.x, m4.y, m4.z, m4.w };
    float bbv[4] = { bb4.x, bb4.y, bb4.z, bb4.w };
#pragma unroll
    for (int rr = 0; rr < 8; ++rr) {
        int gr = row0 + r_t * 8 + rr;
        if (gr < N) {
            u16x4 o;
#pragma unroll
            for (int c = 0; c < 4; ++c)
                o[c] = f2b(fmaxf((acc[rr][c] + lbv[c] - mv[c]) * sc[c] + bbv[c], 0.0f));
            *(u16x4*)(out + (size_t)gr * H + h) = o;
        }
    }
}

// ---------------------------------------------------------------- segment mean (bf16 in/out, fp32 acc)
// one WAVE per node. 16 lanes x 16B per row, 4 rows per wave-instruction,
// 16 rows in flight (R2 rewrite: ~57us total win vs 64-lane x 4B layout).
__global__ __launch_bounds__(256) void agg_bf16(
        const unsigned short* __restrict__ srcA, const int* __restrict__ esA,
        const int* __restrict__ rpA, unsigned short* __restrict__ outA, int nA,
        const unsigned short* __restrict__ srcB, const int* __restrict__ esB,
        const int* __restrict__ rpB, unsigned short* __restrict__ outB, int nB) {
    int wid = blockIdx.x * 4 + (threadIdx.x >> 6);
    const int lane = threadIdx.x & 63;
    const unsigned short* src; const int* es; const int* rp; unsigned short* out; int n;
    if (wid < nA) { src = srcA; es = esA; rp = rpA; out = outA; n = wid; }
    else {
        wid -= nA;
        if (wid >= nB) return;
        src = srcB; es = esB; rp = rpB; out = outB; n = wid;
    }
    const int start = rp[n], end = rp[n + 1];
    const int cb = (lane & 15) * 8;   // col base (8 bf16 = 16B)
    const int ro = lane >> 4;         // row slot 0..3
    float acc[8] = {};
    if (end > start) {
        int j = start;
        for (; j + 16 <= end; j += 16) {   // 16 rows in flight
            u16x8 v0 = *(const u16x8*)(src + (size_t)es[j +      ro] * H + cb);
            u16x8 v1 = *(const u16x8*)(src + (size_t)es[j +  4 + ro] * H + cb);
            u16x8 v2 = *(const u16x8*)(src + (size_t)es[j +  8 + ro] * H + cb);
            u16x8 v3 = *(const u16x8*)(src + (size_t)es[j + 12 + ro] * H + cb);
#pragma unroll
            for (int e = 0; e < 8; ++e)
                acc[e] += b2f(v0[e]) + b2f(v1[e]) + b2f(v2[e]) + b2f(v3[e]);
        }
        for (; j + 4 <= end; j += 4) {
            u16x8 v = *(const u16x8*)(src + (size_t)es[j + ro] * H + cb);
#pragma unroll
            for (int e = 0; e < 8; ++e) acc[e] += b2f(v[e]);
        }
        if (j < end) {   // tail 1..3 rows: masked batch (clamped index, end>start)
            int idx = j + ro;
            int row = es[idx < end ? idx : end - 1];
            float m = (idx < end) ? 1.0f : 0.0f;
            u16x8 v = *(const u16x8*)(src + (size_t)row * H + cb);
#pragma unroll
            for (int e = 0; e < 8; ++e) acc[e] = fmaf(m, b2f(v[e]), acc[e]);
        }
    }
#pragma unroll
    for (int e = 0; e < 8; ++e) {
        acc[e] += __shfl_xor(acc[e], 16);
        acc[e] += __shfl_xor(acc[e], 32);
    }
    float inv = (end > start) ? 1.0f / (float)(end - start) : 0.0f;
    if (ro == 0) {
        u16x8 o;
#pragma unroll
        for (int e = 0; e < 8; ++e) o[e] = f2b(acc[e] * inv);
        *(u16x8*)(out + (size_t)n * H + cb) = o;
    }
}

// ---------------------------------------------------------------- SAGE via MFMA
__global__ __launch_bounds__(256, 4) void sage_mfma(
        const unsigned short* __restrict__ aggA, const unsigned short* __restrict__ xA,
        const unsigned short* __restrict__ WlA, const unsigned short* __restrict__ WrA,
        const float* __restrict__ blA, unsigned short* __restrict__ outA, int NA, int NBLKA,
        const unsigned short* __restrict__ aggB, const unsigned short* __restrict__ xB,
        const unsigned short* __restrict__ WlB, const unsigned short* __restrict__ WrB,
        const float* __restrict__ blB, unsigned short* __restrict__ outB, int NB,
        int relu) {
    __shared__ unsigned short sAg[64 * 16 * 8];  // 16 KB
    __shared__ unsigned short sX[64 * 16 * 8];   // 16 KB
    const int tid = threadIdx.x;
    const unsigned short *agg, *x, *Wl, *Wr; const float* bl; unsigned short* out;
    int N, row0;
    if ((int)blockIdx.x < NBLKA) {
        agg = aggA; x = xA; Wl = WlA; Wr = WrA; bl = blA; out = outA; N = NA;
        row0 = blockIdx.x * 64;
    } else {
        agg = aggB; x = xB; Wl = WlB; Wr = WrB; bl = blB; out = outB; N = NB;
        row0 = (blockIdx.x - NBLKA) * 64;
    }
#pragma unroll
    for (int i = 0; i < 4; ++i) {
        int idx = tid + i * 256;           // 1024 chunks
        int r = idx >> 4, c = idx & 15;
        int gr = min(row0 + r, N - 1);
        *(u16x8*)(sAg + SH1CH(r, c) * 8) = *(const u16x8*)(agg + (size_t)gr * H + c * 8);
        *(u16x8*)(sX  + SH1CH(r, c) * 8) = *(const u16x8*)(x   + (size_t)gr * H + c * 8);
    }
    __syncthreads();
    const int lane = tid & 63, w = tid >> 6;
    const int ln = lane & 15, lq = lane >> 4;
    floatx4 acc[2][4] = {};
#pragma unroll 2
    for (int kg = 0; kg < 4; ++kg) {
        bf16x8 aA[4], aX[4];
#pragma unroll
        for (int mt = 0; mt < 4; ++mt) {
            aA[mt] = *(const bf16x8*)(sAg + SH1CH(mt * 16 + ln, kg * 4 + lq) * 8);
            aX[mt] = *(const bf16x8*)(sX  + SH1CH(mt * 16 + ln, kg * 4 + lq) * 8);
        }
#pragma unroll
        for (int nt = 0; nt < 2; ++nt) {
            int widx = ((w * 2 + nt) * 4 + kg) * 512 + lane * 8;
            bf16x8 bL = *(const bf16x8*)(Wl + widx);
            bf16x8 bR = *(const bf16x8*)(Wr + widx);
#pragma unroll
            for (int mt = 0; mt < 4; ++mt) {
                acc[nt][mt] = __builtin_amdgcn_mfma_f32_16x16x32_bf16(aA[mt], bL, acc[nt][mt], 0, 0, 0);
                acc[nt][mt] = __builtin_amdgcn_mfma_f32_16x16x32_bf16(aX[mt], bR, acc[nt][mt], 0, 0, 0);
            }
        }
    }
    __syncthreads();   // done reading sAg; reuse it for output staging
    {
#pragma unroll
        for (int nt = 0; nt < 2; ++nt) {
            int ncol = w * 32 + nt * 16 + ln;   // 0..127
            float bv = bl[ncol];
            int cch = ncol >> 3, coff = ncol & 7;
#pragma unroll
            for (int mt = 0; mt < 4; ++mt)
#pragma unroll
                for (int i = 0; i < 4; ++i) {
                    int row = mt * 16 + lq * 4 + i;
                    float v = acc[nt][mt][i] + bv;
                    if (relu) v = fmaxf(v, 0.0f);
                    sAg[SH1CH(row, cch) * 8 + coff] = f2b(v);
                }
        }
    }
    __syncthreads();
#pragma unroll
    for (int i = 0; i < 4; ++i) {
        int idx = tid + i * 256;
        int r = idx >> 4, c = idx & 15;
        int gr = row0 + r;
        if (gr < N)
            *(u16x8*)(out + (size_t)gr * H + c * 8) = *(const u16x8*)(sAg + SH1CH(r, c) * 8);
    }
}

// ---------------------------------------------------------------- fused edge decoder MLP — 3-phase, M=48 (PROVEN R2 config)
// Layer 3 fused into phase-2 registers (R1). Full h1 in 48 KB LDS; phases
// fully sequential so only one accumulator array is live at a time (48 then
// 24 regs) — 52 VGPR, no spill. kh-split variants (R4-R6) all spilled.
__global__ __launch_bounds__(512, 4) void decoder_mfma(
        const unsigned short* __restrict__ zu, const unsigned short* __restrict__ zm,
        const int* __restrict__ eli,
        const unsigned short* __restrict__ W1p, const float* __restrict__ b1,
        const unsigned short* __restrict__ W2p, const float* __restrict__ b2,
        const float* __restrict__ W3, const float* __restrict__ b3,
        float* __restrict__ out) {
    __shared__ unsigned short sF[MROW * 32 * 8];   // feat 48x256 bf16 rotated (24 KB), later f32 partials
    __shared__ unsigned short sH1[MROW * 64 * 8];  // h1 FULL 48x512 bf16 rotated (48 KB)
    const int tid = threadIdx.x;
    const int row0 = blockIdx.x * MROW;
    // ---- gather feat = [zu[eu] | zm[em]] (bf16 straight copy); 8 threads/row
    {
        int r = tid >> 3, p = tid & 7;
        if (r < MROW) {
            int rg = min(row0 + r, NL - 1);
            int iu = eli[rg], im = eli[NL + rg];
            const unsigned short* zur = zu + (size_t)iu * H;
            const unsigned short* zmr = zm + (size_t)im * H;
#pragma unroll
            for (int j = 0; j < 4; ++j) {
                int c = p + j * 8;   // 0..31
                const unsigned short* s = (c < 16) ? (zur + c * 8) : (zmr + (c - 16) * 8);
                *(u16x8*)(sF + SFCH(r, c) * 8) = *(const u16x8*)s;
            }
        }
    }
    __syncthreads();
    const int lane = tid & 63, w = tid >> 6;   // 8 waves
    const int ln = lane & 15, lq = lane >> 4;
    // ---- phase 1: h1^T = W1 · feat^T ; wave w owns h1 cols [w*64, +64)
    {
        floatx4 acc1[4][3] = {};   // [nt: h1col tile][mt: edge-row tile]
        const unsigned short* w1base = W1p + ((size_t)(w * 4) * 8) * 512 + lane * 8;
#pragma unroll 2
        for (int kg = 0; kg < 8; ++kg) {
            bf16x8 fb[3];   // feat fragments (B operand): B[n=edge row][k]
#pragma unroll
            for (int mt = 0; mt < 3; ++mt)
                fb[mt] = *(const bf16x8*)(sF + SFCH(mt * 16 + ln, kg * 4 + lq) * 8);
#pragma unroll
            for (int nt = 0; nt < 4; ++nt) {
                bf16x8 wa = *(const bf16x8*)(w1base + (size_t)(nt * 8 + kg) * 512);  // A: W1 rows
#pragma unroll
                for (int mt = 0; mt < 3; ++mt)
                    acc1[nt][mt] = __builtin_amdgcn_mfma_f32_16x16x32_bf16(wa, fb[mt], acc1[nt][mt], 0, 0, 0);
            }
        }
        // epilogue: D[row=h1col lq*4+i][col=edge row ln] -> b64 store per (nt,mt)
#pragma unroll
        for (int nt = 0; nt < 4; ++nt) {
            int colbase = w * 64 + nt * 16 + lq * 4;   // h1 col of reg 0
            float4 bv = *(const float4*)(b1 + colbase);
            int cch = colbase >> 3, coff = colbase & 7;   // coff = (lq&1)*4
#pragma unroll
            for (int mt = 0; mt < 3; ++mt) {
                int erow = mt * 16 + ln;
                u16x4 o = { f2b(fmaxf(acc1[nt][mt][0] + bv.x, 0.0f)),
                            f2b(fmaxf(acc1[nt][mt][1] + bv.y, 0.0f)),
                            f2b(fmaxf(acc1[nt][mt][2] + bv.z, 0.0f)),
                            f2b(fmaxf(acc1[nt][mt][3] + bv.w, 0.0f)) };
                *(u16x4*)(sH1 + SH2CH(erow, cch) * 8 + coff) = o;
            }
        }
    }
    __syncthreads();   // also: last read of sF (feat) is above -> safe to overlay later
    // ---- phase 2: h2^T = W2 · h1^T over full K=512; wave w owns h2 cols [w*32,+32)
    floatx4 acc3[2][3] = {};
    {
        const unsigned short* w2base = W2p + ((size_t)(w * 2) * 16) * 512 + lane * 8;
#pragma unroll 2
        for (int kg = 0; kg < 16; ++kg) {
            bf16x8 hb[3];   // h1 fragments (B operand)
#pragma unroll
            for (int mt = 0; mt < 3; ++mt)
                hb[mt] = *(const bf16x8*)(sH1 + SH2CH(mt * 16 + ln, kg * 4 + lq) * 8);
#pragma unroll
            for (int nt = 0; nt < 2; ++nt) {
                bf16x8 wa = *(const bf16x8*)(w2base + (size_t)(nt * 16 + kg) * 512);
#pragma unroll
                for (int mt = 0; mt < 3; ++mt)
                    acc3[nt][mt] = __builtin_amdgcn_mfma_f32_16x16x32_bf16(wa, hb[mt], acc3[nt][mt], 0, 0, 0);
            }
        }
    }
    // ---- fused layer 3: per-lane partial dot over this lane's 8 h2 cols
    // (ReLU + b2 applied in fp32 registers; no bf16 round-trip, no LDS h2)
    float* sP = (float*)sF;   // 48 x 36 f32 partials (6.9 KB, stride 36 -> <=2-way banks)
    {
        float4 w3a = *(const float4*)(W3 + w * 32 + lq * 4);
        float4 w3b = *(const float4*)(W3 + w * 32 + 16 + lq * 4);
        float4 b2a = *(const float4*)(b2 + w * 32 + lq * 4);
        float4 b2b = *(const float4*)(b2 + w * 32 + 16 + lq * 4);
#pragma unroll
        for (int mt = 0; mt < 3; ++mt) {
            float s =
                fmaxf(acc3[0][mt][0] + b2a.x, 0.0f) * w3a.x +
                fmaxf(acc3[0][mt][1] + b2a.y, 0.0f) * w3a.y +
                fmaxf(acc3[0][mt][2] + b2a.z, 0.0f) * w3a.z +
                fmaxf(acc3[0][mt][3] + b2a.w, 0.0f) * w3a.w +
                fmaxf(acc3[1][mt][0] + b2b.x, 0.0f) * w3b.x +
                fmaxf(acc3[1][mt][1] + b2b.y, 0.0f) * w3b.y +
                fmaxf(acc3[1][mt][2] + b2b.z, 0.0f) * w3b.z +
                fmaxf(acc3[1][mt][3] + b2b.w, 0.0f) * w3b.w;
            sP[(mt * 16 + ln) * 36 + w * 4 + lq] = s;
        }
    }
    __syncthreads();
    // ---- reduce 32 partials per edge row: 8 threads/row, float4 each, shfl
    {
        int r = tid >> 3, p = tid & 7;
        if (r < MROW) {
            float4 v = *(const float4*)(sP + r * 36 + p * 4);
            float sum = v.x + v.y + v.z + v.w;
            sum += __shfl_down(sum, 4, 8);
            sum += __shfl_down(sum, 2, 8);
            sum += __shfl_down(sum, 1, 8);
            if (p == 0 && row0 + r < NL) out[row0 + r] = sum + b3[0];
        }
    }
}

// ---------------------------------------------------------------- host
extern "C" void kernel_launch(void* const* d_in, const int* in_sizes, int n_in,
                              void* d_out, int out_size, void* d_ws, size_t ws_size,
                              hipStream_t stream) {
    const float* x_user  = (const float*)d_in[0];
    const float* x_movie = (const float*)d_in[1];
    const int*   ei      = (const int*)d_in[2];
    const int*   eli     = (const int*)d_in[3];
    const float* lin_u_W = (const float*)d_in[4];
    const float* lin_u_b = (const float*)d_in[5];
    const float* lin_m_W = (const float*)d_in[6];
    const float* lin_m_b = (const float*)d_in[7];
    const float* bn_u_g  = (const float*)d_in[8];
    const float* bn_u_b  = (const float*)d_in[9];
    const float* bn_u_m  = (const float*)d_in[10];
    const float* bn_u_v  = (const float*)d_in[11];
    const float* bn_m_g  = (const float*)d_in[12];
    const float* bn_m_b  = (const float*)d_in[13];
    const float* bn_m_m  = (const float*)d_in[14];
    const float* bn_m_v  = (const float*)d_in[15];
    const float* c1_um_Wl = (const float*)d_in[16];
    const float* c1_um_bl = (const float*)d_in[17];
    const float* c1_um_Wr = (const float*)d_in[18];
    const float* c1_mu_Wl = (const float*)d_in[19];
    const float* c1_mu_bl = (const float*)d_in[20];
    const float* c1_mu_Wr = (const float*)d_in[21];
    const float* c2_um_Wl = (const float*)d_in[22];
    const float* c2_um_bl = (const float*)d_in[23];
    const float* c2_um_Wr = (const float*)d_in[24];
    const float* c2_mu_Wl = (const float*)d_in[25];
    const float* c2_mu_bl = (const float*)d_in[26];
    const float* c2_mu_Wr = (const float*)d_in[27];
    const float* dec_W1 = (const float*)d_in[28];
    const float* dec_b1 = (const float*)d_in[29];
    const float* dec_W2 = (const float*)d_in[30];
    const float* dec_b2 = (const float*)d_in[31];
    const float* dec_W3 = (const float*)d_in[32];
    const float* dec_b3 = (const float*)d_in[33];

    char* base = (char*)d_ws;
    size_t off = 0;
    auto alloc = [&](size_t bytes) -> char* {
        char* p = base + off;
        off += (bytes + 255) & ~(size_t)255;
        return p;
    };
    unsigned short* xu_b  = (unsigned short*)alloc((size_t)NU * H * 2);
    unsigned short* xm_b  = (unsigned short*)alloc((size_t)NM * H * 2);
    unsigned short* xu1_b = (unsigned short*)alloc((size_t)NU * H * 2);
    unsigned short* xm1_b = (unsigned short*)alloc((size_t)NM * H * 2);
    unsigned short* aggu  = (unsigned short*)alloc((size_t)NU * H * 2);
    unsigned short* aggm  = (unsigned short*)alloc((size_t)NM * H * 2);
    float* wt_u = (float*)alloc((size_t)64 * H * 4);
    float* wt_m = (float*)alloc((size_t)H * H * 4);
    unsigned short* wsg = (unsigned short*)alloc((size_t)8 * 16384 * 2);  // packed sage weights
    unsigned short* w1p = (unsigned short*)alloc((size_t)512 * 256 * 2);
    unsigned short* w2p = (unsigned short*)alloc((size_t)256 * 512 * 2);
    int* rp_m  = (int*)alloc((size_t)(NM + 1) * 4);
    int* rp_u  = (int*)alloc((size_t)(NU + 1) * 4);
    int* cur_m = (int*)alloc((size_t)NM * 4);
    int* cur_u = (int*)alloc((size_t)NU * 4);
    int* es_m  = (int*)alloc((size_t)NE * 4);
    int* es_u  = (int*)alloc((size_t)NE * 4);
    unsigned short* zu = xu_b;   // xu_b dead after conv1 sage -> reuse
    unsigned short* zm = xm_b;

    // zero CSR meta (rp_m .. cur_u incl. padding)
    hipMemsetAsync(rp_m, 0, (size_t)((char*)es_m - (char*)rp_m), stream);

    TPack tp;
    tp.t[0] = { lin_u_W, wt_u, H, 64 };
    tp.t[1] = { lin_m_W, wt_m, H, H };
    transpose_all<<<dim3(64, 2), 256, 0, stream>>>(tp);
    pack_weights<<<256, 256, 0, stream>>>(dec_W1, dec_W2, w1p, w2p);
    SPack sp;
    sp.w[0] = c1_um_Wl; sp.w[1] = c1_um_Wr; sp.w[2] = c1_mu_Wl; sp.w[3] = c1_mu_Wr;
    sp.w[4] = c2_um_Wl; sp.w[5] = c2_um_Wr; sp.w[6] = c2_mu_Wl; sp.w[7] = c2_mu_Wr;
    pack_sage<<<128, 256, 0, stream>>>(sp, wsg);
    const unsigned short* W_c1um_l = wsg + 0 * 16384;
    const unsigned short* W_c1um_r = wsg + 1 * 16384;
    const unsigned short* W_c1mu_l = wsg + 2 * 16384;
    const unsigned short* W_c1mu_r = wsg + 3 * 16384;
    const unsigned short* W_c2um_l = wsg + 4 * 16384;
    const unsigned short* W_c2um_r = wsg + 5 * 16384;
    const unsigned short* W_c2mu_l = wsg + 6 * 16384;
    const unsigned short* W_c2mu_r = wsg + 7 * 16384;

    deg_kernel<<<2048, 256, 0, stream>>>(ei, rp_m, rp_u);
    scan2_kernel<<<2, 256, 0, stream>>>(rp_m, NM + 1, rp_u, NU + 1);
    bucket_kernel<<<2048, 256, 0, stream>>>(ei, rp_m, rp_u, cur_m, cur_u, es_m, es_u);

    proj_kernel<64><<<(NU + 63) / 64, 256, 0, stream>>>(
        x_user, wt_u, lin_u_b, bn_u_g, bn_u_b, bn_u_m, bn_u_v, xu_b, NU);
    proj_kernel<128><<<(NM + 63) / 64, 256, 0, stream>>>(
        x_movie, wt_m, lin_m_b, bn_m_g, bn_m_b, bn_m_m, bn_m_v, xm_b, NM);

    const int AGG_BLOCKS = (NM + NU + 3) / 4;
    const int NBLK_M = (NM + 63) / 64, NBLK_U = (NU + 63) / 64;

    // conv1
    agg_bf16<<<AGG_BLOCKS, 256, 0, stream>>>(xu_b, es_m, rp_m, aggm, NM,
                                             xm_b, es_u, rp_u, aggu, NU);
    sage_mfma<<<NBLK_M + NBLK_U, 256, 0, stream>>>(
        aggm, xm_b, W_c1um_l, W_c1um_r, c1_um_bl, xm1_b, NM, NBLK_M,
        aggu, xu_b, W_c1mu_l, W_c1mu_r, c1_mu_bl, xu1_b, NU, 1);
    // conv2
    agg_bf16<<<AGG_BLOCKS, 256, 0, stream>>>(xu1_b, es_m, rp_m, aggm, NM,
                                             xm1_b, es_u, rp_u, aggu, NU);
    sage_mfma<<<NBLK_M + NBLK_U, 256, 0, stream>>>(
        aggm, xm1_b, W_c2um_l, W_c2um_r, c2_um_bl, zm, NM, NBLK_M,
        aggu, xu1_b, W_c2mu_l, W_c2mu_r, c2_mu_bl, zu, NU, 0);

    // decoder (bf16 MFMA, 3-phase, fused layer-3, M=48, 72 KB LDS -> 2 blocks/CU)
    decoder_mfma<<<(NL + MROW - 1) / MROW, 512, 0, stream>>>(
        zu, zm, eli, w1p, dec_b1, w2p, dec_b2, dec_W3, dec_b3, (float*)d_out);
}

// Round 8
// 1115.607 us; speedup vs baseline: 1.2829x; 1.0705x over previous
//
#include <hip/hip_runtime.h>

#define NU 100000
#define NM 20000
#define NE 2000000
#define NL 500000
#define H  128
#define MROW 48   // decoder rows/block: 72 KB LDS -> 2 blocks/CU. PROVEN config (R2/R7:
                  // ~287us, VGPR 52, no spill). M=64/kh-split attempts (R4-R6) all spilled
                  // ~40 dwords/thread regardless of accumulator live-range splitting;
                  // M=32 regressed via 1.5x weight L2 traffic (R3).

typedef __attribute__((ext_vector_type(8))) short bf16x8;            // 8 bf16 (4 VGPRs)
typedef __attribute__((ext_vector_type(4))) float floatx4;           // 4 fp32 acc
typedef __attribute__((ext_vector_type(8))) unsigned short u16x8;    // 16B load/store
typedef __attribute__((ext_vector_type(4))) unsigned short u16x4;    // 8B store

// Native bf16 convert (RNE) — lowers to v_cvt_pk_bf16_f32 on gfx950.
__device__ __forceinline__ unsigned short f2b(float x) {
    union { __bf16 h; unsigned short u; } v;
    v.h = (__bf16)x;
    return v.u;
}
__device__ __forceinline__ float b2f(unsigned short h) {
    union { unsigned u; float f; } v; v.u = ((unsigned)h) << 16;
    return v.f;
}

// rotated LDS chunk addressing (chunk = 16B = 8 bf16), zero-waste bank pad.
// NOTE (R2): residual SQ_LDS_BANK_CONFLICT (~2.8e7) is inherent b128 wide-op
// serialization at full LDS BW, not a fixable conflict.
#define SFCH(r, c)  ((r) * 32 + (((c) + (r)) & 31))   // rows x 32 chunks (256 cols)
#define SH1CH(r, c) ((r) * 16 + (((c) + (r)) & 15))   // rows x 16 chunks (128 cols)
#define SH2CH(r, c) ((r) * 64 + (((c) + (r)) & 63))   // rows x 64 chunks (512 cols)

// ---------------------------------------------------------------- transpose (proj weights only)
struct TDesc { const float* s; float* d; int R; int C; };
struct TPack { TDesc t[2]; };

__global__ __launch_bounds__(256) void transpose_all(TPack p) {
    TDesc d = p.t[blockIdx.y];
    int n = d.R * d.C;
    for (int i = blockIdx.x * 256 + threadIdx.x; i < n; i += gridDim.x * 256) {
        int r = i / d.C, c = i - r * d.C;
        d.d[c * d.R + r] = d.s[i];  // dst[k][h] = src[h][k]
    }
}

// ---------------------------------------------------------------- pack decoder weights into MFMA frag order
// (A-fragment and B-fragment lane layouts are identical for 16x16x32)
__global__ __launch_bounds__(256) void pack_weights(const float* __restrict__ W1,
                                                    const float* __restrict__ W2,
                                                    unsigned short* __restrict__ W1p,
                                                    unsigned short* __restrict__ W2p) {
    const int n = 512 * 256;
    for (int i = blockIdx.x * 256 + threadIdx.x; i < n; i += gridDim.x * 256) {
        int j = i & 7, lane = (i >> 3) & 63;
        int ln = lane & 15, lq = lane >> 4;
        int kg1 = (i >> 9) & 7,  t1 = i >> 12;
        W1p[i] = f2b(W1[(t1 * 16 + ln) * 256 + kg1 * 32 + lq * 8 + j]);
        int kg2 = (i >> 9) & 15, t2 = i >> 13;
        W2p[i] = f2b(W2[(t2 * 16 + ln) * 512 + kg2 * 32 + lq * 8 + j]);
    }
}

// ---------------------------------------------------------------- pack 8 sage weights (H x H) into B-frag order
struct SPack { const float* w[8]; };
__global__ __launch_bounds__(256) void pack_sage(SPack sp, unsigned short* __restrict__ out) {
    const int n = 8 * 16384;
    for (int i = blockIdx.x * 256 + threadIdx.x; i < n; i += gridDim.x * 256) {
        int j = i & 7, lane = (i >> 3) & 63;
        int kg = (i >> 9) & 3, t = (i >> 11) & 7, wsel = i >> 14;
        int ln = lane & 15, lq = lane >> 4;
        out[i] = f2b(sp.w[wsel][(t * 16 + ln) * H + kg * 32 + lq * 8 + j]);
    }
}

// ---------------------------------------------------------------- CSR build
__global__ __launch_bounds__(256) void deg_kernel(const int* __restrict__ ei,
                                                  int* rp_m, int* rp_u) {
    for (int i = blockIdx.x * 256 + threadIdx.x; i < NE; i += gridDim.x * 256) {
        int u = ei[i], m = ei[NE + i];
        atomicAdd(&rp_u[u + 1], 1);
        atomicAdd(&rp_m[m + 1], 1);
    }
}

// Parallel inclusive scan over the two rp arrays (R8: the old scan2_kernel
// ran on TWO blocks with a serial 25-chunk carry chain x ~16 barriers each —
// ~100us of near-idle GPU). Two-pass: p1 = per-4096-tile totals -> aux;
// p2 = each tile block sums its <=24 predecessor totals and rescans its tile.
// aux layout: [0..31] = m tiles, [32..63] = u tiles.
__global__ __launch_bounds__(256) void scan_p1(const int* __restrict__ rp_m, int n_m,
                                               const int* __restrict__ rp_u, int n_u,
                                               int* __restrict__ aux) {
    const int arr = blockIdx.y;
    const int* a = arr ? rp_u : rp_m;
    const int n  = arr ? n_u : n_m;
    const int nb = (n + 4095) >> 12;
    const int b  = blockIdx.x;
    if (b >= nb) return;
    __shared__ int s[256];
    const int tid = threadIdx.x;
    int i0 = (b << 12) + tid * 16;
    int run = 0;
#pragma unroll
    for (int i = 0; i < 16; ++i) { int idx = i0 + i; run += (idx < n) ? a[idx] : 0; }
    s[tid] = run;
    __syncthreads();
    for (int off = 128; off > 0; off >>= 1) {
        if (tid < off) s[tid] += s[tid + off];
        __syncthreads();
    }
    if (tid == 0) aux[arr * 32 + b] = s[0];
}

__global__ __launch_bounds__(256) void scan_p2(int* __restrict__ rp_m, int n_m,
                                               int* __restrict__ rp_u, int n_u,
                                               const int* __restrict__ aux) {
    const int arr = blockIdx.y;
    int* a = arr ? rp_u : rp_m;
    const int n  = arr ? n_u : n_m;
    const int nb = (n + 4095) >> 12;
    const int b  = blockIdx.x;
    if (b >= nb) return;
    __shared__ int s[256];
    __shared__ int sc;
    const int tid = threadIdx.x;
    if (tid == 0) {
        int c = 0;
        for (int i = 0; i < b; ++i) c += aux[arr * 32 + i];
        sc = c;
    }
    int i0 = (b << 12) + tid * 16;
    int v[16];
    int run = 0;
#pragma unroll
    for (int i = 0; i < 16; ++i) {
        int idx = i0 + i;
        int x = (idx < n) ? a[idx] : 0;
        run += x; v[i] = run;
    }
    s[tid] = run;
    __syncthreads();
    for (int off = 1; off < 256; off <<= 1) {
        int t = (tid >= off) ? s[tid - off] : 0;
        __syncthreads();
        s[tid] += t;
        __syncthreads();
    }
    int prev = sc + (tid > 0 ? s[tid - 1] : 0);
#pragma unroll
    for (int i = 0; i < 16; ++i) {
        int idx = i0 + i;
        if (idx < n) a[idx] = v[i] + prev;
    }
}

__global__ __launch_bounds__(256) void bucket_kernel(const int* __restrict__ ei,
        const int* __restrict__ rp_m, const int* __restrict__ rp_u,
        int* cur_m, int* cur_u, int* es_m, int* es_u) {
    for (int i = blockIdx.x * 256 + threadIdx.x; i < NE; i += gridDim.x * 256) {
        int u = ei[i], m = ei[NE + i];
        int pm = atomicAdd(&cur_m[m], 1);
        es_m[rp_m[m] + pm] = u;
        int pu = atomicAdd(&cur_u[u], 1);
        es_u[rp_u[u] + pu] = m;
    }
}

// ---------------------------------------------------------------- projection (Linear + BN(eval) + ReLU) -> bf16
template <int K>
__global__ __launch_bounds__(256, 2) void proj_kernel(
        const float* __restrict__ x, const float* __restrict__ Wt,
        const float* __restrict__ lb, const float* __restrict__ g,
        const float* __restrict__ bb, const float* __restrict__ bm,
        const float* __restrict__ bv, unsigned short* __restrict__ out, int N) {
    __shared__ float sA[64 * K];
    const int tid = threadIdx.x;
    const int row0 = blockIdx.x * 64;
    constexpr int F4 = K / 4;
#pragma unroll
    for (int i = 0; i < (64 * F4) / 256; ++i) {
        int idx = tid + i * 256;
        int r = idx / F4, c = idx - r * F4;
        int gr = min(row0 + r, N - 1);
        ((float4*)sA)[idx] = ((const float4*)(x + (size_t)gr * K))[c];
    }
    __syncthreads();
    const int h_t = tid & 31, r_t = tid >> 5;
    float acc[8][4] = {};
#pragma unroll 4
    for (int k = 0; k < K; k += 4) {
        float4 w[4];
#pragma unroll
        for (int kk = 0; kk < 4; ++kk)
            w[kk] = *(const float4*)(Wt + (k + kk) * H + h_t * 4);
#pragma unroll
        for (int rr = 0; rr < 8; ++rr) {
            float4 a = *(const float4*)(sA + (r_t * 8 + rr) * K + k);
            acc[rr][0] += a.x * w[0].x + a.y * w[1].x + a.z * w[2].x + a.w * w[3].x;
            acc[rr][1] += a.x * w[0].y + a.y * w[1].y + a.z * w[2].y + a.w * w[3].y;
            acc[rr][2] += a.x * w[0].z + a.y * w[1].z + a.z * w[2].z + a.w * w[3].z;
            acc[rr][3] += a.x * w[0].w + a.y * w[1].w + a.z * w[2].w + a.w * w[3].w;
        }
    }
    const int h = h_t * 4;
    float4 lb4 = *(const float4*)(lb + h);
    float4 g4  = *(const float4*)(g  + h);
    float4 bb4 = *(const float4*)(bb + h);
    float4 m4  = *(const float4*)(bm + h);
    float4 v4  = *(const float4*)(bv + h);
    float sc[4] = { g4.x * rsqrtf(v4.x + 1e-5f), g4.y * rsqrtf(v4.y + 1e-5f),
                    g4.z * rsqrtf(v4.z + 1e-5f), g4.w * rsqrtf(v4.w + 1e-5f) };
    float lbv[4] = { lb4.x, lb4.y, lb4.z, lb4.w };
    float mv[4]  = { m4.x, m4.y, m4.z, m4.w };
    float bbv[4] = { bb4.x, bb4.y, bb4.z, bb4.w };
#pragma unroll
    for (int rr = 0; rr < 8; ++rr) {
        int gr = row0 + r_t * 8 + rr;
        if (gr < N) {
            u16x4 o;
#pragma unroll
            for (int c = 0; c < 4; ++c)
                o[c] = f2b(fmaxf((acc[rr][c] + lbv[c] - mv[c]) * sc[c] + bbv[c], 0.0f));
            *(u16x4*)(out + (size_t)gr * H + h) = o;
        }
    }
}

// ---------------------------------------------------------------- segment mean (bf16 in/out, fp32 acc)
// one WAVE per node. 16 lanes x 16B per row, 4 rows per wave-instruction,
// 16 rows in flight (R2 rewrite: ~57us total win vs 64-lane x 4B layout).
__global__ __launch_bounds__(256) void agg_bf16(
        const unsigned short* __restrict__ srcA, const int* __restrict__ esA,
        const int* __restrict__ rpA, unsigned short* __restrict__ outA, int nA,
        const unsigned short* __restrict__ srcB, const int* __restrict__ esB,
        const int* __restrict__ rpB, unsigned short* __restrict__ outB, int nB) {
    int wid = blockIdx.x * 4 + (threadIdx.x >> 6);
    const int lane = threadIdx.x & 63;
    const unsigned short* src; const int* es; const int* rp; unsigned short* out; int n;
    if (wid < nA) { src = srcA; es = esA; rp = rpA; out = outA; n = wid; }
    else {
        wid -= nA;
        if (wid >= nB) return;
        src = srcB; es = esB; rp = rpB; out = outB; n = wid;
    }
    const int start = rp[n], end = rp[n + 1];
    const int cb = (lane & 15) * 8;   // col base (8 bf16 = 16B)
    const int ro = lane >> 4;         // row slot 0..3
    float acc[8] = {};
    if (end > start) {
        int j = start;
        for (; j + 16 <= end; j += 16) {   // 16 rows in flight
            u16x8 v0 = *(const u16x8*)(src + (size_t)es[j +      ro] * H + cb);
            u16x8 v1 = *(const u16x8*)(src + (size_t)es[j +  4 + ro] * H + cb);
            u16x8 v2 = *(const u16x8*)(src + (size_t)es[j +  8 + ro] * H + cb);
            u16x8 v3 = *(const u16x8*)(src + (size_t)es[j + 12 + ro] * H + cb);
#pragma unroll
            for (int e = 0; e < 8; ++e)
                acc[e] += b2f(v0[e]) + b2f(v1[e]) + b2f(v2[e]) + b2f(v3[e]);
        }
        for (; j + 4 <= end; j += 4) {
            u16x8 v = *(const u16x8*)(src + (size_t)es[j + ro] * H + cb);
#pragma unroll
            for (int e = 0; e < 8; ++e) acc[e] += b2f(v[e]);
        }
        if (j < end) {   // tail 1..3 rows: masked batch (clamped index, end>start)
            int idx = j + ro;
            int row = es[idx < end ? idx : end - 1];
            float m = (idx < end) ? 1.0f : 0.0f;
            u16x8 v = *(const u16x8*)(src + (size_t)row * H + cb);
#pragma unroll
            for (int e = 0; e < 8; ++e) acc[e] = fmaf(m, b2f(v[e]), acc[e]);
        }
    }
#pragma unroll
    for (int e = 0; e < 8; ++e) {
        acc[e] += __shfl_xor(acc[e], 16);
        acc[e] += __shfl_xor(acc[e], 32);
    }
    float inv = (end > start) ? 1.0f / (float)(end - start) : 0.0f;
    if (ro == 0) {
        u16x8 o;
#pragma unroll
        for (int e = 0; e < 8; ++e) o[e] = f2b(acc[e] * inv);
        *(u16x8*)(out + (size_t)n * H + cb) = o;
    }
}

// ---------------------------------------------------------------- SAGE via MFMA
__global__ __launch_bounds__(256, 4) void sage_mfma(
        const unsigned short* __restrict__ aggA, const unsigned short* __restrict__ xA,
        const unsigned short* __restrict__ WlA, const unsigned short* __restrict__ WrA,
        const float* __restrict__ blA, unsigned short* __restrict__ outA, int NA, int NBLKA,
        const unsigned short* __restrict__ aggB, const unsigned short* __restrict__ xB,
        const unsigned short* __restrict__ WlB, const unsigned short* __restrict__ WrB,
        const float* __restrict__ blB, unsigned short* __restrict__ outB, int NB,
        int relu) {
    __shared__ unsigned short sAg[64 * 16 * 8];  // 16 KB
    __shared__ unsigned short sX[64 * 16 * 8];   // 16 KB
    const int tid = threadIdx.x;
    const unsigned short *agg, *x, *Wl, *Wr; const float* bl; unsigned short* out;
    int N, row0;
    if ((int)blockIdx.x < NBLKA) {
        agg = aggA; x = xA; Wl = WlA; Wr = WrA; bl = blA; out = outA; N = NA;
        row0 = blockIdx.x * 64;
    } else {
        agg = aggB; x = xB; Wl = WlB; Wr = WrB; bl = blB; out = outB; N = NB;
        row0 = (blockIdx.x - NBLKA) * 64;
    }
#pragma unroll
    for (int i = 0; i < 4; ++i) {
        int idx = tid + i * 256;           // 1024 chunks
        int r = idx >> 4, c = idx & 15;
        int gr = min(row0 + r, N - 1);
        *(u16x8*)(sAg + SH1CH(r, c) * 8) = *(const u16x8*)(agg + (size_t)gr * H + c * 8);
        *(u16x8*)(sX  + SH1CH(r, c) * 8) = *(const u16x8*)(x   + (size_t)gr * H + c * 8);
    }
    __syncthreads();
    const int lane = tid & 63, w = tid >> 6;
    const int ln = lane & 15, lq = lane >> 4;
    floatx4 acc[2][4] = {};
#pragma unroll 2
    for (int kg = 0; kg < 4; ++kg) {
        bf16x8 aA[4], aX[4];
#pragma unroll
        for (int mt = 0; mt < 4; ++mt) {
            aA[mt] = *(const bf16x8*)(sAg + SH1CH(mt * 16 + ln, kg * 4 + lq) * 8);
            aX[mt] = *(const bf16x8*)(sX  + SH1CH(mt * 16 + ln, kg * 4 + lq) * 8);
        }
#pragma unroll
        for (int nt = 0; nt < 2; ++nt) {
            int widx = ((w * 2 + nt) * 4 + kg) * 512 + lane * 8;
            bf16x8 bL = *(const bf16x8*)(Wl + widx);
            bf16x8 bR = *(const bf16x8*)(Wr + widx);
#pragma unroll
            for (int mt = 0; mt < 4; ++mt) {
                acc[nt][mt] = __builtin_amdgcn_mfma_f32_16x16x32_bf16(aA[mt], bL, acc[nt][mt], 0, 0, 0);
                acc[nt][mt] = __builtin_amdgcn_mfma_f32_16x16x32_bf16(aX[mt], bR, acc[nt][mt], 0, 0, 0);
            }
        }
    }
    __syncthreads();   // done reading sAg; reuse it for output staging
    {
#pragma unroll
        for (int nt = 0; nt < 2; ++nt) {
            int ncol = w * 32 + nt * 16 + ln;   // 0..127
            float bv = bl[ncol];
            int cch = ncol >> 3, coff = ncol & 7;
#pragma unroll
            for (int mt = 0; mt < 4; ++mt)
#pragma unroll
                for (int i = 0; i < 4; ++i) {
                    int row = mt * 16 + lq * 4 + i;
                    float v = acc[nt][mt][i] + bv;
                    if (relu) v = fmaxf(v, 0.0f);
                    sAg[SH1CH(row, cch) * 8 + coff] = f2b(v);
                }
        }
    }
    __syncthreads();
#pragma unroll
    for (int i = 0; i < 4; ++i) {
        int idx = tid + i * 256;
        int r = idx >> 4, c = idx & 15;
        int gr = row0 + r;
        if (gr < N)
            *(u16x8*)(out + (size_t)gr * H + c * 8) = *(const u16x8*)(sAg + SH1CH(r, c) * 8);
    }
}

// ---------------------------------------------------------------- fused edge decoder MLP — 3-phase, M=48 (PROVEN R2 config)
// Layer 3 fused into phase-2 registers (R1). Full h1 in 48 KB LDS; phases
// fully sequential so only one accumulator array is live at a time (48 then
// 24 regs) — 52 VGPR, no spill. kh-split variants (R4-R6) all spilled.
// R8: s_setprio(1) around MFMA clusters (T5) — 2 independent blocks/CU give
// wave role diversity; measured cleanly via decoder dur.
__global__ __launch_bounds__(512, 4) void decoder_mfma(
        const unsigned short* __restrict__ zu, const unsigned short* __restrict__ zm,
        const int* __restrict__ eli,
        const unsigned short* __restrict__ W1p, const float* __restrict__ b1,
        const unsigned short* __restrict__ W2p, const float* __restrict__ b2,
        const float* __restrict__ W3, const float* __restrict__ b3,
        float* __restrict__ out) {
    __shared__ unsigned short sF[MROW * 32 * 8];   // feat 48x256 bf16 rotated (24 KB), later f32 partials
    __shared__ unsigned short sH1[MROW * 64 * 8];  // h1 FULL 48x512 bf16 rotated (48 KB)
    const int tid = threadIdx.x;
    const int row0 = blockIdx.x * MROW;
    // ---- gather feat = [zu[eu] | zm[em]] (bf16 straight copy); 8 threads/row
    {
        int r = tid >> 3, p = tid & 7;
        if (r < MROW) {
            int rg = min(row0 + r, NL - 1);
            int iu = eli[rg], im = eli[NL + rg];
            const unsigned short* zur = zu + (size_t)iu * H;
            const unsigned short* zmr = zm + (size_t)im * H;
#pragma unroll
            for (int j = 0; j < 4; ++j) {
                int c = p + j * 8;   // 0..31
                const unsigned short* s = (c < 16) ? (zur + c * 8) : (zmr + (c - 16) * 8);
                *(u16x8*)(sF + SFCH(r, c) * 8) = *(const u16x8*)s;
            }
        }
    }
    __syncthreads();
    const int lane = tid & 63, w = tid >> 6;   // 8 waves
    const int ln = lane & 15, lq = lane >> 4;
    // ---- phase 1: h1^T = W1 · feat^T ; wave w owns h1 cols [w*64, +64)
    {
        floatx4 acc1[4][3] = {};   // [nt: h1col tile][mt: edge-row tile]
        const unsigned short* w1base = W1p + ((size_t)(w * 4) * 8) * 512 + lane * 8;
        __builtin_amdgcn_s_setprio(1);
#pragma unroll 2
        for (int kg = 0; kg < 8; ++kg) {
            bf16x8 fb[3];   // feat fragments (B operand): B[n=edge row][k]
#pragma unroll
            for (int mt = 0; mt < 3; ++mt)
                fb[mt] = *(const bf16x8*)(sF + SFCH(mt * 16 + ln, kg * 4 + lq) * 8);
#pragma unroll
            for (int nt = 0; nt < 4; ++nt) {
                bf16x8 wa = *(const bf16x8*)(w1base + (size_t)(nt * 8 + kg) * 512);  // A: W1 rows
#pragma unroll
                for (int mt = 0; mt < 3; ++mt)
                    acc1[nt][mt] = __builtin_amdgcn_mfma_f32_16x16x32_bf16(wa, fb[mt], acc1[nt][mt], 0, 0, 0);
            }
        }
        __builtin_amdgcn_s_setprio(0);
        // epilogue: D[row=h1col lq*4+i][col=edge row ln] -> b64 store per (nt,mt)
#pragma unroll
        for (int nt = 0; nt < 4; ++nt) {
            int colbase = w * 64 + nt * 16 + lq * 4;   // h1 col of reg 0
            float4 bv = *(const float4*)(b1 + colbase);
            int cch = colbase >> 3, coff = colbase & 7;   // coff = (lq&1)*4
#pragma unroll
            for (int mt = 0; mt < 3; ++mt) {
                int erow = mt * 16 + ln;
                u16x4 o = { f2b(fmaxf(acc1[nt][mt][0] + bv.x, 0.0f)),
                            f2b(fmaxf(acc1[nt][mt][1] + bv.y, 0.0f)),
                            f2b(fmaxf(acc1[nt][mt][2] + bv.z, 0.0f)),
                            f2b(fmaxf(acc1[nt][mt][3] + bv.w, 0.0f)) };
                *(u16x4*)(sH1 + SH2CH(erow, cch) * 8 + coff) = o;
            }
        }
    }
    __syncthreads();   // also: last read of sF (feat) is above -> safe to overlay later
    // ---- phase 2: h2^T = W2 · h1^T over full K=512; wave w owns h2 cols [w*32,+32)
    floatx4 acc3[2][3] = {};
    {
        const unsigned short* w2base = W2p + ((size_t)(w * 2) * 16) * 512 + lane * 8;
        __builtin_amdgcn_s_setprio(1);
#pragma unroll 2
        for (int kg = 0; kg < 16; ++kg) {
            bf16x8 hb[3];   // h1 fragments (B operand)
#pragma unroll
            for (int mt = 0; mt < 3; ++mt)
                hb[mt] = *(const bf16x8*)(sH1 + SH2CH(mt * 16 + ln, kg * 4 + lq) * 8);
#pragma unroll
            for (int nt = 0; nt < 2; ++nt) {
                bf16x8 wa = *(const bf16x8*)(w2base + (size_t)(nt * 16 + kg) * 512);
#pragma unroll
                for (int mt = 0; mt < 3; ++mt)
                    acc3[nt][mt] = __builtin_amdgcn_mfma_f32_16x16x32_bf16(wa, hb[mt], acc3[nt][mt], 0, 0, 0);
            }
        }
        __builtin_amdgcn_s_setprio(0);
    }
    // ---- fused layer 3: per-lane partial dot over this lane's 8 h2 cols
    // (ReLU + b2 applied in fp32 registers; no bf16 round-trip, no LDS h2)
    float* sP = (float*)sF;   // 48 x 36 f32 partials (6.9 KB, stride 36 -> <=2-way banks)
    {
        float4 w3a = *(const float4*)(W3 + w * 32 + lq * 4);
        float4 w3b = *(const float4*)(W3 + w * 32 + 16 + lq * 4);
        float4 b2a = *(const float4*)(b2 + w * 32 + lq * 4);
        float4 b2b = *(const float4*)(b2 + w * 32 + 16 + lq * 4);
#pragma unroll
        for (int mt = 0; mt < 3; ++mt) {
            float s =
                fmaxf(acc3[0][mt][0] + b2a.x, 0.0f) * w3a.x +
                fmaxf(acc3[0][mt][1] + b2a.y, 0.0f) * w3a.y +
                fmaxf(acc3[0][mt][2] + b2a.z, 0.0f) * w3a.z +
                fmaxf(acc3[0][mt][3] + b2a.w, 0.0f) * w3a.w +
                fmaxf(acc3[1][mt][0] + b2b.x, 0.0f) * w3b.x +
                fmaxf(acc3[1][mt][1] + b2b.y, 0.0f) * w3b.y +
                fmaxf(acc3[1][mt][2] + b2b.z, 0.0f) * w3b.z +
                fmaxf(acc3[1][mt][3] + b2b.w, 0.0f) * w3b.w;
            sP[(mt * 16 + ln) * 36 + w * 4 + lq] = s;
        }
    }
    __syncthreads();
    // ---- reduce 32 partials per edge row: 8 threads/row, float4 each, shfl
    {
        int r = tid >> 3, p = tid & 7;
        if (r < MROW) {
            float4 v = *(const float4*)(sP + r * 36 + p * 4);
            float sum = v.x + v.y + v.z + v.w;
            sum += __shfl_down(sum, 4, 8);
            sum += __shfl_down(sum, 2, 8);
            sum += __shfl_down(sum, 1, 8);
            if (p == 0 && row0 + r < NL) out[row0 + r] = sum + b3[0];
        }
    }
}

// ---------------------------------------------------------------- host
extern "C" void kernel_launch(void* const* d_in, const int* in_sizes, int n_in,
                              void* d_out, int out_size, void* d_ws, size_t ws_size,
                              hipStream_t stream) {
    const float* x_user  = (const float*)d_in[0];
    const float* x_movie = (const float*)d_in[1];
    const int*   ei      = (const int*)d_in[2];
    const int*   eli     = (const int*)d_in[3];
    const float* lin_u_W = (const float*)d_in[4];
    const float* lin_u_b = (const float*)d_in[5];
    const float* lin_m_W = (const float*)d_in[6];
    const float* lin_m_b = (const float*)d_in[7];
    const float* bn_u_g  = (const float*)d_in[8];
    const float* bn_u_b  = (const float*)d_in[9];
    const float* bn_u_m  = (const float*)d_in[10];
    const float* bn_u_v  = (const float*)d_in[11];
    const float* bn_m_g  = (const float*)d_in[12];
    const float* bn_m_b  = (const float*)d_in[13];
    const float* bn_m_m  = (const float*)d_in[14];
    const float* bn_m_v  = (const float*)d_in[15];
    const float* c1_um_Wl = (const float*)d_in[16];
    const float* c1_um_bl = (const float*)d_in[17];
    const float* c1_um_Wr = (const float*)d_in[18];
    const float* c1_mu_Wl = (const float*)d_in[19];
    const float* c1_mu_bl = (const float*)d_in[20];
    const float* c1_mu_Wr = (const float*)d_in[21];
    const float* c2_um_Wl = (const float*)d_in[22];
    const float* c2_um_bl = (const float*)d_in[23];
    const float* c2_um_Wr = (const float*)d_in[24];
    const float* c2_mu_Wl = (const float*)d_in[25];
    const float* c2_mu_bl = (const float*)d_in[26];
    const float* c2_mu_Wr = (const float*)d_in[27];
    const float* dec_W1 = (const float*)d_in[28];
    const float* dec_b1 = (const float*)d_in[29];
    const float* dec_W2 = (const float*)d_in[30];
    const float* dec_b2 = (const float*)d_in[31];
    const float* dec_W3 = (const float*)d_in[32];
    const float* dec_b3 = (const float*)d_in[33];

    char* base = (char*)d_ws;
    size_t off = 0;
    auto alloc = [&](size_t bytes) -> char* {
        char* p = base + off;
        off += (bytes + 255) & ~(size_t)255;
        return p;
    };
    unsigned short* xu_b  = (unsigned short*)alloc((size_t)NU * H * 2);
    unsigned short* xm_b  = (unsigned short*)alloc((size_t)NM * H * 2);
    unsigned short* xu1_b = (unsigned short*)alloc((size_t)NU * H * 2);
    unsigned short* xm1_b = (unsigned short*)alloc((size_t)NM * H * 2);
    unsigned short* aggu  = (unsigned short*)alloc((size_t)NU * H * 2);
    unsigned short* aggm  = (unsigned short*)alloc((size_t)NM * H * 2);
    float* wt_u = (float*)alloc((size_t)64 * H * 4);
    float* wt_m = (float*)alloc((size_t)H * H * 4);
    unsigned short* wsg = (unsigned short*)alloc((size_t)8 * 16384 * 2);  // packed sage weights
    unsigned short* w1p = (unsigned short*)alloc((size_t)512 * 256 * 2);
    unsigned short* w2p = (unsigned short*)alloc((size_t)256 * 512 * 2);
    int* rp_m  = (int*)alloc((size_t)(NM + 1) * 4);
    int* rp_u  = (int*)alloc((size_t)(NU + 1) * 4);
    int* cur_m = (int*)alloc((size_t)NM * 4);
    int* cur_u = (int*)alloc((size_t)NU * 4);
    int* es_m  = (int*)alloc((size_t)NE * 4);
    int* es_u  = (int*)alloc((size_t)NE * 4);
    int* scan_aux = (int*)alloc((size_t)64 * 4);
    unsigned short* zu = xu_b;   // xu_b dead after conv1 sage -> reuse
    unsigned short* zm = xm_b;

    // zero CSR meta (rp_m .. cur_u incl. padding)
    hipMemsetAsync(rp_m, 0, (size_t)((char*)es_m - (char*)rp_m), stream);

    TPack tp;
    tp.t[0] = { lin_u_W, wt_u, H, 64 };
    tp.t[1] = { lin_m_W, wt_m, H, H };
    transpose_all<<<dim3(64, 2), 256, 0, stream>>>(tp);
    pack_weights<<<256, 256, 0, stream>>>(dec_W1, dec_W2, w1p, w2p);
    SPack sp;
    sp.w[0] = c1_um_Wl; sp.w[1] = c1_um_Wr; sp.w[2] = c1_mu_Wl; sp.w[3] = c1_mu_Wr;
    sp.w[4] = c2_um_Wl; sp.w[5] = c2_um_Wr; sp.w[6] = c2_mu_Wl; sp.w[7] = c2_mu_Wr;
    pack_sage<<<128, 256, 0, stream>>>(sp, wsg);
    const unsigned short* W_c1um_l = wsg + 0 * 16384;
    const unsigned short* W_c1um_r = wsg + 1 * 16384;
    const unsigned short* W_c1mu_l = wsg + 2 * 16384;
    const unsigned short* W_c1mu_r = wsg + 3 * 16384;
    const unsigned short* W_c2um_l = wsg + 4 * 16384;
    const unsigned short* W_c2um_r = wsg + 5 * 16384;
    const unsigned short* W_c2mu_l = wsg + 6 * 16384;
    const unsigned short* W_c2mu_r = wsg + 7 * 16384;

    deg_kernel<<<2048, 256, 0, stream>>>(ei, rp_m, rp_u);
    scan_p1<<<dim3(25, 2), 256, 0, stream>>>(rp_m, NM + 1, rp_u, NU + 1, scan_aux);
    scan_p2<<<dim3(25, 2), 256, 0, stream>>>(rp_m, NM + 1, rp_u, NU + 1, scan_aux);
    bucket_kernel<<<2048, 256, 0, stream>>>(ei, rp_m, rp_u, cur_m, cur_u, es_m, es_u);

    proj_kernel<64><<<(NU + 63) / 64, 256, 0, stream>>>(
        x_user, wt_u, lin_u_b, bn_u_g, bn_u_b, bn_u_m, bn_u_v, xu_b, NU);
    proj_kernel<128><<<(NM + 63) / 64, 256, 0, stream>>>(
        x_movie, wt_m, lin_m_b, bn_m_g, bn_m_b, bn_m_m, bn_m_v, xm_b, NM);

    const int AGG_BLOCKS = (NM + NU + 3) / 4;
    const int NBLK_M = (NM + 63) / 64, NBLK_U = (NU + 63) / 64;

    // conv1
    agg_bf16<<<AGG_BLOCKS, 256, 0, stream>>>(xu_b, es_m, rp_m, aggm, NM,
                                             xm_b, es_u, rp_u, aggu, NU);
    sage_mfma<<<NBLK_M + NBLK_U, 256, 0, stream>>>(
        aggm, xm_b, W_c1um_l, W_c1um_r, c1_um_bl, xm1_b, NM, NBLK_M,
        aggu, xu_b, W_c1mu_l, W_c1mu_r, c1_mu_bl, xu1_b, NU, 1);
    // conv2
    agg_bf16<<<AGG_BLOCKS, 256, 0, stream>>>(xu1_b, es_m, rp_m, aggm, NM,
                                             xm1_b, es_u, rp_u, aggu, NU);
    sage_mfma<<<NBLK_M + NBLK_U, 256, 0, stream>>>(
        aggm, xm1_b, W_c2um_l, W_c2um_r, c2_um_bl, zm, NM, NBLK_M,
        aggu, xu1_b, W_c2mu_l, W_c2mu_r, c2_mu_bl, zu, NU, 0);

    // decoder (bf16 MFMA, 3-phase, fused layer-3, M=48, 72 KB LDS -> 2 blocks/CU)
    decoder_mfma<<<(NL + MROW - 1) / MROW, 512, 0, stream>>>(
        zu, zm, eli, w1p, dec_b1, w2p, dec_b2, dec_W3, dec_b3, (float*)d_out);
}

// Round 9
// 947.555 us; speedup vs baseline: 1.5105x; 1.1774x over previous
//
#include <hip/hip_runtime.h>

#define NU 100000
#define NM 20000
#define NE 2000000
#define NL 500000
#define H  128
#define MROW 48   // decoder rows/block: 72 KB LDS -> 2 blocks/CU. PROVEN config (R2/R7:
                  // ~287us, VGPR 52, no spill). M=64/kh-split attempts (R4-R6) all spilled
                  // ~40 dwords/thread regardless of accumulator live-range splitting;
                  // M=32 regressed via 1.5x weight L2 traffic (R3). setprio (R8): -2%,
                  // removed (consistent with T5 null on barrier-lockstep GEMM phases).

typedef __attribute__((ext_vector_type(8))) short bf16x8;            // 8 bf16 (4 VGPRs)
typedef __attribute__((ext_vector_type(4))) float floatx4;           // 4 fp32 acc
typedef __attribute__((ext_vector_type(8))) unsigned short u16x8;    // 16B load/store
typedef __attribute__((ext_vector_type(4))) unsigned short u16x4;    // 8B store

// Native bf16 convert (RNE) — lowers to v_cvt_pk_bf16_f32 on gfx950.
__device__ __forceinline__ unsigned short f2b(float x) {
    union { __bf16 h; unsigned short u; } v;
    v.h = (__bf16)x;
    return v.u;
}
__device__ __forceinline__ float b2f(unsigned short h) {
    union { unsigned u; float f; } v; v.u = ((unsigned)h) << 16;
    return v.f;
}

// rotated LDS chunk addressing (chunk = 16B = 8 bf16), zero-waste bank pad.
// NOTE (R2): residual SQ_LDS_BANK_CONFLICT (~2.8e7) is inherent b128 wide-op
// serialization at full LDS BW, not a fixable conflict.
#define SFCH(r, c)  ((r) * 32 + (((c) + (r)) & 31))   // rows x 32 chunks (256 cols)
#define SH1CH(r, c) ((r) * 16 + (((c) + (r)) & 15))   // rows x 16 chunks (128 cols)
#define SH2CH(r, c) ((r) * 64 + (((c) + (r)) & 63))   // rows x 64 chunks (512 cols)

// ---------------------------------------------------------------- fused prep:
// {transpose x2, pack_weights, pack_sage, deg+pos} — all independent; fusing
// co-runs latency-bound deg with compute-bound packs and saves 3 launches (R9).
struct PrepArgs {
    const float* luW; float* wtu;          // transpose: (H x 64) -> wtu[k*H+h]
    const float* lmW; float* wtm;          // transpose: (H x H)  -> wtm[k*H+h]
    const float* W1; const float* W2;
    unsigned short* W1p; unsigned short* W2p;
    const float* sw[8]; unsigned short* wsg;
    const int* ei; int* rp_m; int* rp_u; int* pos_m; int* pos_u;
};

__global__ __launch_bounds__(256) void prep1(PrepArgs a) {
    const int b = blockIdx.x, tid = threadIdx.x;
    if (b < 64) {                 // transpose lin_u_W: R=H rows, C=64 cols
        const int n = H * 64;
        for (int i = b * 256 + tid; i < n; i += 64 * 256) {
            int r = i >> 6, c = i & 63;
            a.wtu[c * H + r] = a.luW[i];
        }
    } else if (b < 128) {         // transpose lin_m_W: R=H, C=H
        const int n = H * H;
        for (int i = (b - 64) * 256 + tid; i < n; i += 64 * 256) {
            int r = i >> 7, c = i & 127;
            a.wtm[c * H + r] = a.lmW[i];
        }
    } else if (b < 384) {         // pack decoder weights into MFMA frag order
        const int n = 512 * 256;
        for (int i = (b - 128) * 256 + tid; i < n; i += 256 * 256) {
            int j = i & 7, lane = (i >> 3) & 63;
            int ln = lane & 15, lq = lane >> 4;
            int kg1 = (i >> 9) & 7,  t1 = i >> 12;
            a.W1p[i] = f2b(a.W1[(t1 * 16 + ln) * 256 + kg1 * 32 + lq * 8 + j]);
            int kg2 = (i >> 9) & 15, t2 = i >> 13;
            a.W2p[i] = f2b(a.W2[(t2 * 16 + ln) * 512 + kg2 * 32 + lq * 8 + j]);
        }
    } else if (b < 512) {         // pack 8 sage weights (H x H) into B-frag order
        const int n = 8 * 16384;
        for (int i = (b - 384) * 256 + tid; i < n; i += 128 * 256) {
            int j = i & 7, lane = (i >> 3) & 63;
            int kg = (i >> 9) & 3, t = (i >> 11) & 7, wsel = i >> 14;
            int ln = lane & 15, lq = lane >> 4;
            a.wsg[i] = f2b(a.sw[wsel][(t * 16 + ln) * H + kg * 32 + lq * 8 + j]);
        }
    } else {                      // deg + per-edge position (R9: pos makes bucket atomic-free)
        for (int i = (b - 512) * 256 + tid; i < NE; i += 2048 * 256) {
            int u = a.ei[i], m = a.ei[NE + i];
            a.pos_u[i] = atomicAdd(&a.rp_u[u + 1], 1);
            a.pos_m[i] = atomicAdd(&a.rp_m[m + 1], 1);
        }
    }
}

// Parallel inclusive scan over the two rp arrays (R8: old 2-block serial scan
// was ~80us of near-idle GPU; this two-pass version is ~10us).
// aux layout: [0..31] = m tiles, [32..63] = u tiles.
__global__ __launch_bounds__(256) void scan_p1(const int* __restrict__ rp_m, int n_m,
                                               const int* __restrict__ rp_u, int n_u,
                                               int* __restrict__ aux) {
    const int arr = blockIdx.y;
    const int* a = arr ? rp_u : rp_m;
    const int n  = arr ? n_u : n_m;
    const int nb = (n + 4095) >> 12;
    const int b  = blockIdx.x;
    if (b >= nb) return;
    __shared__ int s[256];
    const int tid = threadIdx.x;
    int i0 = (b << 12) + tid * 16;
    int run = 0;
#pragma unroll
    for (int i = 0; i < 16; ++i) { int idx = i0 + i; run += (idx < n) ? a[idx] : 0; }
    s[tid] = run;
    __syncthreads();
    for (int off = 128; off > 0; off >>= 1) {
        if (tid < off) s[tid] += s[tid + off];
        __syncthreads();
    }
    if (tid == 0) aux[arr * 32 + b] = s[0];
}

__global__ __launch_bounds__(256) void scan_p2(int* __restrict__ rp_m, int n_m,
                                               int* __restrict__ rp_u, int n_u,
                                               const int* __restrict__ aux) {
    const int arr = blockIdx.y;
    int* a = arr ? rp_u : rp_m;
    const int n  = arr ? n_u : n_m;
    const int nb = (n + 4095) >> 12;
    const int b  = blockIdx.x;
    if (b >= nb) return;
    __shared__ int s[256];
    __shared__ int sc;
    const int tid = threadIdx.x;
    if (tid == 0) {
        int c = 0;
        for (int i = 0; i < b; ++i) c += aux[arr * 32 + i];
        sc = c;
    }
    int i0 = (b << 12) + tid * 16;
    int v[16];
    int run = 0;
#pragma unroll
    for (int i = 0; i < 16; ++i) {
        int idx = i0 + i;
        int x = (idx < n) ? a[idx] : 0;
        run += x; v[i] = run;
    }
    s[tid] = run;
    __syncthreads();
    for (int off = 1; off < 256; off <<= 1) {
        int t = (tid >= off) ? s[tid - off] : 0;
        __syncthreads();
        s[tid] += t;
        __syncthreads();
    }
    int prev = sc + (tid > 0 ? s[tid - 1] : 0);
#pragma unroll
    for (int i = 0; i < 16; ++i) {
        int idx = i0 + i;
        if (idx < n) a[idx] = v[i] + prev;
    }
}

// ---------------------------------------------------------------- projection body (Linear + BN(eval) + ReLU) -> bf16
template <int K>
__device__ __forceinline__ void proj_body(
        const float* __restrict__ x, const float* __restrict__ Wt,
        const float* __restrict__ lb, const float* __restrict__ g,
        const float* __restrict__ bb, const float* __restrict__ bm,
        const float* __restrict__ bv, unsigned short* __restrict__ out, int N,
        int blk, float* sA) {
    const int tid = threadIdx.x;
    const int row0 = blk * 64;
    constexpr int F4 = K / 4;
#pragma unroll
    for (int i = 0; i < (64 * F4) / 256; ++i) {
        int idx = tid + i * 256;
        int r = idx / F4, c = idx - r * F4;
        int gr = min(row0 + r, N - 1);
        ((float4*)sA)[idx] = ((const float4*)(x + (size_t)gr * K))[c];
    }
    __syncthreads();
    const int h_t = tid & 31, r_t = tid >> 5;
    float acc[8][4] = {};
#pragma unroll 4
    for (int k = 0; k < K; k += 4) {
        float4 w[4];
#pragma unroll
        for (int kk = 0; kk < 4; ++kk)
            w[kk] = *(const float4*)(Wt + (k + kk) * H + h_t * 4);
#pragma unroll
        for (int rr = 0; rr < 8; ++rr) {
            float4 a = *(const float4*)(sA + (r_t * 8 + rr) * K + k);
            acc[rr][0] += a.x * w[0].x + a.y * w[1].x + a.z * w[2].x + a.w * w[3].x;
            acc[rr][1] += a.x * w[0].y + a.y * w[1].y + a.z * w[2].y + a.w * w[3].y;
            acc[rr][2] += a.x * w[0].z + a.y * w[1].z + a.z * w[2].z + a.w * w[3].z;
            acc[rr][3] += a.x * w[0].w + a.y * w[1].w + a.z * w[2].w + a.w * w[3].w;
        }
    }
    const int h = h_t * 4;
    float4 lb4 = *(const float4*)(lb + h);
    float4 g4  = *(const float4*)(g  + h);
    float4 bb4 = *(const float4*)(bb + h);
    float4 m4  = *(const float4*)(bm + h);
    float4 v4  = *(const float4*)(bv + h);
    float sc[4] = { g4.x * rsqrtf(v4.x + 1e-5f), g4.y * rsqrtf(v4.y + 1e-5f),
                    g4.z * rsqrtf(v4.z + 1e-5f), g4.w * rsqrtf(v4.w + 1e-5f) };
    float lbv[4] = { lb4.x, lb4.y, lb4.z, lb4.w };
    float mv[4]  = { m4.x, m4.y, m4.z, m4.w };
    float bbv[4] = { bb4.x, bb4.y, bb4.z, bb4.w };
#pragma unroll
    for (int rr = 0; rr < 8; ++rr) {
        int gr = row0 + r_t * 8 + rr;
        if (gr < N) {
            u16x4 o;
#pragma unroll
            for (int c = 0; c < 4; ++c)
                o[c] = f2b(fmaxf((acc[rr][c] + lbv[c] - mv[c]) * sc[c] + bbv[c], 0.0f));
            *(u16x4*)(out + (size_t)gr * H + h) = o;
        }
    }
}

// ---------------------------------------------------------------- fused {bucket, proj_u, proj_m}
// bucket (scatter-latency-bound, now atomic-free via pos arrays) co-runs with
// compute-bound proj. Independent work; both depend only on scan / transpose.
struct PBArgs {
    const int* ei; const int* rp_m; const int* rp_u;
    const int* pos_m; const int* pos_u; int* es_m; int* es_u;
    const float* xu; const float* wtu;
    const float* lub; const float* bug; const float* bub; const float* bum; const float* buv;
    unsigned short* xu_b;
    const float* xm; const float* wtm;
    const float* lmb; const float* bmg; const float* bmb; const float* bmm; const float* bmv;
    unsigned short* xm_b;
    int nbu;   // proj_u block count
};

__global__ __launch_bounds__(256, 2) void projbucket(PBArgs a) {
    __shared__ float sA[64 * H];   // 32 KB; proj branches only
    const int b = blockIdx.x;
    if (b < 2048) {               // bucket: atomic-free scatter using precomputed pos
        for (int i = b * 256 + threadIdx.x; i < NE; i += 2048 * 256) {
            int u = a.ei[i], m = a.ei[NE + i];
            a.es_m[a.rp_m[m] + a.pos_m[i]] = u;
            a.es_u[a.rp_u[u] + a.pos_u[i]] = m;
        }
    } else if (b < 2048 + a.nbu) {
        proj_body<64>(a.xu, a.wtu, a.lub, a.bug, a.bub, a.bum, a.buv, a.xu_b, NU,
                      b - 2048, sA);
    } else {
        proj_body<128>(a.xm, a.wtm, a.lmb, a.bmg, a.bmb, a.bmm, a.bmv, a.xm_b, NM,
                       b - 2048 - a.nbu, sA);
    }
}

// ---------------------------------------------------------------- segment mean (bf16 in/out, fp32 acc)
// one WAVE per node. 16 lanes x 16B per row, 4 rows per wave-instruction,
// 16 rows in flight (R2 rewrite: ~57us total win vs 64-lane x 4B layout).
__global__ __launch_bounds__(256) void agg_bf16(
        const unsigned short* __restrict__ srcA, const int* __restrict__ esA,
        const int* __restrict__ rpA, unsigned short* __restrict__ outA, int nA,
        const unsigned short* __restrict__ srcB, const int* __restrict__ esB,
        const int* __restrict__ rpB, unsigned short* __restrict__ outB, int nB) {
    int wid = blockIdx.x * 4 + (threadIdx.x >> 6);
    const int lane = threadIdx.x & 63;
    const unsigned short* src; const int* es; const int* rp; unsigned short* out; int n;
    if (wid < nA) { src = srcA; es = esA; rp = rpA; out = outA; n = wid; }
    else {
        wid -= nA;
        if (wid >= nB) return;
        src = srcB; es = esB; rp = rpB; out = outB; n = wid;
    }
    const int start = rp[n], end = rp[n + 1];
    const int cb = (lane & 15) * 8;   // col base (8 bf16 = 16B)
    const int ro = lane >> 4;         // row slot 0..3
    float acc[8] = {};
    if (end > start) {
        int j = start;
        for (; j + 16 <= end; j += 16) {   // 16 rows in flight
            u16x8 v0 = *(const u16x8*)(src + (size_t)es[j +      ro] * H + cb);
            u16x8 v1 = *(const u16x8*)(src + (size_t)es[j +  4 + ro] * H + cb);
            u16x8 v2 = *(const u16x8*)(src + (size_t)es[j +  8 + ro] * H + cb);
            u16x8 v3 = *(const u16x8*)(src + (size_t)es[j + 12 + ro] * H + cb);
#pragma unroll
            for (int e = 0; e < 8; ++e)
                acc[e] += b2f(v0[e]) + b2f(v1[e]) + b2f(v2[e]) + b2f(v3[e]);
        }
        for (; j + 4 <= end; j += 4) {
            u16x8 v = *(const u16x8*)(src + (size_t)es[j + ro] * H + cb);
#pragma unroll
            for (int e = 0; e < 8; ++e) acc[e] += b2f(v[e]);
        }
        if (j < end) {   // tail 1..3 rows: masked batch (clamped index, end>start)
            int idx = j + ro;
            int row = es[idx < end ? idx : end - 1];
            float m = (idx < end) ? 1.0f : 0.0f;
            u16x8 v = *(const u16x8*)(src + (size_t)row * H + cb);
#pragma unroll
            for (int e = 0; e < 8; ++e) acc[e] = fmaf(m, b2f(v[e]), acc[e]);
        }
    }
#pragma unroll
    for (int e = 0; e < 8; ++e) {
        acc[e] += __shfl_xor(acc[e], 16);
        acc[e] += __shfl_xor(acc[e], 32);
    }
    float inv = (end > start) ? 1.0f / (float)(end - start) : 0.0f;
    if (ro == 0) {
        u16x8 o;
#pragma unroll
        for (int e = 0; e < 8; ++e) o[e] = f2b(acc[e] * inv);
        *(u16x8*)(out + (size_t)n * H + cb) = o;
    }
}

// ---------------------------------------------------------------- SAGE via MFMA
__global__ __launch_bounds__(256, 4) void sage_mfma(
        const unsigned short* __restrict__ aggA, const unsigned short* __restrict__ xA,
        const unsigned short* __restrict__ WlA, const unsigned short* __restrict__ WrA,
        const float* __restrict__ blA, unsigned short* __restrict__ outA, int NA, int NBLKA,
        const unsigned short* __restrict__ aggB, const unsigned short* __restrict__ xB,
        const unsigned short* __restrict__ WlB, const unsigned short* __restrict__ WrB,
        const float* __restrict__ blB, unsigned short* __restrict__ outB, int NB,
        int relu) {
    __shared__ unsigned short sAg[64 * 16 * 8];  // 16 KB
    __shared__ unsigned short sX[64 * 16 * 8];   // 16 KB
    const int tid = threadIdx.x;
    const unsigned short *agg, *x, *Wl, *Wr; const float* bl; unsigned short* out;
    int N, row0;
    if ((int)blockIdx.x < NBLKA) {
        agg = aggA; x = xA; Wl = WlA; Wr = WrA; bl = blA; out = outA; N = NA;
        row0 = blockIdx.x * 64;
    } else {
        agg = aggB; x = xB; Wl = WlB; Wr = WrB; bl = blB; out = outB; N = NB;
        row0 = (blockIdx.x - NBLKA) * 64;
    }
#pragma unroll
    for (int i = 0; i < 4; ++i) {
        int idx = tid + i * 256;           // 1024 chunks
        int r = idx >> 4, c = idx & 15;
        int gr = min(row0 + r, N - 1);
        *(u16x8*)(sAg + SH1CH(r, c) * 8) = *(const u16x8*)(agg + (size_t)gr * H + c * 8);
        *(u16x8*)(sX  + SH1CH(r, c) * 8) = *(const u16x8*)(x   + (size_t)gr * H + c * 8);
    }
    __syncthreads();
    const int lane = tid & 63, w = tid >> 6;
    const int ln = lane & 15, lq = lane >> 4;
    floatx4 acc[2][4] = {};
#pragma unroll 2
    for (int kg = 0; kg < 4; ++kg) {
        bf16x8 aA[4], aX[4];
#pragma unroll
        for (int mt = 0; mt < 4; ++mt) {
            aA[mt] = *(const bf16x8*)(sAg + SH1CH(mt * 16 + ln, kg * 4 + lq) * 8);
            aX[mt] = *(const bf16x8*)(sX  + SH1CH(mt * 16 + ln, kg * 4 + lq) * 8);
        }
#pragma unroll
        for (int nt = 0; nt < 2; ++nt) {
            int widx = ((w * 2 + nt) * 4 + kg) * 512 + lane * 8;
            bf16x8 bL = *(const bf16x8*)(Wl + widx);
            bf16x8 bR = *(const bf16x8*)(Wr + widx);
#pragma unroll
            for (int mt = 0; mt < 4; ++mt) {
                acc[nt][mt] = __builtin_amdgcn_mfma_f32_16x16x32_bf16(aA[mt], bL, acc[nt][mt], 0, 0, 0);
                acc[nt][mt] = __builtin_amdgcn_mfma_f32_16x16x32_bf16(aX[mt], bR, acc[nt][mt], 0, 0, 0);
            }
        }
    }
    __syncthreads();   // done reading sAg; reuse it for output staging
    {
#pragma unroll
        for (int nt = 0; nt < 2; ++nt) {
            int ncol = w * 32 + nt * 16 + ln;   // 0..127
            float bv = bl[ncol];
            int cch = ncol >> 3, coff = ncol & 7;
#pragma unroll
            for (int mt = 0; mt < 4; ++mt)
#pragma unroll
                for (int i = 0; i < 4; ++i) {
                    int row = mt * 16 + lq * 4 + i;
                    float v = acc[nt][mt][i] + bv;
                    if (relu) v = fmaxf(v, 0.0f);
                    sAg[SH1CH(row, cch) * 8 + coff] = f2b(v);
                }
        }
    }
    __syncthreads();
#pragma unroll
    for (int i = 0; i < 4; ++i) {
        int idx = tid + i * 256;
        int r = idx >> 4, c = idx & 15;
        int gr = row0 + r;
        if (gr < N)
            *(u16x8*)(out + (size_t)gr * H + c * 8) = *(const u16x8*)(sAg + SH1CH(r, c) * 8);
    }
}

// ---------------------------------------------------------------- fused edge decoder MLP — 3-phase, M=48 (PROVEN R2/R7 config)
// Layer 3 fused into phase-2 registers (R1). Full h1 in 48 KB LDS; phases
// fully sequential so only one accumulator array is live at a time (48 then
// 24 regs) — 52 VGPR, no spill. kh-split variants (R4-R6) all spilled.
__global__ __launch_bounds__(512, 4) void decoder_mfma(
        const unsigned short* __restrict__ zu, const unsigned short* __restrict__ zm,
        const int* __restrict__ eli,
        const unsigned short* __restrict__ W1p, const float* __restrict__ b1,
        const unsigned short* __restrict__ W2p, const float* __restrict__ b2,
        const float* __restrict__ W3, const float* __restrict__ b3,
        float* __restrict__ out) {
    __shared__ unsigned short sF[MROW * 32 * 8];   // feat 48x256 bf16 rotated (24 KB), later f32 partials
    __shared__ unsigned short sH1[MROW * 64 * 8];  // h1 FULL 48x512 bf16 rotated (48 KB)
    const int tid = threadIdx.x;
    const int row0 = blockIdx.x * MROW;
    // ---- gather feat = [zu[eu] | zm[em]] (bf16 straight copy); 8 threads/row
    {
        int r = tid >> 3, p = tid & 7;
        if (r < MROW) {
            int rg = min(row0 + r, NL - 1);
            int iu = eli[rg], im = eli[NL + rg];
            const unsigned short* zur = zu + (size_t)iu * H;
            const unsigned short* zmr = zm + (size_t)im * H;
#pragma unroll
            for (int j = 0; j < 4; ++j) {
                int c = p + j * 8;   // 0..31
                const unsigned short* s = (c < 16) ? (zur + c * 8) : (zmr + (c - 16) * 8);
                *(u16x8*)(sF + SFCH(r, c) * 8) = *(const u16x8*)s;
            }
        }
    }
    __syncthreads();
    const int lane = tid & 63, w = tid >> 6;   // 8 waves
    const int ln = lane & 15, lq = lane >> 4;
    // ---- phase 1: h1^T = W1 · feat^T ; wave w owns h1 cols [w*64, +64)
    {
        floatx4 acc1[4][3] = {};   // [nt: h1col tile][mt: edge-row tile]
        const unsigned short* w1base = W1p + ((size_t)(w * 4) * 8) * 512 + lane * 8;
#pragma unroll 2
        for (int kg = 0; kg < 8; ++kg) {
            bf16x8 fb[3];   // feat fragments (B operand): B[n=edge row][k]
#pragma unroll
            for (int mt = 0; mt < 3; ++mt)
                fb[mt] = *(const bf16x8*)(sF + SFCH(mt * 16 + ln, kg * 4 + lq) * 8);
#pragma unroll
            for (int nt = 0; nt < 4; ++nt) {
                bf16x8 wa = *(const bf16x8*)(w1base + (size_t)(nt * 8 + kg) * 512);  // A: W1 rows
#pragma unroll
                for (int mt = 0; mt < 3; ++mt)
                    acc1[nt][mt] = __builtin_amdgcn_mfma_f32_16x16x32_bf16(wa, fb[mt], acc1[nt][mt], 0, 0, 0);
            }
        }
        // epilogue: D[row=h1col lq*4+i][col=edge row ln] -> b64 store per (nt,mt)
#pragma unroll
        for (int nt = 0; nt < 4; ++nt) {
            int colbase = w * 64 + nt * 16 + lq * 4;   // h1 col of reg 0
            float4 bv = *(const float4*)(b1 + colbase);
            int cch = colbase >> 3, coff = colbase & 7;   // coff = (lq&1)*4
#pragma unroll
            for (int mt = 0; mt < 3; ++mt) {
                int erow = mt * 16 + ln;
                u16x4 o = { f2b(fmaxf(acc1[nt][mt][0] + bv.x, 0.0f)),
                            f2b(fmaxf(acc1[nt][mt][1] + bv.y, 0.0f)),
                            f2b(fmaxf(acc1[nt][mt][2] + bv.z, 0.0f)),
                            f2b(fmaxf(acc1[nt][mt][3] + bv.w, 0.0f)) };
                *(u16x4*)(sH1 + SH2CH(erow, cch) * 8 + coff) = o;
            }
        }
    }
    __syncthreads();   // also: last read of sF (feat) is above -> safe to overlay later
    // ---- phase 2: h2^T = W2 · h1^T over full K=512; wave w owns h2 cols [w*32,+32)
    floatx4 acc3[2][3] = {};
    {
        const unsigned short* w2base = W2p + ((size_t)(w * 2) * 16) * 512 + lane * 8;
#pragma unroll 2
        for (int kg = 0; kg < 16; ++kg) {
            bf16x8 hb[3];   // h1 fragments (B operand)
#pragma unroll
            for (int mt = 0; mt < 3; ++mt)
                hb[mt] = *(const bf16x8*)(sH1 + SH2CH(mt * 16 + ln, kg * 4 + lq) * 8);
#pragma unroll
            for (int nt = 0; nt < 2; ++nt) {
                bf16x8 wa = *(const bf16x8*)(w2base + (size_t)(nt * 16 + kg) * 512);
#pragma unroll
                for (int mt = 0; mt < 3; ++mt)
                    acc3[nt][mt] = __builtin_amdgcn_mfma_f32_16x16x32_bf16(wa, hb[mt], acc3[nt][mt], 0, 0, 0);
            }
        }
    }
    // ---- fused layer 3: per-lane partial dot over this lane's 8 h2 cols
    // (ReLU + b2 applied in fp32 registers; no bf16 round-trip, no LDS h2)
    float* sP = (float*)sF;   // 48 x 36 f32 partials (6.9 KB, stride 36 -> <=2-way banks)
    {
        float4 w3a = *(const float4*)(W3 + w * 32 + lq * 4);
        float4 w3b = *(const float4*)(W3 + w * 32 + 16 + lq * 4);
        float4 b2a = *(const float4*)(b2 + w * 32 + lq * 4);
        float4 b2b = *(const float4*)(b2 + w * 32 + 16 + lq * 4);
#pragma unroll
        for (int mt = 0; mt < 3; ++mt) {
            float s =
                fmaxf(acc3[0][mt][0] + b2a.x, 0.0f) * w3a.x +
                fmaxf(acc3[0][mt][1] + b2a.y, 0.0f) * w3a.y +
                fmaxf(acc3[0][mt][2] + b2a.z, 0.0f) * w3a.z +
                fmaxf(acc3[0][mt][3] + b2a.w, 0.0f) * w3a.w +
                fmaxf(acc3[1][mt][0] + b2b.x, 0.0f) * w3b.x +
                fmaxf(acc3[1][mt][1] + b2b.y, 0.0f) * w3b.y +
                fmaxf(acc3[1][mt][2] + b2b.z, 0.0f) * w3b.z +
                fmaxf(acc3[1][mt][3] + b2b.w, 0.0f) * w3b.w;
            sP[(mt * 16 + ln) * 36 + w * 4 + lq] = s;
        }
    }
    __syncthreads();
    // ---- reduce 32 partials per edge row: 8 threads/row, float4 each, shfl
    {
        int r = tid >> 3, p = tid & 7;
        if (r < MROW) {
            float4 v = *(const float4*)(sP + r * 36 + p * 4);
            float sum = v.x + v.y + v.z + v.w;
            sum += __shfl_down(sum, 4, 8);
            sum += __shfl_down(sum, 2, 8);
            sum += __shfl_down(sum, 1, 8);
            if (p == 0 && row0 + r < NL) out[row0 + r] = sum + b3[0];
        }
    }
}

// ---------------------------------------------------------------- host
extern "C" void kernel_launch(void* const* d_in, const int* in_sizes, int n_in,
                              void* d_out, int out_size, void* d_ws, size_t ws_size,
                              hipStream_t stream) {
    const float* x_user  = (const float*)d_in[0];
    const float* x_movie = (const float*)d_in[1];
    const int*   ei      = (const int*)d_in[2];
    const int*   eli     = (const int*)d_in[3];
    const float* lin_u_W = (const float*)d_in[4];
    const float* lin_u_b = (const float*)d_in[5];
    const float* lin_m_W = (const float*)d_in[6];
    const float* lin_m_b = (const float*)d_in[7];
    const float* bn_u_g  = (const float*)d_in[8];
    const float* bn_u_b  = (const float*)d_in[9];
    const float* bn_u_m  = (const float*)d_in[10];
    const float* bn_u_v  = (const float*)d_in[11];
    const float* bn_m_g  = (const float*)d_in[12];
    const float* bn_m_b  = (const float*)d_in[13];
    const float* bn_m_m  = (const float*)d_in[14];
    const float* bn_m_v  = (const float*)d_in[15];
    const float* c1_um_Wl = (const float*)d_in[16];
    const float* c1_um_bl = (const float*)d_in[17];
    const float* c1_um_Wr = (const float*)d_in[18];
    const float* c1_mu_Wl = (const float*)d_in[19];
    const float* c1_mu_bl = (const float*)d_in[20];
    const float* c1_mu_Wr = (const float*)d_in[21];
    const float* c2_um_Wl = (const float*)d_in[22];
    const float* c2_um_bl = (const float*)d_in[23];
    const float* c2_um_Wr = (const float*)d_in[24];
    const float* c2_mu_Wl = (const float*)d_in[25];
    const float* c2_mu_bl = (const float*)d_in[26];
    const float* c2_mu_Wr = (const float*)d_in[27];
    const float* dec_W1 = (const float*)d_in[28];
    const float* dec_b1 = (const float*)d_in[29];
    const float* dec_W2 = (const float*)d_in[30];
    const float* dec_b2 = (const float*)d_in[31];
    const float* dec_W3 = (const float*)d_in[32];
    const float* dec_b3 = (const float*)d_in[33];

    char* base = (char*)d_ws;
    size_t off = 0;
    auto alloc = [&](size_t bytes) -> char* {
        char* p = base + off;
        off += (bytes + 255) & ~(size_t)255;
        return p;
    };
    unsigned short* xu_b  = (unsigned short*)alloc((size_t)NU * H * 2);
    unsigned short* xm_b  = (unsigned short*)alloc((size_t)NM * H * 2);
    unsigned short* xu1_b = (unsigned short*)alloc((size_t)NU * H * 2);
    unsigned short* xm1_b = (unsigned short*)alloc((size_t)NM * H * 2);
    unsigned short* aggu  = (unsigned short*)alloc((size_t)NU * H * 2);
    unsigned short* aggm  = (unsigned short*)alloc((size_t)NM * H * 2);
    float* wt_u = (float*)alloc((size_t)64 * H * 4);
    float* wt_m = (float*)alloc((size_t)H * H * 4);
    unsigned short* wsg = (unsigned short*)alloc((size_t)8 * 16384 * 2);  // packed sage weights
    unsigned short* w1p = (unsigned short*)alloc((size_t)512 * 256 * 2);
    unsigned short* w2p = (unsigned short*)alloc((size_t)256 * 512 * 2);
    int* rp_m  = (int*)alloc((size_t)(NM + 1) * 4);
    int* rp_u  = (int*)alloc((size_t)(NU + 1) * 4);
    int* es_m  = (int*)alloc((size_t)NE * 4);
    int* es_u  = (int*)alloc((size_t)NE * 4);
    int* scan_aux = (int*)alloc((size_t)64 * 4);
    unsigned short* zu = xu_b;   // xu_b dead after conv1 sage -> reuse
    unsigned short* zm = xm_b;
    // pos arrays alias aggu (16 MB <= 25.6 MB): dead before agg1 writes aggu.
    int* pos_m = (int*)aggu;
    int* pos_u = pos_m + NE;

    // zero rp arrays (deg atomicAdds into them); es not in span (alloc order)
    hipMemsetAsync(rp_m, 0, (size_t)((char*)es_m - (char*)rp_m), stream);

    PrepArgs pa;
    pa.luW = lin_u_W; pa.wtu = wt_u;
    pa.lmW = lin_m_W; pa.wtm = wt_m;
    pa.W1 = dec_W1; pa.W2 = dec_W2; pa.W1p = w1p; pa.W2p = w2p;
    pa.sw[0] = c1_um_Wl; pa.sw[1] = c1_um_Wr; pa.sw[2] = c1_mu_Wl; pa.sw[3] = c1_mu_Wr;
    pa.sw[4] = c2_um_Wl; pa.sw[5] = c2_um_Wr; pa.sw[6] = c2_mu_Wl; pa.sw[7] = c2_mu_Wr;
    pa.wsg = wsg;
    pa.ei = ei; pa.rp_m = rp_m; pa.rp_u = rp_u; pa.pos_m = pos_m; pa.pos_u = pos_u;
    prep1<<<2560, 256, 0, stream>>>(pa);

    scan_p1<<<dim3(25, 2), 256, 0, stream>>>(rp_m, NM + 1, rp_u, NU + 1, scan_aux);
    scan_p2<<<dim3(25, 2), 256, 0, stream>>>(rp_m, NM + 1, rp_u, NU + 1, scan_aux);

    const int NBU = (NU + 63) / 64, NBM = (NM + 63) / 64;
    PBArgs pb;
    pb.ei = ei; pb.rp_m = rp_m; pb.rp_u = rp_u;
    pb.pos_m = pos_m; pb.pos_u = pos_u; pb.es_m = es_m; pb.es_u = es_u;
    pb.xu = x_user; pb.wtu = wt_u;
    pb.lub = lin_u_b; pb.bug = bn_u_g; pb.bub = bn_u_b; pb.bum = bn_u_m; pb.buv = bn_u_v;
    pb.xu_b = xu_b;
    pb.xm = x_movie; pb.wtm = wt_m;
    pb.lmb = lin_m_b; pb.bmg = bn_m_g; pb.bmb = bn_m_b; pb.bmm = bn_m_m; pb.bmv = bn_m_v;
    pb.xm_b = xm_b;
    pb.nbu = NBU;
    projbucket<<<2048 + NBU + NBM, 256, 0, stream>>>(pb);

    const unsigned short* W_c1um_l = wsg + 0 * 16384;
    const unsigned short* W_c1um_r = wsg + 1 * 16384;
    const unsigned short* W_c1mu_l = wsg + 2 * 16384;
    const unsigned short* W_c1mu_r = wsg + 3 * 16384;
    const unsigned short* W_c2um_l = wsg + 4 * 16384;
    const unsigned short* W_c2um_r = wsg + 5 * 16384;
    const unsigned short* W_c2mu_l = wsg + 6 * 16384;
    const unsigned short* W_c2mu_r = wsg + 7 * 16384;

    const int AGG_BLOCKS = (NM + NU + 3) / 4;
    const int NBLK_M = (NM + 63) / 64, NBLK_U = (NU + 63) / 64;

    // conv1
    agg_bf16<<<AGG_BLOCKS, 256, 0, stream>>>(xu_b, es_m, rp_m, aggm, NM,
                                             xm_b, es_u, rp_u, aggu, NU);
    sage_mfma<<<NBLK_M + NBLK_U, 256, 0, stream>>>(
        aggm, xm_b, W_c1um_l, W_c1um_r, c1_um_bl, xm1_b, NM, NBLK_M,
        aggu, xu_b, W_c1mu_l, W_c1mu_r, c1_mu_bl, xu1_b, NU, 1);
    // conv2
    agg_bf16<<<AGG_BLOCKS, 256, 0, stream>>>(xu1_b, es_m, rp_m, aggm, NM,
                                             xm1_b, es_u, rp_u, aggu, NU);
    sage_mfma<<<NBLK_M + NBLK_U, 256, 0, stream>>>(
        aggm, xm1_b, W_c2um_l, W_c2um_r, c2_um_bl, zm, NM, NBLK_M,
        aggu, xu1_b, W_c2mu_l, W_c2mu_r, c2_mu_bl, zu, NU, 0);

    // decoder (bf16 MFMA, 3-phase, fused layer-3, M=48, 72 KB LDS -> 2 blocks/CU)
    decoder_mfma<<<(NL + MROW - 1) / MROW, 512, 0, stream>>>(
        zu, zm, eli, w1p, dec_b1, w2p, dec_b2, dec_W3, dec_b3, (float*)d_out);
}